// Round 5
// baseline (1096.831 us; speedup 1.0000x reference)
//
#include <hip/hip_runtime.h>
#include <hip/hip_bf16.h>

// B=8, H=W=64, C=128, rate=2 -> k=3, h=w=32, L=1024
// Workspace (72,433,664 bytes), time-multiplexed regions (liveness checked):
//  phase A/B: sp [0,4.73M) invd [4.73,5.26M) Bf [5.26,43.0M) T [0,33.55M)
//             Bp [0,37.75M) yup [37.75,54.53M)
//  phase C/D: SM [0,16.78M) P3 pair [16.78,34.62M) A1 [34.62,51.40M)
//             X pair [51.40,69.24M)
//  static:    weights [69.24,71.11M) m0/mm [71.11,71.17M)

#define BOFF_SP      0
#define BOFF_INVD    4734976
#define BOFF_BFH     5259264
#define BOFF_BFL     24133632
#define BOFF_T       0
#define BOFF_BPH     0
#define BOFF_BPL     18874368
#define BOFF_YUP     37748736
#define BOFF_SM      0
#define BOFF_P3H     16777216
#define BOFF_P3L     25698304
#define BOFF_A1      34619392
#define BOFF_XH      51396608
#define BOFF_XL      60317696
#define BOFF_WT1H    69238784
#define BOFF_WT1L    69533696
#define BOFF_WT2H    69828608
#define BOFF_WT2L    70418432
#define BOFF_PW1B    71008256
#define BOFF_PW2B    71041024
#define BOFF_M0      71106560
#define BOFF_MM      71139328

typedef float f32x4 __attribute__((ext_vector_type(4)));
typedef short bf16x8 __attribute__((ext_vector_type(8)));

__device__ __forceinline__ short f2bf(float f) {
    unsigned u = __float_as_uint(f);
    unsigned r = u + 0x7FFFu + ((u >> 16) & 1u);
    return (short)(r >> 16);
}
__device__ __forceinline__ float bf2f(short s) {
    return __uint_as_float(((unsigned)(unsigned short)s) << 16);
}
__device__ __forceinline__ void cvt8(const float4 v0, const float4 v1, bf16x8& h, bf16x8& l) {
    float a[8] = {v0.x, v0.y, v0.z, v0.w, v1.x, v1.y, v1.z, v1.w};
#pragma unroll
    for (int u = 0; u < 8; ++u) {
        short hh = f2bf(a[u]);
        h[u] = hh;
        l[u] = f2bf(a[u] - bf2f(hh));
    }
}

__global__ __launch_bounds__(256) void k_mask_pool(const float* __restrict__ mask, float* __restrict__ m0) {
    int blk = blockIdx.x;
    int b = blk >> 10, pq = blk & 1023, p = pq >> 5, q = pq & 31;
    int t = threadIdx.x, dy = t >> 4, dx = t & 15;
    float v = mask[((size_t)(b * 512 + p * 16 + dy)) * 512 + q * 16 + dx];
#pragma unroll
    for (int o = 32; o; o >>= 1) v = fmaxf(v, __shfl_xor(v, o));
    __shared__ float s[4];
    if ((t & 63) == 0) s[t >> 6] = v;
    __syncthreads();
    if (t == 0) m0[blk] = fmaxf(fmaxf(s[0], s[1]), fmaxf(s[2], s[3]));
}

__global__ void k_mask_dilate(const float* __restrict__ m0, float* __restrict__ mm) {
    int idx = blockIdx.x * 256 + threadIdx.x;
    if (idx >= 8192) return;
    int b = idx >> 10, pq = idx & 1023, p = pq >> 5, q = pq & 31;
    float v = -1e30f;
    for (int di = -1; di <= 1; ++di)
        for (int dj = -1; dj <= 1; ++dj) {
            int pp = p + di, qq = q + dj;
            if (pp >= 0 && pp < 32 && qq >= 0 && qq < 32)
                v = fmaxf(v, m0[(b << 10) + pp * 32 + qq]);
        }
    mm[idx] = 1.0f - v;
}

__global__ void k_srcpad(const float* __restrict__ x, float* __restrict__ sp) {
    int idx = blockIdx.x * 256 + threadIdx.x;
    if (idx >= 8 * 34 * 34 * 128) return;
    int c = idx & 127;
    int r = idx >> 7;
    int xx = r % 34; r /= 34;
    int yy = r % 34; int b = r / 34;
    float v = 0.f;
    if (yy >= 1 && yy <= 32 && xx >= 1 && xx <= 32)
        v = x[(((size_t)(b * 64 + (yy - 1) * 2)) * 64 + (xx - 1) * 2) * 128 + c];
    sp[idx] = v;
}

__global__ void k_invd(const float* __restrict__ sp, float* __restrict__ invd) {
    int idx = blockIdx.x * 256 + threadIdx.x;
    if (idx >= 1024 * 128) return;
    int c = idx & 127, l = idx >> 7, lh = l >> 5, lw = l & 31;
    float s = 0.f;
    for (int b = 0; b < 8; ++b)
#pragma unroll
        for (int i = 0; i < 3; ++i)
#pragma unroll
            for (int j = 0; j < 3; ++j) {
                float v = sp[(((size_t)(b * 34 + lh + i)) * 34 + (lw + j)) * 128 + c];
                s += v * v;
            }
    invd[idx] = 1.0f / fmaxf(s, 1e-8f);
}

// Bf[b][l][ij][c] = sp[b][lh+i][lw+j][c] * invd[l][c], split bf16 pair.
__global__ void k_corr_B(const float* __restrict__ sp, const float* __restrict__ invd,
                         short* __restrict__ bh, short* __restrict__ bl) {
    int idx = blockIdx.x * 256 + threadIdx.x;
    int c8 = idx & 15; int rest = idx >> 4;
    int ij = rest % 9; int rest2 = rest / 9;
    int l = rest2 & 1023, b = rest2 >> 10;
    int lh = l >> 5, lw = l & 31;
    int i = (ij >= 6) ? 2 : (ij >= 3 ? 1 : 0);
    int j = ij - 3 * i;
    int c0 = c8 * 8;
    const float* s = sp + (((size_t)(b * 34 + lh + i)) * 34 + (lw + j)) * 128 + c0;
    const float* dv = invd + l * 128 + c0;
    bf16x8 h, lo;
#pragma unroll
    for (int u = 0; u < 8; ++u) {
        float v = s[u] * dv[u];
        short hh = f2bf(v);
        h[u] = hh;
        lo[u] = f2bf(v - bf2f(hh));
    }
    size_t off = ((size_t)(b * 1024 + l)) * 1152 + ij * 128 + c0;
    *reinterpret_cast<bf16x8*>(bh + off) = h;
    *reinterpret_cast<bf16x8*>(bl + off) = lo;
}

// Bp[b][ij][c][l] = x[b][2lh+ip][2lw+jp][c] (0 OOB), split bf16 pair.
__global__ void k_deconv_B(const float* __restrict__ x, short* __restrict__ bh, short* __restrict__ bl) {
    int idx = blockIdx.x * 256 + threadIdx.x;
    int l8 = idx & 127; int rest = idx >> 7;
    int c = rest & 127; int rest2 = rest >> 7;
    int ij = rest2 % 9; int b = rest2 / 9;
    int ip = (ij >= 6) ? 2 : (ij >= 3 ? 1 : 0);
    int jp = ij - 3 * ip;
    int l0 = l8 * 8;
    int lh = l0 >> 5, lw0 = l0 & 31;
    int rr = 2 * lh + ip;
    bf16x8 h, lo;
#pragma unroll
    for (int u = 0; u < 8; ++u) {
        int ss = 2 * (lw0 + u) + jp;
        float v = (rr < 64 && ss < 64) ? x[(((size_t)(b * 64 + rr)) * 64 + ss) * 128 + c] : 0.f;
        short hh = f2bf(v);
        h[u] = hh;
        lo[u] = f2bf(v - bf2f(hh));
    }
    size_t off = (((size_t)(b * 9 + ij)) * 128 + c) * 1024 + l0;
    *reinterpret_cast<bf16x8*>(bh + off) = h;
    *reinterpret_cast<bf16x8*>(bl + off) = lo;
}

// corr MFMA: per batch y[pq,l] = sum_k A[pq,k]*B[k,l]; M=1024,N=1024,K=1152.
__global__ __launch_bounds__(256) void k_corr_mfma(const float* __restrict__ sp,
                                                   const short* __restrict__ bfh,
                                                   const short* __restrict__ bfl,
                                                   float* __restrict__ outy) {
    const int b = blockIdx.z, tm = blockIdx.y, tn = blockIdx.x;
    __shared__ short Ah[64][32];
    __shared__ short Al[64][32];
    const int tid = threadIdx.x;
    const int w = tid >> 6, lane = tid & 63, m = lane & 15, g = lane >> 4;
    f32x4 acc[4][2];
#pragma unroll
    for (int mf = 0; mf < 4; ++mf)
#pragma unroll
        for (int nn = 0; nn < 2; ++nn) acc[mf][nn] = f32x4{0.f, 0.f, 0.f, 0.f};
    const int srow = tid >> 2, scc = (tid & 3) * 8;
    const int pq = tm * 64 + srow, p = pq >> 5, q = pq & 31;
    const int col0 = tn * 128 + w * 32 + m;
    const size_t bB = (size_t)b * 1024;
    for (int kt = 0; kt < 1152; kt += 32) {
        int ij = kt >> 7;
        int i = (ij >= 6) ? 2 : (ij >= 3 ? 1 : 0);
        int j = ij - 3 * i;
        int c0 = (kt & 127) + scc;
        const float* s = sp + (((size_t)(b * 34 + p + i)) * 34 + (q + j)) * 128 + c0;
        float4 v0 = *reinterpret_cast<const float4*>(s);
        float4 v1 = *reinterpret_cast<const float4*>(s + 4);
        bf16x8 hh, ll;
        cvt8(v0, v1, hh, ll);
        __syncthreads();
        *reinterpret_cast<bf16x8*>(&Ah[srow][scc]) = hh;
        *reinterpret_cast<bf16x8*>(&Al[srow][scc]) = ll;
        __syncthreads();
        bf16x8 ah[4], al[4];
#pragma unroll
        for (int mf = 0; mf < 4; ++mf) {
            ah[mf] = *reinterpret_cast<const bf16x8*>(&Ah[mf * 16 + m][g * 8]);
            al[mf] = *reinterpret_cast<const bf16x8*>(&Al[mf * 16 + m][g * 8]);
        }
#pragma unroll
        for (int nn = 0; nn < 2; ++nn) {
            size_t off = (bB + col0 + nn * 16) * 1152 + kt + g * 8;
            bf16x8 bh = *reinterpret_cast<const bf16x8*>(bfh + off);
            bf16x8 bl = *reinterpret_cast<const bf16x8*>(bfl + off);
#pragma unroll
            for (int mf = 0; mf < 4; ++mf) {
                acc[mf][nn] = __builtin_amdgcn_mfma_f32_16x16x32_bf16(ah[mf], bh, acc[mf][nn], 0, 0, 0);
                acc[mf][nn] = __builtin_amdgcn_mfma_f32_16x16x32_bf16(al[mf], bh, acc[mf][nn], 0, 0, 0);
                acc[mf][nn] = __builtin_amdgcn_mfma_f32_16x16x32_bf16(ah[mf], bl, acc[mf][nn], 0, 0, 0);
            }
        }
    }
#pragma unroll
    for (int mf = 0; mf < 4; ++mf) {
        int row = tm * 64 + mf * 16 + g * 4;
#pragma unroll
        for (int nn = 0; nn < 2; ++nn) {
            int col = col0 + nn * 16;
#pragma unroll
            for (int r = 0; r < 4; ++r)
                outy[((size_t)b << 20) + (size_t)(row + r) * 1024 + col] = acc[mf][nn][r];
        }
    }
}

// deconv MFMA: per batch Z[uv,kcol] = sum_l y[uv,l]*Bp[kcol,l]; M=1024,N=1152,K=1024.
__global__ __launch_bounds__(256) void k_deconv_mfma(const float* __restrict__ yprob,
                                                     const short* __restrict__ bph,
                                                     const short* __restrict__ bpl,
                                                     float* __restrict__ yup) {
    const int b = blockIdx.z, tm = blockIdx.y, tn = blockIdx.x;   // tn = ij in 0..8
    __shared__ short Ah[64][32];
    __shared__ short Al[64][32];
    const int tid = threadIdx.x;
    const int w = tid >> 6, lane = tid & 63, m = lane & 15, g = lane >> 4;
    f32x4 acc[4][2];
#pragma unroll
    for (int mf = 0; mf < 4; ++mf)
#pragma unroll
        for (int nn = 0; nn < 2; ++nn) acc[mf][nn] = f32x4{0.f, 0.f, 0.f, 0.f};
    const int srow = tid >> 2, scc = (tid & 3) * 8;
    const int uvs = tm * 64 + srow;
    const int col0 = tn * 128 + w * 32 + m;
    for (int kt = 0; kt < 1024; kt += 32) {
        const float* s = yprob + ((size_t)b << 20) + (size_t)uvs * 1024 + kt + scc;
        float4 v0 = *reinterpret_cast<const float4*>(s);
        float4 v1 = *reinterpret_cast<const float4*>(s + 4);
        bf16x8 hh, ll;
        cvt8(v0, v1, hh, ll);
        __syncthreads();
        *reinterpret_cast<bf16x8*>(&Ah[srow][scc]) = hh;
        *reinterpret_cast<bf16x8*>(&Al[srow][scc]) = ll;
        __syncthreads();
        bf16x8 ah[4], al[4];
#pragma unroll
        for (int mf = 0; mf < 4; ++mf) {
            ah[mf] = *reinterpret_cast<const bf16x8*>(&Ah[mf * 16 + m][g * 8]);
            al[mf] = *reinterpret_cast<const bf16x8*>(&Al[mf * 16 + m][g * 8]);
        }
#pragma unroll
        for (int nn = 0; nn < 2; ++nn) {
            size_t off = ((size_t)b * 1152 + col0 + nn * 16) * 1024 + kt + g * 8;
            bf16x8 bh = *reinterpret_cast<const bf16x8*>(bph + off);
            bf16x8 bl = *reinterpret_cast<const bf16x8*>(bpl + off);
#pragma unroll
            for (int mf = 0; mf < 4; ++mf) {
                acc[mf][nn] = __builtin_amdgcn_mfma_f32_16x16x32_bf16(ah[mf], bh, acc[mf][nn], 0, 0, 0);
                acc[mf][nn] = __builtin_amdgcn_mfma_f32_16x16x32_bf16(al[mf], bh, acc[mf][nn], 0, 0, 0);
                acc[mf][nn] = __builtin_amdgcn_mfma_f32_16x16x32_bf16(ah[mf], bl, acc[mf][nn], 0, 0, 0);
            }
        }
    }
    const int ip = (tn >= 6) ? 2 : (tn >= 3 ? 1 : 0);
    const int jp = tn - 3 * ip;
#pragma unroll
    for (int mf = 0; mf < 4; ++mf) {
        int uvb = tm * 64 + mf * 16 + g * 4;
#pragma unroll
        for (int nn = 0; nn < 2; ++nn) {
            int c = w * 32 + nn * 16 + m;
#pragma unroll
            for (int r = 0; r < 4; ++r) {
                int uv = uvb + r;
                int uu = uv >> 5, vv = uv & 31;
                int P = 2 * uu + ip, Q = 2 * vv + jp;
                if (P < 64 && Q < 64)
                    atomicAdd(&yup[(((size_t)(b * 64 + P)) * 64 + Q) * 128 + c], acc[mf][nn][r]);
            }
        }
    }
}

__global__ void k_fuse1(const float* __restrict__ in, float* __restrict__ out) {
    size_t idx = (size_t)blockIdx.x * 256 + threadIdx.x;
    if (idx >= (size_t)8 * 1024 * 1024) return;
    int t = (int)(idx & 1023);
    int s = (int)((idx >> 10) & 1023);
    int b = (int)(idx >> 20);
    const float* base = in + ((size_t)b << 20);
    float v = base[(size_t)s * 1024 + t];
    if (s > 0 && t > 0) v += base[(size_t)(s - 1) * 1024 + (t - 1)];
    if (s < 1023 && t < 1023) v += base[(size_t)(s + 1) * 1024 + (t + 1)];
    out[idx] = v;
}

__global__ void k_fuse2(const float* __restrict__ in, float* __restrict__ out) {
    size_t idx = (size_t)blockIdx.x * 256 + threadIdx.x;
    if (idx >= (size_t)8 * 1024 * 1024) return;
    int t = (int)(idx & 1023);
    int s = (int)((idx >> 10) & 1023);
    int b = (int)(idx >> 20);
    int m0 = ((s & 31) << 5) + (s >> 5);
    int n0 = ((t & 31) << 5) + (t >> 5);
    const float* base = in + ((size_t)b << 20);
    float v = 0.f;
#pragma unroll
    for (int d = -1; d <= 1; ++d) {
        int m = m0 + d, n = n0 + d;
        if (m >= 0 && m < 1024 && n >= 0 && n < 1024)
            v += base[(size_t)(((m & 31) << 5) + (m >> 5)) * 1024 + (((n & 31) << 5) + (n >> 5))];
    }
    out[idx] = v;
}

__global__ __launch_bounds__(256) void k_softmax1024(const float* __restrict__ yv,
                                                     const float* __restrict__ mm,
                                                     float* __restrict__ outc) {
    int row = blockIdx.x;
    const float* base = yv + (size_t)row * 1024;
    float mmv = mm[row];
    int t = threadIdx.x;
    float vals[4];
    float mx = -1e30f;
#pragma unroll
    for (int i = 0; i < 4; ++i) {
        vals[i] = base[t + i * 256] * mmv * 10.0f;
        mx = fmaxf(mx, vals[i]);
    }
#pragma unroll
    for (int o = 32; o; o >>= 1) mx = fmaxf(mx, __shfl_xor(mx, o));
    __shared__ float red[8];
    if ((t & 63) == 0) red[t >> 6] = mx;
    __syncthreads();
    mx = fmaxf(fmaxf(red[0], red[1]), fmaxf(red[2], red[3]));
    float s = 0.f;
#pragma unroll
    for (int i = 0; i < 4; ++i) {
        vals[i] = expf(vals[i] - mx);
        s += vals[i];
    }
#pragma unroll
    for (int o = 32; o; o >>= 1) s += __shfl_xor(s, o);
    if ((t & 63) == 0) red[4 + (t >> 6)] = s;
    __syncthreads();
    s = red[4] + red[5] + red[6] + red[7];
    float inv = mmv / s;
#pragma unroll
    for (int i = 0; i < 4; ++i)
        outc[(size_t)row * 1024 + t + i * 256] = vals[i] * inv;
}

// f32 image (8,64,64,128) -> padded bf16 hi/lo pair (8,66,66,128), zero halo
__global__ __launch_bounds__(256) void k_pair_pad(const float* __restrict__ in,
                                                  short* __restrict__ hi, short* __restrict__ lo) {
    int idx = blockIdx.x * 256 + threadIdx.x;   // [0, 8*66*66*16)
    int c8 = idx & 15;
    int r = idx >> 4;
    int pc = r % 66; r /= 66;
    int pr = r % 66; int b = r / 66;
    bf16x8 h, l;
    if (pr >= 1 && pr <= 64 && pc >= 1 && pc <= 64) {
        const float* s = in + (((size_t)(b * 64 + pr - 1)) * 64 + (pc - 1)) * 128 + c8 * 8;
        float4 v0 = *reinterpret_cast<const float4*>(s);
        float4 v1 = *reinterpret_cast<const float4*>(s + 4);
        cvt8(v0, v1, h, l);
    } else {
#pragma unroll
        for (int u = 0; u < 8; ++u) { h[u] = 0; l[u] = 0; }
    }
    size_t off = (size_t)idx * 8;
    *reinterpret_cast<bf16x8*>(hi + off) = h;
    *reinterpret_cast<bf16x8*>(lo + off) = l;
}

__global__ void k_wt_pair(const float* __restrict__ w, short* __restrict__ hi,
                          short* __restrict__ lo, int CI) {
    int idx = blockIdx.x * 256 + threadIdx.x;
    if (idx >= 9 * CI * 128) return;
    int ci = idx % CI; int rest = idx / CI;
    int co = rest & 127; int ij = rest >> 7;
    float v = w[((size_t)ij * CI + ci) * 128 + co];
    short h = f2bf(v);
    hi[idx] = h;
    lo[idx] = f2bf(v - bf2f(h));
}

__global__ void k_pw_bf16(const float* __restrict__ pw, short* __restrict__ out, int n) {
    int idx = blockIdx.x * 256 + threadIdx.x;
    if (idx < n) out[idx] = f2bf(pw[idx]);
}

template <int CI>
__global__ __launch_bounds__(128) void k_dwpw_sm(const float* __restrict__ in0,
                                                 const float* __restrict__ in1,
                                                 const float* __restrict__ dwW,
                                                 const short* __restrict__ pwb,
                                                 const float* __restrict__ db,
                                                 float* __restrict__ smout) {
    int pix = blockIdx.x;
    int b = pix >> 12, P = (pix >> 6) & 63, Q = pix & 63;
    __shared__ float row[CI];
    __shared__ float red[4];
    int t = threadIdx.x;
    for (int c = t; c < CI; c += 128) {
        float acc = 0.f;
#pragma unroll
        for (int i = 0; i < 3; ++i) {
            int rr = P + i - 1;
            if (rr < 0 || rr > 63) continue;
#pragma unroll
            for (int j = 0; j < 3; ++j) {
                int ss = Q + j - 1;
                if (ss < 0 || ss > 63) continue;
                float v = (CI == 128 || c < 128)
                              ? in0[(((size_t)(b * 64 + rr)) * 64 + ss) * 128 + (c & 127)]
                              : in1[(((size_t)(b * 64 + rr)) * 64 + ss) * 128 + (c - 128)];
                acc = fmaf(v, dwW[(i * 3 + j) * CI + c], acc);
            }
        }
        row[c] = acc;
    }
    __syncthreads();
    float acc = db[t];
#pragma unroll 8
    for (int ci = 0; ci < CI; ++ci)
        acc = fmaf(row[ci], bf2f(pwb[(size_t)ci * 128 + t]), acc);
    float m = acc;
#pragma unroll
    for (int o = 32; o; o >>= 1) m = fmaxf(m, __shfl_xor(m, o));
    if ((t & 63) == 0) red[t >> 6] = m;
    __syncthreads();
    m = fmaxf(red[0], red[1]);
    float e = expf(acc - m);
    float s = e;
#pragma unroll
    for (int o = 32; o; o >>= 1) s += __shfl_xor(s, o);
    if ((t & 63) == 0) red[2 + (t >> 6)] = s;
    __syncthreads();
    s = red[2] + red[3];
    smout[(size_t)pix * 128 + t] = e / s;
}

// MFMA split-bf16 implicit-GEMM 3x3 conv + bias + elu + gate multiply.
// Padded inputs [8][66][66][128] (zero halo) -> no bounds checks.
// Grid: 512 1-D blocks, XCD-swizzled so XCD k owns batch k's rows sequentially
// (tap rows stay L2-resident). Block = 1 row x 128 co, 8 waves (512 thr);
// wave = one 16-co tile x 64 px, 4 accumulator chains.
template <int CI>
__global__ __launch_bounds__(512, 4) void k_conv_mfma(const short* __restrict__ in0h,
                                                      const short* __restrict__ in0l,
                                                      const short* __restrict__ in1h,
                                                      const short* __restrict__ in1l,
                                                      const short* __restrict__ wh,
                                                      const short* __restrict__ wl,
                                                      const float* __restrict__ bias,
                                                      const float* __restrict__ sm,
                                                      float* __restrict__ out) {
    const int bid = blockIdx.x;
    const int swz = (bid & 7) * 64 + (bid >> 3);   // bijective, XCD-contiguous rows
    const int b = swz >> 6, P = swz & 63;
    const int wv = threadIdx.x >> 6, lane = threadIdx.x & 63;
    const int m = lane & 15, g = lane >> 4;
    const int co = wv * 16 + m;
    f32x4 acc[4];
#pragma unroll
    for (int mt = 0; mt < 4; ++mt) acc[mt] = f32x4{0.f, 0.f, 0.f, 0.f};
    const size_t pb = (size_t)b * 66 * 66 * 128;
#pragma unroll
    for (int i = 0; i < 3; ++i) {
        const size_t rowb = pb + (size_t)((P + i) * 66) * 128;
#pragma unroll
        for (int j = 0; j < 3; ++j) {
            const int ij = i * 3 + j;
#pragma unroll
            for (int half = 0; half < CI / 128; ++half) {
                const short* sh = (half == 0) ? in0h : in1h;
                const short* sl = (half == 0) ? in0l : in1l;
                const short* wph = wh + ((size_t)ij * 128 + co) * CI + half * 128 + g * 8;
                const short* wpl = wl + ((size_t)ij * 128 + co) * CI + half * 128 + g * 8;
#pragma unroll
                for (int ci0 = 0; ci0 < 128; ci0 += 32) {
                    bf16x8 bh = *reinterpret_cast<const bf16x8*>(wph + ci0);
                    bf16x8 bl = *reinterpret_cast<const bf16x8*>(wpl + ci0);
#pragma unroll
                    for (int mt = 0; mt < 4; ++mt) {
                        size_t off = rowb + (size_t)(mt * 16 + m + j) * 128 + ci0 + g * 8;
                        bf16x8 ah = *reinterpret_cast<const bf16x8*>(sh + off);
                        bf16x8 al = *reinterpret_cast<const bf16x8*>(sl + off);
                        acc[mt] = __builtin_amdgcn_mfma_f32_16x16x32_bf16(ah, bh, acc[mt], 0, 0, 0);
                        acc[mt] = __builtin_amdgcn_mfma_f32_16x16x32_bf16(ah, bl, acc[mt], 0, 0, 0);
                        acc[mt] = __builtin_amdgcn_mfma_f32_16x16x32_bf16(al, bh, acc[mt], 0, 0, 0);
                    }
                }
            }
        }
    }
    const float bb = bias[co];
#pragma unroll
    for (int mt = 0; mt < 4; ++mt) {
#pragma unroll
        for (int r = 0; r < 4; ++r) {
            int Q = mt * 16 + g * 4 + r;
            size_t pix = ((size_t)b * 64 + P) * 64 + Q;
            float z = acc[mt][r] + bb;
            z = z > 0.f ? z : expm1f(z);
            out[pix * 128 + co] = z * sm[pix * 128 + co];
        }
    }
}

extern "C" void kernel_launch(void* const* d_in, const int* in_sizes, int n_in,
                              void* d_out, int out_size, void* d_ws, size_t ws_size,
                              hipStream_t stream) {
    const float* x    = (const float*)d_in[0];
    const float* mask = (const float*)d_in[1];
    const float* w1   = (const float*)d_in[2];
    const float* b1   = (const float*)d_in[3];
    const float* dw1  = (const float*)d_in[4];
    const float* pw1  = (const float*)d_in[5];
    const float* db1  = (const float*)d_in[6];
    const float* w2   = (const float*)d_in[7];
    const float* b2   = (const float*)d_in[8];
    const float* dw2  = (const float*)d_in[9];
    const float* pw2  = (const float*)d_in[10];
    const float* db2  = (const float*)d_in[11];

    float* out_a = (float*)d_out;            // (8,64,64,128)
    float* out_c = out_a + 4194304;          // (8,32,32,1024)

    char* wsb = (char*)d_ws;
    float* sp   = (float*)(wsb + BOFF_SP);
    float* invd = (float*)(wsb + BOFF_INVD);
    short* bfh  = (short*)(wsb + BOFF_BFH);
    short* bfl  = (short*)(wsb + BOFF_BFL);
    float* Tbuf = (float*)(wsb + BOFF_T);
    short* bph  = (short*)(wsb + BOFF_BPH);
    short* bpl  = (short*)(wsb + BOFF_BPL);
    float* yup  = (float*)(wsb + BOFF_YUP);
    float* smb  = (float*)(wsb + BOFF_SM);
    short* p3h  = (short*)(wsb + BOFF_P3H);
    short* p3l  = (short*)(wsb + BOFF_P3L);
    float* a1   = (float*)(wsb + BOFF_A1);
    short* xh   = (short*)(wsb + BOFF_XH);
    short* xl   = (short*)(wsb + BOFF_XL);
    short* wt1h = (short*)(wsb + BOFF_WT1H);
    short* wt1l = (short*)(wsb + BOFF_WT1L);
    short* wt2h = (short*)(wsb + BOFF_WT2H);
    short* wt2l = (short*)(wsb + BOFF_WT2L);
    short* pw1b = (short*)(wsb + BOFF_PW1B);
    short* pw2b = (short*)(wsb + BOFF_PW2B);
    float* m0   = (float*)(wsb + BOFF_M0);
    float* mmb  = (float*)(wsb + BOFF_MM);

    // phase A: mask + correlation (MFMA) + fuse + softmax
    k_mask_pool<<<8192, 256, 0, stream>>>(mask, m0);
    k_mask_dilate<<<32, 256, 0, stream>>>(m0, mmb);
    k_srcpad<<<4624, 256, 0, stream>>>(x, sp);
    k_invd<<<512, 256, 0, stream>>>(sp, invd);
    k_wt_pair<<<576, 256, 0, stream>>>(w1, wt1h, wt1l, 128);
    k_wt_pair<<<1152, 256, 0, stream>>>(w2, wt2h, wt2l, 256);
    k_pw_bf16<<<64, 256, 0, stream>>>(pw1, pw1b, 16384);
    k_pw_bf16<<<128, 256, 0, stream>>>(pw2, pw2b, 32768);
    k_corr_B<<<4608, 256, 0, stream>>>(sp, invd, bfh, bfl);
    k_corr_mfma<<<dim3(8, 16, 8), 256, 0, stream>>>(sp, bfh, bfl, out_c);
    k_fuse1<<<32768, 256, 0, stream>>>(out_c, Tbuf);
    k_fuse2<<<32768, 256, 0, stream>>>(Tbuf, out_c);
    k_deconv_B<<<4608, 256, 0, stream>>>(x, bph, bpl);
    k_softmax1024<<<8192, 256, 0, stream>>>(out_c, mmb, out_c);   // in-place, row-local
    // phase B: deconv (MFMA) -> yup
    hipMemsetAsync(yup, 0, (size_t)4194304 * sizeof(float), stream);
    k_deconv_mfma<<<dim3(9, 16, 8), 256, 0, stream>>>(out_c, bph, bpl, yup);
    // phase C: gated conv 1
    k_dwpw_sm<128><<<32768, 128, 0, stream>>>(yup, nullptr, dw1, pw1b, db1, smb);
    k_pair_pad<<<2178, 256, 0, stream>>>(yup, p3h, p3l);   // yup dead after this
    k_pair_pad<<<2178, 256, 0, stream>>>(x, xh, xl);       // overlaps dead yup tail
    k_conv_mfma<128><<<512, 512, 0, stream>>>(p3h, p3l, nullptr, nullptr,
                                              wt1h, wt1l, b1, smb, a1);
    // phase D: gated conv 2 (concat(a1, x))
    k_dwpw_sm<256><<<32768, 128, 0, stream>>>(a1, x, dw2, pw2b, db2, smb);
    k_pair_pad<<<2178, 256, 0, stream>>>(a1, p3h, p3l);
    k_conv_mfma<256><<<512, 512, 0, stream>>>(p3h, p3l, xh, xl,
                                              wt2h, wt2l, b2, smb, out_a);
}

// Round 6
// 801.065 us; speedup vs baseline: 1.3692x; 1.3692x over previous
//
#include <hip/hip_runtime.h>
#include <hip/hip_bf16.h>

// B=8, H=W=64, C=128, rate=2 -> k=3, h=w=32, L=1024
// Workspace (72,433,664 bytes), time-multiplexed regions (liveness checked):
//  phase A/B: sp [0,4.73M) invd [4.73,5.26M) Bf [5.26,43.0M) T [0,33.55M)
//             Bp [0,37.75M) yup [37.75,54.53M)
//  phase C/D: SM [0,16.78M) P3 pair [16.78,34.62M) A1 [34.62,51.40M)
//             X pair [51.40,69.24M)
//  static:    weights [69.24,71.11M) m0/mm [71.11,71.17M)

#define BOFF_SP      0
#define BOFF_INVD    4734976
#define BOFF_BFH     5259264
#define BOFF_BFL     24133632
#define BOFF_T       0
#define BOFF_BPH     0
#define BOFF_BPL     18874368
#define BOFF_YUP     37748736
#define BOFF_SM      0
#define BOFF_P3H     16777216
#define BOFF_P3L     25698304
#define BOFF_A1      34619392
#define BOFF_XH      51396608
#define BOFF_XL      60317696
#define BOFF_WT1H    69238784
#define BOFF_WT1L    69533696
#define BOFF_WT2H    69828608
#define BOFF_WT2L    70418432
#define BOFF_PW1B    71008256
#define BOFF_PW2B    71041024
#define BOFF_M0      71106560
#define BOFF_MM      71139328

typedef float f32x4 __attribute__((ext_vector_type(4)));
typedef short bf16x8 __attribute__((ext_vector_type(8)));

__device__ __forceinline__ short f2bf(float f) {
    unsigned u = __float_as_uint(f);
    unsigned r = u + 0x7FFFu + ((u >> 16) & 1u);
    return (short)(r >> 16);
}
__device__ __forceinline__ float bf2f(short s) {
    return __uint_as_float(((unsigned)(unsigned short)s) << 16);
}
__device__ __forceinline__ void cvt8(const float4 v0, const float4 v1, bf16x8& h, bf16x8& l) {
    float a[8] = {v0.x, v0.y, v0.z, v0.w, v1.x, v1.y, v1.z, v1.w};
#pragma unroll
    for (int u = 0; u < 8; ++u) {
        short hh = f2bf(a[u]);
        h[u] = hh;
        l[u] = f2bf(a[u] - bf2f(hh));
    }
}

__global__ __launch_bounds__(256) void k_mask_pool(const float* __restrict__ mask, float* __restrict__ m0) {
    int blk = blockIdx.x;
    int b = blk >> 10, pq = blk & 1023, p = pq >> 5, q = pq & 31;
    int t = threadIdx.x, dy = t >> 4, dx = t & 15;
    float v = mask[((size_t)(b * 512 + p * 16 + dy)) * 512 + q * 16 + dx];
#pragma unroll
    for (int o = 32; o; o >>= 1) v = fmaxf(v, __shfl_xor(v, o));
    __shared__ float s[4];
    if ((t & 63) == 0) s[t >> 6] = v;
    __syncthreads();
    if (t == 0) m0[blk] = fmaxf(fmaxf(s[0], s[1]), fmaxf(s[2], s[3]));
}

__global__ void k_mask_dilate(const float* __restrict__ m0, float* __restrict__ mm) {
    int idx = blockIdx.x * 256 + threadIdx.x;
    if (idx >= 8192) return;
    int b = idx >> 10, pq = idx & 1023, p = pq >> 5, q = pq & 31;
    float v = -1e30f;
    for (int di = -1; di <= 1; ++di)
        for (int dj = -1; dj <= 1; ++dj) {
            int pp = p + di, qq = q + dj;
            if (pp >= 0 && pp < 32 && qq >= 0 && qq < 32)
                v = fmaxf(v, m0[(b << 10) + pp * 32 + qq]);
        }
    mm[idx] = 1.0f - v;
}

__global__ void k_srcpad(const float* __restrict__ x, float* __restrict__ sp) {
    int idx = blockIdx.x * 256 + threadIdx.x;
    if (idx >= 8 * 34 * 34 * 128) return;
    int c = idx & 127;
    int r = idx >> 7;
    int xx = r % 34; r /= 34;
    int yy = r % 34; int b = r / 34;
    float v = 0.f;
    if (yy >= 1 && yy <= 32 && xx >= 1 && xx <= 32)
        v = x[(((size_t)(b * 64 + (yy - 1) * 2)) * 64 + (xx - 1) * 2) * 128 + c];
    sp[idx] = v;
}

__global__ void k_invd(const float* __restrict__ sp, float* __restrict__ invd) {
    int idx = blockIdx.x * 256 + threadIdx.x;
    if (idx >= 1024 * 128) return;
    int c = idx & 127, l = idx >> 7, lh = l >> 5, lw = l & 31;
    float s = 0.f;
    for (int b = 0; b < 8; ++b)
#pragma unroll
        for (int i = 0; i < 3; ++i)
#pragma unroll
            for (int j = 0; j < 3; ++j) {
                float v = sp[(((size_t)(b * 34 + lh + i)) * 34 + (lw + j)) * 128 + c];
                s += v * v;
            }
    invd[idx] = 1.0f / fmaxf(s, 1e-8f);
}

// Bf[b][l][ij][c] = sp[b][lh+i][lw+j][c] * invd[l][c], split bf16 pair.
__global__ void k_corr_B(const float* __restrict__ sp, const float* __restrict__ invd,
                         short* __restrict__ bh, short* __restrict__ bl) {
    int idx = blockIdx.x * 256 + threadIdx.x;
    int c8 = idx & 15; int rest = idx >> 4;
    int ij = rest % 9; int rest2 = rest / 9;
    int l = rest2 & 1023, b = rest2 >> 10;
    int lh = l >> 5, lw = l & 31;
    int i = (ij >= 6) ? 2 : (ij >= 3 ? 1 : 0);
    int j = ij - 3 * i;
    int c0 = c8 * 8;
    const float* s = sp + (((size_t)(b * 34 + lh + i)) * 34 + (lw + j)) * 128 + c0;
    const float* dv = invd + l * 128 + c0;
    bf16x8 h, lo;
#pragma unroll
    for (int u = 0; u < 8; ++u) {
        float v = s[u] * dv[u];
        short hh = f2bf(v);
        h[u] = hh;
        lo[u] = f2bf(v - bf2f(hh));
    }
    size_t off = ((size_t)(b * 1024 + l)) * 1152 + ij * 128 + c0;
    *reinterpret_cast<bf16x8*>(bh + off) = h;
    *reinterpret_cast<bf16x8*>(bl + off) = lo;
}

// Bp[b][ij][c][l] = x[b][2lh+ip][2lw+jp][c] (0 OOB), split bf16 pair.
__global__ void k_deconv_B(const float* __restrict__ x, short* __restrict__ bh, short* __restrict__ bl) {
    int idx = blockIdx.x * 256 + threadIdx.x;
    int l8 = idx & 127; int rest = idx >> 7;
    int c = rest & 127; int rest2 = rest >> 7;
    int ij = rest2 % 9; int b = rest2 / 9;
    int ip = (ij >= 6) ? 2 : (ij >= 3 ? 1 : 0);
    int jp = ij - 3 * ip;
    int l0 = l8 * 8;
    int lh = l0 >> 5, lw0 = l0 & 31;
    int rr = 2 * lh + ip;
    bf16x8 h, lo;
#pragma unroll
    for (int u = 0; u < 8; ++u) {
        int ss = 2 * (lw0 + u) + jp;
        float v = (rr < 64 && ss < 64) ? x[(((size_t)(b * 64 + rr)) * 64 + ss) * 128 + c] : 0.f;
        short hh = f2bf(v);
        h[u] = hh;
        lo[u] = f2bf(v - bf2f(hh));
    }
    size_t off = (((size_t)(b * 9 + ij)) * 128 + c) * 1024 + l0;
    *reinterpret_cast<bf16x8*>(bh + off) = h;
    *reinterpret_cast<bf16x8*>(bl + off) = lo;
}

// corr MFMA: per batch y[pq,l] = sum_k A[pq,k]*B[k,l]; M=1024,N=1024,K=1152.
// LDS rows padded 32->40 shorts (stride 20 words -> 2-way bank aliasing, free).
__global__ __launch_bounds__(256) void k_corr_mfma(const float* __restrict__ sp,
                                                   const short* __restrict__ bfh,
                                                   const short* __restrict__ bfl,
                                                   float* __restrict__ outy) {
    const int b = blockIdx.z, tm = blockIdx.y, tn = blockIdx.x;
    __shared__ short Ah[64][40];
    __shared__ short Al[64][40];
    const int tid = threadIdx.x;
    const int w = tid >> 6, lane = tid & 63, m = lane & 15, g = lane >> 4;
    f32x4 acc[4][2];
#pragma unroll
    for (int mf = 0; mf < 4; ++mf)
#pragma unroll
        for (int nn = 0; nn < 2; ++nn) acc[mf][nn] = f32x4{0.f, 0.f, 0.f, 0.f};
    const int srow = tid >> 2, scc = (tid & 3) * 8;
    const int pq = tm * 64 + srow, p = pq >> 5, q = pq & 31;
    const int col0 = tn * 128 + w * 32 + m;
    const size_t bB = (size_t)b * 1024;
    for (int kt = 0; kt < 1152; kt += 32) {
        int ij = kt >> 7;
        int i = (ij >= 6) ? 2 : (ij >= 3 ? 1 : 0);
        int j = ij - 3 * i;
        int c0 = (kt & 127) + scc;
        const float* s = sp + (((size_t)(b * 34 + p + i)) * 34 + (q + j)) * 128 + c0;
        float4 v0 = *reinterpret_cast<const float4*>(s);
        float4 v1 = *reinterpret_cast<const float4*>(s + 4);
        bf16x8 hh, ll;
        cvt8(v0, v1, hh, ll);
        __syncthreads();
        *reinterpret_cast<bf16x8*>(&Ah[srow][scc]) = hh;
        *reinterpret_cast<bf16x8*>(&Al[srow][scc]) = ll;
        __syncthreads();
        bf16x8 ah[4], al[4];
#pragma unroll
        for (int mf = 0; mf < 4; ++mf) {
            ah[mf] = *reinterpret_cast<const bf16x8*>(&Ah[mf * 16 + m][g * 8]);
            al[mf] = *reinterpret_cast<const bf16x8*>(&Al[mf * 16 + m][g * 8]);
        }
#pragma unroll
        for (int nn = 0; nn < 2; ++nn) {
            size_t off = (bB + col0 + nn * 16) * 1152 + kt + g * 8;
            bf16x8 bh = *reinterpret_cast<const bf16x8*>(bfh + off);
            bf16x8 bl = *reinterpret_cast<const bf16x8*>(bfl + off);
#pragma unroll
            for (int mf = 0; mf < 4; ++mf) {
                acc[mf][nn] = __builtin_amdgcn_mfma_f32_16x16x32_bf16(ah[mf], bh, acc[mf][nn], 0, 0, 0);
                acc[mf][nn] = __builtin_amdgcn_mfma_f32_16x16x32_bf16(al[mf], bh, acc[mf][nn], 0, 0, 0);
                acc[mf][nn] = __builtin_amdgcn_mfma_f32_16x16x32_bf16(ah[mf], bl, acc[mf][nn], 0, 0, 0);
            }
        }
    }
#pragma unroll
    for (int mf = 0; mf < 4; ++mf) {
        int row = tm * 64 + mf * 16 + g * 4;
#pragma unroll
        for (int nn = 0; nn < 2; ++nn) {
            int col = col0 + nn * 16;
#pragma unroll
            for (int r = 0; r < 4; ++r)
                outy[((size_t)b << 20) + (size_t)(row + r) * 1024 + col] = acc[mf][nn][r];
        }
    }
}

// deconv MFMA: per batch Z[uv,kcol] = sum_l y[uv,l]*Bp[kcol,l]; M=1024,N=1152,K=1024.
__global__ __launch_bounds__(256) void k_deconv_mfma(const float* __restrict__ yprob,
                                                     const short* __restrict__ bph,
                                                     const short* __restrict__ bpl,
                                                     float* __restrict__ yup) {
    const int b = blockIdx.z, tm = blockIdx.y, tn = blockIdx.x;   // tn = ij in 0..8
    __shared__ short Ah[64][40];
    __shared__ short Al[64][40];
    const int tid = threadIdx.x;
    const int w = tid >> 6, lane = tid & 63, m = lane & 15, g = lane >> 4;
    f32x4 acc[4][2];
#pragma unroll
    for (int mf = 0; mf < 4; ++mf)
#pragma unroll
        for (int nn = 0; nn < 2; ++nn) acc[mf][nn] = f32x4{0.f, 0.f, 0.f, 0.f};
    const int srow = tid >> 2, scc = (tid & 3) * 8;
    const int uvs = tm * 64 + srow;
    const int col0 = tn * 128 + w * 32 + m;
    for (int kt = 0; kt < 1024; kt += 32) {
        const float* s = yprob + ((size_t)b << 20) + (size_t)uvs * 1024 + kt + scc;
        float4 v0 = *reinterpret_cast<const float4*>(s);
        float4 v1 = *reinterpret_cast<const float4*>(s + 4);
        bf16x8 hh, ll;
        cvt8(v0, v1, hh, ll);
        __syncthreads();
        *reinterpret_cast<bf16x8*>(&Ah[srow][scc]) = hh;
        *reinterpret_cast<bf16x8*>(&Al[srow][scc]) = ll;
        __syncthreads();
        bf16x8 ah[4], al[4];
#pragma unroll
        for (int mf = 0; mf < 4; ++mf) {
            ah[mf] = *reinterpret_cast<const bf16x8*>(&Ah[mf * 16 + m][g * 8]);
            al[mf] = *reinterpret_cast<const bf16x8*>(&Al[mf * 16 + m][g * 8]);
        }
#pragma unroll
        for (int nn = 0; nn < 2; ++nn) {
            size_t off = ((size_t)b * 1152 + col0 + nn * 16) * 1024 + kt + g * 8;
            bf16x8 bh = *reinterpret_cast<const bf16x8*>(bph + off);
            bf16x8 bl = *reinterpret_cast<const bf16x8*>(bpl + off);
#pragma unroll
            for (int mf = 0; mf < 4; ++mf) {
                acc[mf][nn] = __builtin_amdgcn_mfma_f32_16x16x32_bf16(ah[mf], bh, acc[mf][nn], 0, 0, 0);
                acc[mf][nn] = __builtin_amdgcn_mfma_f32_16x16x32_bf16(al[mf], bh, acc[mf][nn], 0, 0, 0);
                acc[mf][nn] = __builtin_amdgcn_mfma_f32_16x16x32_bf16(ah[mf], bl, acc[mf][nn], 0, 0, 0);
            }
        }
    }
    const int ip = (tn >= 6) ? 2 : (tn >= 3 ? 1 : 0);
    const int jp = tn - 3 * ip;
#pragma unroll
    for (int mf = 0; mf < 4; ++mf) {
        int uvb = tm * 64 + mf * 16 + g * 4;
#pragma unroll
        for (int nn = 0; nn < 2; ++nn) {
            int c = w * 32 + nn * 16 + m;
#pragma unroll
            for (int r = 0; r < 4; ++r) {
                int uv = uvb + r;
                int uu = uv >> 5, vv = uv & 31;
                int P = 2 * uu + ip, Q = 2 * vv + jp;
                if (P < 64 && Q < 64)
                    atomicAdd(&yup[(((size_t)(b * 64 + P)) * 64 + Q) * 128 + c], acc[mf][nn][r]);
            }
        }
    }
}

__global__ void k_fuse1(const float* __restrict__ in, float* __restrict__ out) {
    size_t idx = (size_t)blockIdx.x * 256 + threadIdx.x;
    if (idx >= (size_t)8 * 1024 * 1024) return;
    int t = (int)(idx & 1023);
    int s = (int)((idx >> 10) & 1023);
    int b = (int)(idx >> 20);
    const float* base = in + ((size_t)b << 20);
    float v = base[(size_t)s * 1024 + t];
    if (s > 0 && t > 0) v += base[(size_t)(s - 1) * 1024 + (t - 1)];
    if (s < 1023 && t < 1023) v += base[(size_t)(s + 1) * 1024 + (t + 1)];
    out[idx] = v;
}

__global__ void k_fuse2(const float* __restrict__ in, float* __restrict__ out) {
    size_t idx = (size_t)blockIdx.x * 256 + threadIdx.x;
    if (idx >= (size_t)8 * 1024 * 1024) return;
    int t = (int)(idx & 1023);
    int s = (int)((idx >> 10) & 1023);
    int b = (int)(idx >> 20);
    int m0 = ((s & 31) << 5) + (s >> 5);
    int n0 = ((t & 31) << 5) + (t >> 5);
    const float* base = in + ((size_t)b << 20);
    float v = 0.f;
#pragma unroll
    for (int d = -1; d <= 1; ++d) {
        int m = m0 + d, n = n0 + d;
        if (m >= 0 && m < 1024 && n >= 0 && n < 1024)
            v += base[(size_t)(((m & 31) << 5) + (m >> 5)) * 1024 + (((n & 31) << 5) + (n >> 5))];
    }
    out[idx] = v;
}

__global__ __launch_bounds__(256) void k_softmax1024(const float* __restrict__ yv,
                                                     const float* __restrict__ mm,
                                                     float* __restrict__ outc) {
    int row = blockIdx.x;
    const float* base = yv + (size_t)row * 1024;
    float mmv = mm[row];
    int t = threadIdx.x;
    float vals[4];
    float mx = -1e30f;
#pragma unroll
    for (int i = 0; i < 4; ++i) {
        vals[i] = base[t + i * 256] * mmv * 10.0f;
        mx = fmaxf(mx, vals[i]);
    }
#pragma unroll
    for (int o = 32; o; o >>= 1) mx = fmaxf(mx, __shfl_xor(mx, o));
    __shared__ float red[8];
    if ((t & 63) == 0) red[t >> 6] = mx;
    __syncthreads();
    mx = fmaxf(fmaxf(red[0], red[1]), fmaxf(red[2], red[3]));
    float s = 0.f;
#pragma unroll
    for (int i = 0; i < 4; ++i) {
        vals[i] = expf(vals[i] - mx);
        s += vals[i];
    }
#pragma unroll
    for (int o = 32; o; o >>= 1) s += __shfl_xor(s, o);
    if ((t & 63) == 0) red[4 + (t >> 6)] = s;
    __syncthreads();
    s = red[4] + red[5] + red[6] + red[7];
    float inv = mmv / s;
#pragma unroll
    for (int i = 0; i < 4; ++i)
        outc[(size_t)row * 1024 + t + i * 256] = vals[i] * inv;
}

// f32 image (8,64,64,128) -> padded bf16 hi/lo pair (8,66,66,128), zero halo
__global__ __launch_bounds__(256) void k_pair_pad(const float* __restrict__ in,
                                                  short* __restrict__ hi, short* __restrict__ lo) {
    int idx = blockIdx.x * 256 + threadIdx.x;   // [0, 8*66*66*16)
    int c8 = idx & 15;
    int r = idx >> 4;
    int pc = r % 66; r /= 66;
    int pr = r % 66; int b = r / 66;
    bf16x8 h, l;
    if (pr >= 1 && pr <= 64 && pc >= 1 && pc <= 64) {
        const float* s = in + (((size_t)(b * 64 + pr - 1)) * 64 + (pc - 1)) * 128 + c8 * 8;
        float4 v0 = *reinterpret_cast<const float4*>(s);
        float4 v1 = *reinterpret_cast<const float4*>(s + 4);
        cvt8(v0, v1, h, l);
    } else {
#pragma unroll
        for (int u = 0; u < 8; ++u) { h[u] = 0; l[u] = 0; }
    }
    size_t off = (size_t)idx * 8;
    *reinterpret_cast<bf16x8*>(hi + off) = h;
    *reinterpret_cast<bf16x8*>(lo + off) = l;
}

__global__ void k_wt_pair(const float* __restrict__ w, short* __restrict__ hi,
                          short* __restrict__ lo, int CI) {
    int idx = blockIdx.x * 256 + threadIdx.x;
    if (idx >= 9 * CI * 128) return;
    int ci = idx % CI; int rest = idx / CI;
    int co = rest & 127; int ij = rest >> 7;
    float v = w[((size_t)ij * CI + ci) * 128 + co];
    short h = f2bf(v);
    hi[idx] = h;
    lo[idx] = f2bf(v - bf2f(h));
}

__global__ void k_pw_bf16(const float* __restrict__ pw, short* __restrict__ out, int n) {
    int idx = blockIdx.x * 256 + threadIdx.x;
    if (idx < n) out[idx] = f2bf(pw[idx]);
}

template <int CI>
__global__ __launch_bounds__(128) void k_dwpw_sm(const float* __restrict__ in0,
                                                 const float* __restrict__ in1,
                                                 const float* __restrict__ dwW,
                                                 const short* __restrict__ pwb,
                                                 const float* __restrict__ db,
                                                 float* __restrict__ smout) {
    int pix = blockIdx.x;
    int b = pix >> 12, P = (pix >> 6) & 63, Q = pix & 63;
    __shared__ float row[CI];
    __shared__ float red[4];
    int t = threadIdx.x;
    for (int c = t; c < CI; c += 128) {
        float acc = 0.f;
#pragma unroll
        for (int i = 0; i < 3; ++i) {
            int rr = P + i - 1;
            if (rr < 0 || rr > 63) continue;
#pragma unroll
            for (int j = 0; j < 3; ++j) {
                int ss = Q + j - 1;
                if (ss < 0 || ss > 63) continue;
                float v = (CI == 128 || c < 128)
                              ? in0[(((size_t)(b * 64 + rr)) * 64 + ss) * 128 + (c & 127)]
                              : in1[(((size_t)(b * 64 + rr)) * 64 + ss) * 128 + (c - 128)];
                acc = fmaf(v, dwW[(i * 3 + j) * CI + c], acc);
            }
        }
        row[c] = acc;
    }
    __syncthreads();
    float acc = db[t];
#pragma unroll 8
    for (int ci = 0; ci < CI; ++ci)
        acc = fmaf(row[ci], bf2f(pwb[(size_t)ci * 128 + t]), acc);
    float m = acc;
#pragma unroll
    for (int o = 32; o; o >>= 1) m = fmaxf(m, __shfl_xor(m, o));
    if ((t & 63) == 0) red[t >> 6] = m;
    __syncthreads();
    m = fmaxf(red[0], red[1]);
    float e = expf(acc - m);
    float s = e;
#pragma unroll
    for (int o = 32; o; o >>= 1) s += __shfl_xor(s, o);
    if ((t & 63) == 0) red[2 + (t >> 6)] = s;
    __syncthreads();
    s = red[2] + red[3];
    smout[(size_t)pix * 128 + t] = e / s;
}

// MFMA split-bf16 implicit-GEMM 3x3 conv + bias + elu + gate, LDS-staged rows.
// Padded inputs [8][66][66][128] (zero halo). Block = (b,P): 64 px x 128 co,
// 4 waves x 2 co-tiles. Per (half,i): stage row P+i (both planes, XOR-swizzled)
// in LDS once; fragments come from ds_read_b128 instead of strided L2 loads.
template <int CI>
__global__ __launch_bounds__(256, 4) void k_conv_lds(const short* __restrict__ in0h,
                                                     const short* __restrict__ in0l,
                                                     const short* __restrict__ in1h,
                                                     const short* __restrict__ in1l,
                                                     const short* __restrict__ wh,
                                                     const short* __restrict__ wl,
                                                     const float* __restrict__ bias,
                                                     const float* __restrict__ sm,
                                                     float* __restrict__ out) {
    const int bid = blockIdx.x;
    const int swz = (bid & 7) * 64 + (bid >> 3);   // XCD-contiguous rows
    const int b = swz >> 6, P = swz & 63;
    const int tid = threadIdx.x;
    const int w = tid >> 6, lane = tid & 63;
    const int m = lane & 15, g = lane >> 4;
    __shared__ short Sh[66 * 128];
    __shared__ short Sl[66 * 128];
    char* shb = (char*)Sh;
    char* slb = (char*)Sl;
    f32x4 acc[4][2];
#pragma unroll
    for (int mt = 0; mt < 4; ++mt)
#pragma unroll
        for (int nn = 0; nn < 2; ++nn) acc[mt][nn] = f32x4{0.f, 0.f, 0.f, 0.f};

#pragma unroll
    for (int half = 0; half < CI / 128; ++half) {
        const short* ih = (half == 0) ? in0h : in1h;
        const short* il = (half == 0) ? in0l : in1l;
        const size_t rbase0 = ((size_t)b * 66 + P) * 66 * 128;
#pragma unroll
        for (int i = 0; i < 3; ++i) {
            // ---- stage row P+i (padded coords), swizzled ----
            __syncthreads();   // previous compute done before overwrite
            const size_t rsrc = rbase0 + (size_t)i * 66 * 128;
#pragma unroll
            for (int e0 = 0; e0 < 1056; e0 += 256) {
                int e = e0 + tid;
                if (e < 1056) {
                    int px = e >> 4, c8 = e & 15;
                    int lin = px * 256 + c8 * 16;
                    int sz = lin ^ ((px & 7) << 4);
                    size_t so = rsrc + (size_t)px * 128 + c8 * 8;
                    *reinterpret_cast<bf16x8*>(shb + sz) = *reinterpret_cast<const bf16x8*>(ih + so);
                    *reinterpret_cast<bf16x8*>(slb + sz) = *reinterpret_cast<const bf16x8*>(il + so);
                }
            }
            __syncthreads();
            // ---- compute: 3 j-taps x 4 ci-chunks ----
#pragma unroll
            for (int j = 0; j < 3; ++j) {
                const int ij = i * 3 + j;
                const short* wph = wh + ((size_t)ij * 128 + w * 32 + m) * CI + half * 128 + g * 8;
                const short* wpl = wl + ((size_t)ij * 128 + w * 32 + m) * CI + half * 128 + g * 8;
#pragma unroll
                for (int ci0 = 0; ci0 < 128; ci0 += 32) {
                    bf16x8 bhv[2], blv[2];
#pragma unroll
                    for (int nn = 0; nn < 2; ++nn) {
                        bhv[nn] = *reinterpret_cast<const bf16x8*>(wph + (size_t)nn * 16 * CI + ci0);
                        blv[nn] = *reinterpret_cast<const bf16x8*>(wpl + (size_t)nn * 16 * CI + ci0);
                    }
                    bf16x8 ah[4], al[4];
#pragma unroll
                    for (int mt = 0; mt < 4; ++mt) {
                        int px = mt * 16 + m + j;
                        int lin = px * 256 + ci0 * 2 + g * 16;
                        int sz = lin ^ ((px & 7) << 4);
                        ah[mt] = *reinterpret_cast<const bf16x8*>(shb + sz);
                        al[mt] = *reinterpret_cast<const bf16x8*>(slb + sz);
                    }
#pragma unroll
                    for (int nn = 0; nn < 2; ++nn)
#pragma unroll
                        for (int mt = 0; mt < 4; ++mt) {
                            acc[mt][nn] = __builtin_amdgcn_mfma_f32_16x16x32_bf16(ah[mt], bhv[nn], acc[mt][nn], 0, 0, 0);
                            acc[mt][nn] = __builtin_amdgcn_mfma_f32_16x16x32_bf16(ah[mt], blv[nn], acc[mt][nn], 0, 0, 0);
                            acc[mt][nn] = __builtin_amdgcn_mfma_f32_16x16x32_bf16(al[mt], bhv[nn], acc[mt][nn], 0, 0, 0);
                        }
                }
            }
        }
    }
#pragma unroll
    for (int nn = 0; nn < 2; ++nn) {
        const int co = w * 32 + nn * 16 + m;
        const float bb = bias[co];
#pragma unroll
        for (int mt = 0; mt < 4; ++mt) {
#pragma unroll
            for (int r = 0; r < 4; ++r) {
                int Q = mt * 16 + g * 4 + r;
                size_t pix = ((size_t)b * 64 + P) * 64 + Q;
                float z = acc[mt][nn][r] + bb;
                z = z > 0.f ? z : expm1f(z);
                out[pix * 128 + co] = z * sm[pix * 128 + co];
            }
        }
    }
}

extern "C" void kernel_launch(void* const* d_in, const int* in_sizes, int n_in,
                              void* d_out, int out_size, void* d_ws, size_t ws_size,
                              hipStream_t stream) {
    const float* x    = (const float*)d_in[0];
    const float* mask = (const float*)d_in[1];
    const float* w1   = (const float*)d_in[2];
    const float* b1   = (const float*)d_in[3];
    const float* dw1  = (const float*)d_in[4];
    const float* pw1  = (const float*)d_in[5];
    const float* db1  = (const float*)d_in[6];
    const float* w2   = (const float*)d_in[7];
    const float* b2   = (const float*)d_in[8];
    const float* dw2  = (const float*)d_in[9];
    const float* pw2  = (const float*)d_in[10];
    const float* db2  = (const float*)d_in[11];

    float* out_a = (float*)d_out;            // (8,64,64,128)
    float* out_c = out_a + 4194304;          // (8,32,32,1024)

    char* wsb = (char*)d_ws;
    float* sp   = (float*)(wsb + BOFF_SP);
    float* invd = (float*)(wsb + BOFF_INVD);
    short* bfh  = (short*)(wsb + BOFF_BFH);
    short* bfl  = (short*)(wsb + BOFF_BFL);
    float* Tbuf = (float*)(wsb + BOFF_T);
    short* bph  = (short*)(wsb + BOFF_BPH);
    short* bpl  = (short*)(wsb + BOFF_BPL);
    float* yup  = (float*)(wsb + BOFF_YUP);
    float* smb  = (float*)(wsb + BOFF_SM);
    short* p3h  = (short*)(wsb + BOFF_P3H);
    short* p3l  = (short*)(wsb + BOFF_P3L);
    float* a1   = (float*)(wsb + BOFF_A1);
    short* xh   = (short*)(wsb + BOFF_XH);
    short* xl   = (short*)(wsb + BOFF_XL);
    short* wt1h = (short*)(wsb + BOFF_WT1H);
    short* wt1l = (short*)(wsb + BOFF_WT1L);
    short* wt2h = (short*)(wsb + BOFF_WT2H);
    short* wt2l = (short*)(wsb + BOFF_WT2L);
    short* pw1b = (short*)(wsb + BOFF_PW1B);
    short* pw2b = (short*)(wsb + BOFF_PW2B);
    float* m0   = (float*)(wsb + BOFF_M0);
    float* mmb  = (float*)(wsb + BOFF_MM);

    // phase A: mask + correlation (MFMA) + fuse + softmax
    k_mask_pool<<<8192, 256, 0, stream>>>(mask, m0);
    k_mask_dilate<<<32, 256, 0, stream>>>(m0, mmb);
    k_srcpad<<<4624, 256, 0, stream>>>(x, sp);
    k_invd<<<512, 256, 0, stream>>>(sp, invd);
    k_wt_pair<<<576, 256, 0, stream>>>(w1, wt1h, wt1l, 128);
    k_wt_pair<<<1152, 256, 0, stream>>>(w2, wt2h, wt2l, 256);
    k_pw_bf16<<<64, 256, 0, stream>>>(pw1, pw1b, 16384);
    k_pw_bf16<<<128, 256, 0, stream>>>(pw2, pw2b, 32768);
    k_corr_B<<<4608, 256, 0, stream>>>(sp, invd, bfh, bfl);
    k_corr_mfma<<<dim3(8, 16, 8), 256, 0, stream>>>(sp, bfh, bfl, out_c);
    k_fuse1<<<32768, 256, 0, stream>>>(out_c, Tbuf);
    k_fuse2<<<32768, 256, 0, stream>>>(Tbuf, out_c);
    k_deconv_B<<<4608, 256, 0, stream>>>(x, bph, bpl);
    k_softmax1024<<<8192, 256, 0, stream>>>(out_c, mmb, out_c);   // in-place, row-local
    // phase B: deconv (MFMA) -> yup
    hipMemsetAsync(yup, 0, (size_t)4194304 * sizeof(float), stream);
    k_deconv_mfma<<<dim3(9, 16, 8), 256, 0, stream>>>(out_c, bph, bpl, yup);
    // phase C: gated conv 1
    k_dwpw_sm<128><<<32768, 128, 0, stream>>>(yup, nullptr, dw1, pw1b, db1, smb);
    k_pair_pad<<<2178, 256, 0, stream>>>(yup, p3h, p3l);   // yup dead after this
    k_pair_pad<<<2178, 256, 0, stream>>>(x, xh, xl);       // overlaps dead yup tail
    k_conv_lds<128><<<512, 256, 0, stream>>>(p3h, p3l, nullptr, nullptr,
                                             wt1h, wt1l, b1, smb, a1);
    // phase D: gated conv 2 (concat(a1, x))
    k_dwpw_sm<256><<<32768, 128, 0, stream>>>(a1, x, dw2, pw2b, db2, smb);
    k_pair_pad<<<2178, 256, 0, stream>>>(a1, p3h, p3l);
    k_conv_lds<256><<<512, 256, 0, stream>>>(p3h, p3l, xh, xl,
                                             wt2h, wt2l, b2, smb, out_a);
}

// Round 7
// 699.300 us; speedup vs baseline: 1.5685x; 1.1455x over previous
//
#include <hip/hip_runtime.h>
#include <hip/hip_bf16.h>

// B=8, H=W=64, C=128, rate=2 -> k=3, h=w=32, L=1024
// Workspace (72,433,664 bytes), time-multiplexed regions (liveness checked):
//  phase A/B: sp [0,4.73M) invd [4.73,5.26M) Bf [5.26,43.0M) T [0,33.55M)
//             Bp [0,37.75M) yup [37.75,54.53M)
//  phase C/D: SM [0,16.78M) P3 pair [16.78,34.62M) A1 [34.62,51.40M)
//             X pair [51.40,69.24M)
//  static:    weights [69.24,71.11M) m0/mm [71.11,71.17M)

#define BOFF_SP      0
#define BOFF_INVD    4734976
#define BOFF_BFH     5259264
#define BOFF_BFL     24133632
#define BOFF_T       0
#define BOFF_BPH     0
#define BOFF_BPL     18874368
#define BOFF_YUP     37748736
#define BOFF_SM      0
#define BOFF_P3H     16777216
#define BOFF_P3L     25698304
#define BOFF_A1      34619392
#define BOFF_XH      51396608
#define BOFF_XL      60317696
#define BOFF_WT1H    69238784
#define BOFF_WT1L    69533696
#define BOFF_WT2H    69828608
#define BOFF_WT2L    70418432
#define BOFF_PW1B    71008256
#define BOFF_PW2B    71041024
#define BOFF_M0      71106560
#define BOFF_MM      71139328

typedef float f32x4 __attribute__((ext_vector_type(4)));
typedef short bf16x8 __attribute__((ext_vector_type(8)));

__device__ __forceinline__ short f2bf(float f) {
    unsigned u = __float_as_uint(f);
    unsigned r = u + 0x7FFFu + ((u >> 16) & 1u);
    return (short)(r >> 16);
}
__device__ __forceinline__ float bf2f(short s) {
    return __uint_as_float(((unsigned)(unsigned short)s) << 16);
}
__device__ __forceinline__ void cvt8(const float4 v0, const float4 v1, bf16x8& h, bf16x8& l) {
    float a[8] = {v0.x, v0.y, v0.z, v0.w, v1.x, v1.y, v1.z, v1.w};
#pragma unroll
    for (int u = 0; u < 8; ++u) {
        short hh = f2bf(a[u]);
        h[u] = hh;
        l[u] = f2bf(a[u] - bf2f(hh));
    }
}

__global__ __launch_bounds__(256) void k_mask_pool(const float* __restrict__ mask, float* __restrict__ m0) {
    int blk = blockIdx.x;
    int b = blk >> 10, pq = blk & 1023, p = pq >> 5, q = pq & 31;
    int t = threadIdx.x, dy = t >> 4, dx = t & 15;
    float v = mask[((size_t)(b * 512 + p * 16 + dy)) * 512 + q * 16 + dx];
#pragma unroll
    for (int o = 32; o; o >>= 1) v = fmaxf(v, __shfl_xor(v, o));
    __shared__ float s[4];
    if ((t & 63) == 0) s[t >> 6] = v;
    __syncthreads();
    if (t == 0) m0[blk] = fmaxf(fmaxf(s[0], s[1]), fmaxf(s[2], s[3]));
}

__global__ void k_mask_dilate(const float* __restrict__ m0, float* __restrict__ mm) {
    int idx = blockIdx.x * 256 + threadIdx.x;
    if (idx >= 8192) return;
    int b = idx >> 10, pq = idx & 1023, p = pq >> 5, q = pq & 31;
    float v = -1e30f;
    for (int di = -1; di <= 1; ++di)
        for (int dj = -1; dj <= 1; ++dj) {
            int pp = p + di, qq = q + dj;
            if (pp >= 0 && pp < 32 && qq >= 0 && qq < 32)
                v = fmaxf(v, m0[(b << 10) + pp * 32 + qq]);
        }
    mm[idx] = 1.0f - v;
}

__global__ void k_srcpad(const float* __restrict__ x, float* __restrict__ sp) {
    int idx = blockIdx.x * 256 + threadIdx.x;
    if (idx >= 8 * 34 * 34 * 128) return;
    int c = idx & 127;
    int r = idx >> 7;
    int xx = r % 34; r /= 34;
    int yy = r % 34; int b = r / 34;
    float v = 0.f;
    if (yy >= 1 && yy <= 32 && xx >= 1 && xx <= 32)
        v = x[(((size_t)(b * 64 + (yy - 1) * 2)) * 64 + (xx - 1) * 2) * 128 + c];
    sp[idx] = v;
}

__global__ void k_invd(const float* __restrict__ sp, float* __restrict__ invd) {
    int idx = blockIdx.x * 256 + threadIdx.x;
    if (idx >= 1024 * 128) return;
    int c = idx & 127, l = idx >> 7, lh = l >> 5, lw = l & 31;
    float s = 0.f;
    for (int b = 0; b < 8; ++b)
#pragma unroll
        for (int i = 0; i < 3; ++i)
#pragma unroll
            for (int j = 0; j < 3; ++j) {
                float v = sp[(((size_t)(b * 34 + lh + i)) * 34 + (lw + j)) * 128 + c];
                s += v * v;
            }
    invd[idx] = 1.0f / fmaxf(s, 1e-8f);
}

// Bf[b][l][ij][c] = sp[b][lh+i][lw+j][c] * invd[l][c], split bf16 pair.
__global__ void k_corr_B(const float* __restrict__ sp, const float* __restrict__ invd,
                         short* __restrict__ bh, short* __restrict__ bl) {
    int idx = blockIdx.x * 256 + threadIdx.x;
    int c8 = idx & 15; int rest = idx >> 4;
    int ij = rest % 9; int rest2 = rest / 9;
    int l = rest2 & 1023, b = rest2 >> 10;
    int lh = l >> 5, lw = l & 31;
    int i = (ij >= 6) ? 2 : (ij >= 3 ? 1 : 0);
    int j = ij - 3 * i;
    int c0 = c8 * 8;
    const float* s = sp + (((size_t)(b * 34 + lh + i)) * 34 + (lw + j)) * 128 + c0;
    const float* dv = invd + l * 128 + c0;
    bf16x8 h, lo;
#pragma unroll
    for (int u = 0; u < 8; ++u) {
        float v = s[u] * dv[u];
        short hh = f2bf(v);
        h[u] = hh;
        lo[u] = f2bf(v - bf2f(hh));
    }
    size_t off = ((size_t)(b * 1024 + l)) * 1152 + ij * 128 + c0;
    *reinterpret_cast<bf16x8*>(bh + off) = h;
    *reinterpret_cast<bf16x8*>(bl + off) = lo;
}

// Bp[b][ij][c][l] = x[b][2lh+ip][2lw+jp][c] (0 OOB), split bf16 pair.
__global__ void k_deconv_B(const float* __restrict__ x, short* __restrict__ bh, short* __restrict__ bl) {
    int idx = blockIdx.x * 256 + threadIdx.x;
    int l8 = idx & 127; int rest = idx >> 7;
    int c = rest & 127; int rest2 = rest >> 7;
    int ij = rest2 % 9; int b = rest2 / 9;
    int ip = (ij >= 6) ? 2 : (ij >= 3 ? 1 : 0);
    int jp = ij - 3 * ip;
    int l0 = l8 * 8;
    int lh = l0 >> 5, lw0 = l0 & 31;
    int rr = 2 * lh + ip;
    bf16x8 h, lo;
#pragma unroll
    for (int u = 0; u < 8; ++u) {
        int ss = 2 * (lw0 + u) + jp;
        float v = (rr < 64 && ss < 64) ? x[(((size_t)(b * 64 + rr)) * 64 + ss) * 128 + c] : 0.f;
        short hh = f2bf(v);
        h[u] = hh;
        lo[u] = f2bf(v - bf2f(hh));
    }
    size_t off = (((size_t)(b * 9 + ij)) * 128 + c) * 1024 + l0;
    *reinterpret_cast<bf16x8*>(bh + off) = h;
    *reinterpret_cast<bf16x8*>(bl + off) = lo;
}

// corr MFMA: per batch y[pq,l] = sum_k A[pq,k]*B[k,l]; M=1024,N=1024,K=1152.
__global__ __launch_bounds__(256) void k_corr_mfma(const float* __restrict__ sp,
                                                   const short* __restrict__ bfh,
                                                   const short* __restrict__ bfl,
                                                   float* __restrict__ outy) {
    const int b = blockIdx.z, tm = blockIdx.y, tn = blockIdx.x;
    __shared__ short Ah[64][40];
    __shared__ short Al[64][40];
    const int tid = threadIdx.x;
    const int w = tid >> 6, lane = tid & 63, m = lane & 15, g = lane >> 4;
    f32x4 acc[4][2];
#pragma unroll
    for (int mf = 0; mf < 4; ++mf)
#pragma unroll
        for (int nn = 0; nn < 2; ++nn) acc[mf][nn] = f32x4{0.f, 0.f, 0.f, 0.f};
    const int srow = tid >> 2, scc = (tid & 3) * 8;
    const int pq = tm * 64 + srow, p = pq >> 5, q = pq & 31;
    const int col0 = tn * 128 + w * 32 + m;
    const size_t bB = (size_t)b * 1024;
    for (int kt = 0; kt < 1152; kt += 32) {
        int ij = kt >> 7;
        int i = (ij >= 6) ? 2 : (ij >= 3 ? 1 : 0);
        int j = ij - 3 * i;
        int c0 = (kt & 127) + scc;
        const float* s = sp + (((size_t)(b * 34 + p + i)) * 34 + (q + j)) * 128 + c0;
        float4 v0 = *reinterpret_cast<const float4*>(s);
        float4 v1 = *reinterpret_cast<const float4*>(s + 4);
        bf16x8 hh, ll;
        cvt8(v0, v1, hh, ll);
        __syncthreads();
        *reinterpret_cast<bf16x8*>(&Ah[srow][scc]) = hh;
        *reinterpret_cast<bf16x8*>(&Al[srow][scc]) = ll;
        __syncthreads();
        bf16x8 ah[4], al[4];
#pragma unroll
        for (int mf = 0; mf < 4; ++mf) {
            ah[mf] = *reinterpret_cast<const bf16x8*>(&Ah[mf * 16 + m][g * 8]);
            al[mf] = *reinterpret_cast<const bf16x8*>(&Al[mf * 16 + m][g * 8]);
        }
#pragma unroll
        for (int nn = 0; nn < 2; ++nn) {
            size_t off = (bB + col0 + nn * 16) * 1152 + kt + g * 8;
            bf16x8 bh = *reinterpret_cast<const bf16x8*>(bfh + off);
            bf16x8 bl = *reinterpret_cast<const bf16x8*>(bfl + off);
#pragma unroll
            for (int mf = 0; mf < 4; ++mf) {
                acc[mf][nn] = __builtin_amdgcn_mfma_f32_16x16x32_bf16(ah[mf], bh, acc[mf][nn], 0, 0, 0);
                acc[mf][nn] = __builtin_amdgcn_mfma_f32_16x16x32_bf16(al[mf], bh, acc[mf][nn], 0, 0, 0);
                acc[mf][nn] = __builtin_amdgcn_mfma_f32_16x16x32_bf16(ah[mf], bl, acc[mf][nn], 0, 0, 0);
            }
        }
    }
#pragma unroll
    for (int mf = 0; mf < 4; ++mf) {
        int row = tm * 64 + mf * 16 + g * 4;
#pragma unroll
        for (int nn = 0; nn < 2; ++nn) {
            int col = col0 + nn * 16;
#pragma unroll
            for (int r = 0; r < 4; ++r)
                outy[((size_t)b << 20) + (size_t)(row + r) * 1024 + col] = acc[mf][nn][r];
        }
    }
}

// deconv MFMA: per batch Z[uv,kcol] = sum_l y[uv,l]*Bp[kcol,l]; M=1024,N=1152,K=1024.
__global__ __launch_bounds__(256) void k_deconv_mfma(const float* __restrict__ yprob,
                                                     const short* __restrict__ bph,
                                                     const short* __restrict__ bpl,
                                                     float* __restrict__ yup) {
    const int b = blockIdx.z, tm = blockIdx.y, tn = blockIdx.x;   // tn = ij in 0..8
    __shared__ short Ah[64][40];
    __shared__ short Al[64][40];
    const int tid = threadIdx.x;
    const int w = tid >> 6, lane = tid & 63, m = lane & 15, g = lane >> 4;
    f32x4 acc[4][2];
#pragma unroll
    for (int mf = 0; mf < 4; ++mf)
#pragma unroll
        for (int nn = 0; nn < 2; ++nn) acc[mf][nn] = f32x4{0.f, 0.f, 0.f, 0.f};
    const int srow = tid >> 2, scc = (tid & 3) * 8;
    const int uvs = tm * 64 + srow;
    const int col0 = tn * 128 + w * 32 + m;
    for (int kt = 0; kt < 1024; kt += 32) {
        const float* s = yprob + ((size_t)b << 20) + (size_t)uvs * 1024 + kt + scc;
        float4 v0 = *reinterpret_cast<const float4*>(s);
        float4 v1 = *reinterpret_cast<const float4*>(s + 4);
        bf16x8 hh, ll;
        cvt8(v0, v1, hh, ll);
        __syncthreads();
        *reinterpret_cast<bf16x8*>(&Ah[srow][scc]) = hh;
        *reinterpret_cast<bf16x8*>(&Al[srow][scc]) = ll;
        __syncthreads();
        bf16x8 ah[4], al[4];
#pragma unroll
        for (int mf = 0; mf < 4; ++mf) {
            ah[mf] = *reinterpret_cast<const bf16x8*>(&Ah[mf * 16 + m][g * 8]);
            al[mf] = *reinterpret_cast<const bf16x8*>(&Al[mf * 16 + m][g * 8]);
        }
#pragma unroll
        for (int nn = 0; nn < 2; ++nn) {
            size_t off = ((size_t)b * 1152 + col0 + nn * 16) * 1024 + kt + g * 8;
            bf16x8 bh = *reinterpret_cast<const bf16x8*>(bph + off);
            bf16x8 bl = *reinterpret_cast<const bf16x8*>(bpl + off);
#pragma unroll
            for (int mf = 0; mf < 4; ++mf) {
                acc[mf][nn] = __builtin_amdgcn_mfma_f32_16x16x32_bf16(ah[mf], bh, acc[mf][nn], 0, 0, 0);
                acc[mf][nn] = __builtin_amdgcn_mfma_f32_16x16x32_bf16(al[mf], bh, acc[mf][nn], 0, 0, 0);
                acc[mf][nn] = __builtin_amdgcn_mfma_f32_16x16x32_bf16(ah[mf], bl, acc[mf][nn], 0, 0, 0);
            }
        }
    }
    const int ip = (tn >= 6) ? 2 : (tn >= 3 ? 1 : 0);
    const int jp = tn - 3 * ip;
#pragma unroll
    for (int mf = 0; mf < 4; ++mf) {
        int uvb = tm * 64 + mf * 16 + g * 4;
#pragma unroll
        for (int nn = 0; nn < 2; ++nn) {
            int c = w * 32 + nn * 16 + m;
#pragma unroll
            for (int r = 0; r < 4; ++r) {
                int uv = uvb + r;
                int uu = uv >> 5, vv = uv & 31;
                int P = 2 * uu + ip, Q = 2 * vv + jp;
                if (P < 64 && Q < 64)
                    atomicAdd(&yup[(((size_t)(b * 64 + P)) * 64 + Q) * 128 + c], acc[mf][nn][r]);
            }
        }
    }
}

__global__ void k_fuse1(const float* __restrict__ in, float* __restrict__ out) {
    size_t idx = (size_t)blockIdx.x * 256 + threadIdx.x;
    if (idx >= (size_t)8 * 1024 * 1024) return;
    int t = (int)(idx & 1023);
    int s = (int)((idx >> 10) & 1023);
    int b = (int)(idx >> 20);
    const float* base = in + ((size_t)b << 20);
    float v = base[(size_t)s * 1024 + t];
    if (s > 0 && t > 0) v += base[(size_t)(s - 1) * 1024 + (t - 1)];
    if (s < 1023 && t < 1023) v += base[(size_t)(s + 1) * 1024 + (t + 1)];
    out[idx] = v;
}

__global__ void k_fuse2(const float* __restrict__ in, float* __restrict__ out) {
    size_t idx = (size_t)blockIdx.x * 256 + threadIdx.x;
    if (idx >= (size_t)8 * 1024 * 1024) return;
    int t = (int)(idx & 1023);
    int s = (int)((idx >> 10) & 1023);
    int b = (int)(idx >> 20);
    int m0 = ((s & 31) << 5) + (s >> 5);
    int n0 = ((t & 31) << 5) + (t >> 5);
    const float* base = in + ((size_t)b << 20);
    float v = 0.f;
#pragma unroll
    for (int d = -1; d <= 1; ++d) {
        int m = m0 + d, n = n0 + d;
        if (m >= 0 && m < 1024 && n >= 0 && n < 1024)
            v += base[(size_t)(((m & 31) << 5) + (m >> 5)) * 1024 + (((n & 31) << 5) + (n >> 5))];
    }
    out[idx] = v;
}

__global__ __launch_bounds__(256) void k_softmax1024(const float* __restrict__ yv,
                                                     const float* __restrict__ mm,
                                                     float* __restrict__ outc) {
    int row = blockIdx.x;
    const float* base = yv + (size_t)row * 1024;
    float mmv = mm[row];
    int t = threadIdx.x;
    float vals[4];
    float mx = -1e30f;
#pragma unroll
    for (int i = 0; i < 4; ++i) {
        vals[i] = base[t + i * 256] * mmv * 10.0f;
        mx = fmaxf(mx, vals[i]);
    }
#pragma unroll
    for (int o = 32; o; o >>= 1) mx = fmaxf(mx, __shfl_xor(mx, o));
    __shared__ float red[8];
    if ((t & 63) == 0) red[t >> 6] = mx;
    __syncthreads();
    mx = fmaxf(fmaxf(red[0], red[1]), fmaxf(red[2], red[3]));
    float s = 0.f;
#pragma unroll
    for (int i = 0; i < 4; ++i) {
        vals[i] = expf(vals[i] - mx);
        s += vals[i];
    }
#pragma unroll
    for (int o = 32; o; o >>= 1) s += __shfl_xor(s, o);
    if ((t & 63) == 0) red[4 + (t >> 6)] = s;
    __syncthreads();
    s = red[4] + red[5] + red[6] + red[7];
    float inv = mmv / s;
#pragma unroll
    for (int i = 0; i < 4; ++i)
        outc[(size_t)row * 1024 + t + i * 256] = vals[i] * inv;
}

// f32 image (8,64,64,128) -> padded bf16 hi/lo pair (8,66,66,128), zero halo
__global__ __launch_bounds__(256) void k_pair_pad(const float* __restrict__ in,
                                                  short* __restrict__ hi, short* __restrict__ lo) {
    int idx = blockIdx.x * 256 + threadIdx.x;   // [0, 8*66*66*16)
    int c8 = idx & 15;
    int r = idx >> 4;
    int pc = r % 66; r /= 66;
    int pr = r % 66; int b = r / 66;
    bf16x8 h, l;
    if (pr >= 1 && pr <= 64 && pc >= 1 && pc <= 64) {
        const float* s = in + (((size_t)(b * 64 + pr - 1)) * 64 + (pc - 1)) * 128 + c8 * 8;
        float4 v0 = *reinterpret_cast<const float4*>(s);
        float4 v1 = *reinterpret_cast<const float4*>(s + 4);
        cvt8(v0, v1, h, l);
    } else {
#pragma unroll
        for (int u = 0; u < 8; ++u) { h[u] = 0; l[u] = 0; }
    }
    size_t off = (size_t)idx * 8;
    *reinterpret_cast<bf16x8*>(hi + off) = h;
    *reinterpret_cast<bf16x8*>(lo + off) = l;
}

__global__ void k_wt_pair(const float* __restrict__ w, short* __restrict__ hi,
                          short* __restrict__ lo, int CI) {
    int idx = blockIdx.x * 256 + threadIdx.x;
    if (idx >= 9 * CI * 128) return;
    int ci = idx % CI; int rest = idx / CI;
    int co = rest & 127; int ij = rest >> 7;
    float v = w[((size_t)ij * CI + ci) * 128 + co];
    short h = f2bf(v);
    hi[idx] = h;
    lo[idx] = f2bf(v - bf2f(h));
}

// pw (1,1,CI,128) f32 -> transposed bf16 [co][ci]
__global__ void k_pw_t(const float* __restrict__ pw, short* __restrict__ out, int CI) {
    int idx = blockIdx.x * 256 + threadIdx.x;
    if (idx >= CI * 128) return;
    int co = idx & 127, ci = idx >> 7;
    out[(size_t)co * CI + ci] = f2bf(pw[idx]);
}

// Fused depthwise 3x3 + pointwise (MFMA, K=CI) + channel softmax -> smout f32.
// Block = (b,P) row (XCD-swizzled), 256 thr / 4 waves. Lane=px, wave=channel quarter.
template <int CI>
__global__ __launch_bounds__(256, 2) void k_dwpw_mfma(const short* __restrict__ in0h,
                                                      const short* __restrict__ in0l,
                                                      const short* __restrict__ in1h,
                                                      const short* __restrict__ in1l,
                                                      const float* __restrict__ dwW,
                                                      const short* __restrict__ pwt,
                                                      const float* __restrict__ db,
                                                      float* __restrict__ smout) {
    const int bid = blockIdx.x;
    const int swz = (bid & 7) * 64 + (bid >> 3);
    const int b = swz >> 6, P = swz & 63;
    const int t = threadIdx.x;
    const int w = t >> 6, lane = t & 63, m = lane & 15, g = lane >> 4;
    __shared__ short Adw[64 * CI];
    __shared__ float red[2][4][64];
    char* ab = (char*)Adw;
    // ---- depthwise: thread = (px=lane, channels cb..cb+CI/4) ----
    const int px = lane;
    const int cb = w * (CI / 4);
    float dwacc[CI / 4];
#pragma unroll
    for (int u = 0; u < CI / 4; ++u) dwacc[u] = 0.f;
#pragma unroll
    for (int i = 0; i < 3; ++i) {
#pragma unroll
        for (int j = 0; j < 3; ++j) {
            const int ij = i * 3 + j;
#pragma unroll
            for (int c8 = 0; c8 < CI / 32; ++c8) {
                const int c = cb + c8 * 8;
                const short* ph = (CI == 256 && c >= 128) ? in1h : in0h;
                const short* pl = (CI == 256 && c >= 128) ? in1l : in0l;
                const int cc = (CI == 256 && c >= 128) ? (c - 128) : c;
                size_t off = (((size_t)b * 66 + P + i) * 66 + px + j) * 128 + cc;
                bf16x8 vh = *reinterpret_cast<const bf16x8*>(ph + off);
                bf16x8 vl = *reinterpret_cast<const bf16x8*>(pl + off);
#pragma unroll
                for (int u = 0; u < 8; ++u) {
                    float v = bf2f(vh[u]) + bf2f(vl[u]);
                    dwacc[c8 * 8 + u] = fmaf(v, dwW[ij * CI + c + u], dwacc[c8 * 8 + u]);
                }
            }
        }
    }
    // ---- write dw out to LDS (single bf16, XOR-swizzled) ----
#pragma unroll
    for (int c8 = 0; c8 < CI / 32; ++c8) {
        bf16x8 hv;
#pragma unroll
        for (int u = 0; u < 8; ++u) hv[u] = f2bf(dwacc[c8 * 8 + u]);
        int byte = px * (CI * 2) + (cb + c8 * 8) * 2;
        int sz = byte ^ ((px & 7) << 4);
        *reinterpret_cast<bf16x8*>(ab + sz) = hv;
    }
    __syncthreads();
    // ---- pointwise MFMA: M=64 px, N=128 co, K=CI ----
    f32x4 acc[4][2];
#pragma unroll
    for (int mt = 0; mt < 4; ++mt)
#pragma unroll
        for (int nn = 0; nn < 2; ++nn) acc[mt][nn] = f32x4{0.f, 0.f, 0.f, 0.f};
    const int co0 = w * 32 + m;
#pragma unroll
    for (int kc = 0; kc < CI / 32; ++kc) {
        bf16x8 av[4];
#pragma unroll
        for (int mt = 0; mt < 4; ++mt) {
            int prow = mt * 16 + m;
            int byte = prow * (CI * 2) + (kc * 32 + g * 8) * 2;
            int sz = byte ^ ((prow & 7) << 4);
            av[mt] = *reinterpret_cast<const bf16x8*>(ab + sz);
        }
#pragma unroll
        for (int nn = 0; nn < 2; ++nn) {
            bf16x8 bv = *reinterpret_cast<const bf16x8*>(pwt + (size_t)(co0 + nn * 16) * CI + kc * 32 + g * 8);
#pragma unroll
            for (int mt = 0; mt < 4; ++mt)
                acc[mt][nn] = __builtin_amdgcn_mfma_f32_16x16x32_bf16(av[mt], bv, acc[mt][nn], 0, 0, 0);
        }
    }
    // ---- bias + channel softmax (butterfly over m, LDS over waves) ----
    float db0 = db[co0], db1 = db[co0 + 16];
    float mx[4][4];
#pragma unroll
    for (int mt = 0; mt < 4; ++mt)
#pragma unroll
        for (int r = 0; r < 4; ++r) {
            acc[mt][0][r] += db0;
            acc[mt][1][r] += db1;
            float v = fmaxf(acc[mt][0][r], acc[mt][1][r]);
#pragma unroll
            for (int o = 1; o <= 8; o <<= 1) v = fmaxf(v, __shfl_xor(v, o));
            mx[mt][r] = v;
        }
    if (m == 0) {
#pragma unroll
        for (int mt = 0; mt < 4; ++mt)
#pragma unroll
            for (int r = 0; r < 4; ++r) red[0][w][mt * 16 + g * 4 + r] = mx[mt][r];
    }
    __syncthreads();
    float sume[4][4];
#pragma unroll
    for (int mt = 0; mt < 4; ++mt)
#pragma unroll
        for (int r = 0; r < 4; ++r) {
            int p = mt * 16 + g * 4 + r;
            float M = fmaxf(fmaxf(red[0][0][p], red[0][1][p]), fmaxf(red[0][2][p], red[0][3][p]));
            acc[mt][0][r] = expf(acc[mt][0][r] - M);
            acc[mt][1][r] = expf(acc[mt][1][r] - M);
            float s = acc[mt][0][r] + acc[mt][1][r];
#pragma unroll
            for (int o = 1; o <= 8; o <<= 1) s += __shfl_xor(s, o);
            sume[mt][r] = s;
        }
    if (m == 0) {
#pragma unroll
        for (int mt = 0; mt < 4; ++mt)
#pragma unroll
            for (int r = 0; r < 4; ++r) red[1][w][mt * 16 + g * 4 + r] = sume[mt][r];
    }
    __syncthreads();
#pragma unroll
    for (int mt = 0; mt < 4; ++mt)
#pragma unroll
        for (int r = 0; r < 4; ++r) {
            int p = mt * 16 + g * 4 + r;
            float S = red[1][0][p] + red[1][1][p] + red[1][2][p] + red[1][3][p];
            float inv = 1.0f / S;
            size_t pix = ((size_t)b * 64 + P) * 64 + p;
            smout[pix * 128 + co0] = acc[mt][0][r] * inv;
            smout[pix * 128 + co0 + 16] = acc[mt][1][r] * inv;
        }
}

// MFMA split-bf16 implicit-GEMM 3x3 conv + bias + elu + gate, LDS-staged rows.
template <int CI>
__global__ __launch_bounds__(256, 4) void k_conv_lds(const short* __restrict__ in0h,
                                                     const short* __restrict__ in0l,
                                                     const short* __restrict__ in1h,
                                                     const short* __restrict__ in1l,
                                                     const short* __restrict__ wh,
                                                     const short* __restrict__ wl,
                                                     const float* __restrict__ bias,
                                                     const float* __restrict__ sm,
                                                     float* __restrict__ out) {
    const int bid = blockIdx.x;
    const int swz = (bid & 7) * 64 + (bid >> 3);   // XCD-contiguous rows
    const int b = swz >> 6, P = swz & 63;
    const int tid = threadIdx.x;
    const int w = tid >> 6, lane = tid & 63;
    const int m = lane & 15, g = lane >> 4;
    __shared__ short Sh[66 * 128];
    __shared__ short Sl[66 * 128];
    char* shb = (char*)Sh;
    char* slb = (char*)Sl;
    f32x4 acc[4][2];
#pragma unroll
    for (int mt = 0; mt < 4; ++mt)
#pragma unroll
        for (int nn = 0; nn < 2; ++nn) acc[mt][nn] = f32x4{0.f, 0.f, 0.f, 0.f};

#pragma unroll
    for (int half = 0; half < CI / 128; ++half) {
        const short* ih = (half == 0) ? in0h : in1h;
        const short* il = (half == 0) ? in0l : in1l;
        const size_t rbase0 = ((size_t)b * 66 + P) * 66 * 128;
#pragma unroll
        for (int i = 0; i < 3; ++i) {
            __syncthreads();
            const size_t rsrc = rbase0 + (size_t)i * 66 * 128;
#pragma unroll
            for (int e0 = 0; e0 < 1056; e0 += 256) {
                int e = e0 + tid;
                if (e < 1056) {
                    int px = e >> 4, c8 = e & 15;
                    int lin = px * 256 + c8 * 16;
                    int sz = lin ^ ((px & 7) << 4);
                    size_t so = rsrc + (size_t)px * 128 + c8 * 8;
                    *reinterpret_cast<bf16x8*>(shb + sz) = *reinterpret_cast<const bf16x8*>(ih + so);
                    *reinterpret_cast<bf16x8*>(slb + sz) = *reinterpret_cast<const bf16x8*>(il + so);
                }
            }
            __syncthreads();
#pragma unroll
            for (int j = 0; j < 3; ++j) {
                const int ij = i * 3 + j;
                const short* wph = wh + ((size_t)ij * 128 + w * 32 + m) * CI + half * 128 + g * 8;
                const short* wpl = wl + ((size_t)ij * 128 + w * 32 + m) * CI + half * 128 + g * 8;
#pragma unroll
                for (int ci0 = 0; ci0 < 128; ci0 += 32) {
                    bf16x8 bhv[2], blv[2];
#pragma unroll
                    for (int nn = 0; nn < 2; ++nn) {
                        bhv[nn] = *reinterpret_cast<const bf16x8*>(wph + (size_t)nn * 16 * CI + ci0);
                        blv[nn] = *reinterpret_cast<const bf16x8*>(wpl + (size_t)nn * 16 * CI + ci0);
                    }
                    bf16x8 ah[4], al[4];
#pragma unroll
                    for (int mt = 0; mt < 4; ++mt) {
                        int px = mt * 16 + m + j;
                        int lin = px * 256 + ci0 * 2 + g * 16;
                        int sz = lin ^ ((px & 7) << 4);
                        ah[mt] = *reinterpret_cast<const bf16x8*>(shb + sz);
                        al[mt] = *reinterpret_cast<const bf16x8*>(slb + sz);
                    }
#pragma unroll
                    for (int nn = 0; nn < 2; ++nn)
#pragma unroll
                        for (int mt = 0; mt < 4; ++mt) {
                            acc[mt][nn] = __builtin_amdgcn_mfma_f32_16x16x32_bf16(ah[mt], bhv[nn], acc[mt][nn], 0, 0, 0);
                            acc[mt][nn] = __builtin_amdgcn_mfma_f32_16x16x32_bf16(ah[mt], blv[nn], acc[mt][nn], 0, 0, 0);
                            acc[mt][nn] = __builtin_amdgcn_mfma_f32_16x16x32_bf16(al[mt], bhv[nn], acc[mt][nn], 0, 0, 0);
                        }
                }
            }
        }
    }
#pragma unroll
    for (int nn = 0; nn < 2; ++nn) {
        const int co = w * 32 + nn * 16 + m;
        const float bb = bias[co];
#pragma unroll
        for (int mt = 0; mt < 4; ++mt) {
#pragma unroll
            for (int r = 0; r < 4; ++r) {
                int Q = mt * 16 + g * 4 + r;
                size_t pix = ((size_t)b * 64 + P) * 64 + Q;
                float z = acc[mt][nn][r] + bb;
                z = z > 0.f ? z : expm1f(z);
                out[pix * 128 + co] = z * sm[pix * 128 + co];
            }
        }
    }
}

extern "C" void kernel_launch(void* const* d_in, const int* in_sizes, int n_in,
                              void* d_out, int out_size, void* d_ws, size_t ws_size,
                              hipStream_t stream) {
    const float* x    = (const float*)d_in[0];
    const float* mask = (const float*)d_in[1];
    const float* w1   = (const float*)d_in[2];
    const float* b1   = (const float*)d_in[3];
    const float* dw1  = (const float*)d_in[4];
    const float* pw1  = (const float*)d_in[5];
    const float* db1  = (const float*)d_in[6];
    const float* w2   = (const float*)d_in[7];
    const float* b2   = (const float*)d_in[8];
    const float* dw2  = (const float*)d_in[9];
    const float* pw2  = (const float*)d_in[10];
    const float* db2  = (const float*)d_in[11];

    float* out_a = (float*)d_out;            // (8,64,64,128)
    float* out_c = out_a + 4194304;          // (8,32,32,1024)

    char* wsb = (char*)d_ws;
    float* sp   = (float*)(wsb + BOFF_SP);
    float* invd = (float*)(wsb + BOFF_INVD);
    short* bfh  = (short*)(wsb + BOFF_BFH);
    short* bfl  = (short*)(wsb + BOFF_BFL);
    float* Tbuf = (float*)(wsb + BOFF_T);
    short* bph  = (short*)(wsb + BOFF_BPH);
    short* bpl  = (short*)(wsb + BOFF_BPL);
    float* yup  = (float*)(wsb + BOFF_YUP);
    float* smb  = (float*)(wsb + BOFF_SM);
    short* p3h  = (short*)(wsb + BOFF_P3H);
    short* p3l  = (short*)(wsb + BOFF_P3L);
    float* a1   = (float*)(wsb + BOFF_A1);
    short* xh   = (short*)(wsb + BOFF_XH);
    short* xl   = (short*)(wsb + BOFF_XL);
    short* wt1h = (short*)(wsb + BOFF_WT1H);
    short* wt1l = (short*)(wsb + BOFF_WT1L);
    short* wt2h = (short*)(wsb + BOFF_WT2H);
    short* wt2l = (short*)(wsb + BOFF_WT2L);
    short* pw1t = (short*)(wsb + BOFF_PW1B);
    short* pw2t = (short*)(wsb + BOFF_PW2B);
    float* m0   = (float*)(wsb + BOFF_M0);
    float* mmb  = (float*)(wsb + BOFF_MM);

    // phase A: mask + correlation (MFMA) + fuse + softmax
    k_mask_pool<<<8192, 256, 0, stream>>>(mask, m0);
    k_mask_dilate<<<32, 256, 0, stream>>>(m0, mmb);
    k_srcpad<<<4624, 256, 0, stream>>>(x, sp);
    k_invd<<<512, 256, 0, stream>>>(sp, invd);
    k_wt_pair<<<576, 256, 0, stream>>>(w1, wt1h, wt1l, 128);
    k_wt_pair<<<1152, 256, 0, stream>>>(w2, wt2h, wt2l, 256);
    k_pw_t<<<64, 256, 0, stream>>>(pw1, pw1t, 128);
    k_pw_t<<<128, 256, 0, stream>>>(pw2, pw2t, 256);
    k_corr_B<<<4608, 256, 0, stream>>>(sp, invd, bfh, bfl);
    k_corr_mfma<<<dim3(8, 16, 8), 256, 0, stream>>>(sp, bfh, bfl, out_c);
    k_fuse1<<<32768, 256, 0, stream>>>(out_c, Tbuf);
    k_fuse2<<<32768, 256, 0, stream>>>(Tbuf, out_c);
    k_deconv_B<<<4608, 256, 0, stream>>>(x, bph, bpl);
    k_softmax1024<<<8192, 256, 0, stream>>>(out_c, mmb, out_c);   // in-place, row-local
    // phase B: deconv (MFMA) -> yup
    hipMemsetAsync(yup, 0, (size_t)4194304 * sizeof(float), stream);
    k_deconv_mfma<<<dim3(9, 16, 8), 256, 0, stream>>>(out_c, bph, bpl, yup);
    // phase C: gated conv 1 (pair first, then MFMA dwpw, then conv)
    k_pair_pad<<<2178, 256, 0, stream>>>(yup, p3h, p3l);   // yup dead after this
    k_pair_pad<<<2178, 256, 0, stream>>>(x, xh, xl);       // overlaps dead yup tail
    k_dwpw_mfma<128><<<512, 256, 0, stream>>>(p3h, p3l, nullptr, nullptr,
                                              dw1, pw1t, db1, smb);
    k_conv_lds<128><<<512, 256, 0, stream>>>(p3h, p3l, nullptr, nullptr,
                                             wt1h, wt1l, b1, smb, a1);
    // phase D: gated conv 2 (concat(a1, x))
    k_pair_pad<<<2178, 256, 0, stream>>>(a1, p3h, p3l);
    k_dwpw_mfma<256><<<512, 256, 0, stream>>>(p3h, p3l, xh, xl,
                                              dw2, pw2t, db2, smb);
    k_conv_lds<256><<<512, 256, 0, stream>>>(p3h, p3l, xh, xl,
                                             wt2h, wt2l, b2, smb, out_a);
}

// Round 8
// 668.079 us; speedup vs baseline: 1.6418x; 1.0467x over previous
//
#include <hip/hip_runtime.h>
#include <hip/hip_bf16.h>

// B=8, H=W=64, C=128, rate=2 -> k=3, h=w=32, L=1024
// Workspace (72,433,664 bytes), time-multiplexed regions (liveness checked):
//  phase A/B: sp [0,4.73M) invd [4.73,5.26M) Bf [5.26,43.0M) T [0,33.55M)
//             Bp [0,37.75M) yup [37.75,54.53M)
//  phase C/D: SM [0,16.78M) P3 pair [16.78,34.62M) A1 [34.62,51.40M)
//             X pair [51.40,69.24M)
//  static:    weights [69.24,71.11M) m0/mm [71.11,71.17M)

#define BOFF_SP      0
#define BOFF_INVD    4734976
#define BOFF_BFH     5259264
#define BOFF_BFL     24133632
#define BOFF_T       0
#define BOFF_BPH     0
#define BOFF_BPL     18874368
#define BOFF_YUP     37748736
#define BOFF_SM      0
#define BOFF_P3H     16777216
#define BOFF_P3L     25698304
#define BOFF_A1      34619392
#define BOFF_XH      51396608
#define BOFF_XL      60317696
#define BOFF_WT1H    69238784
#define BOFF_WT1L    69533696
#define BOFF_WT2H    69828608
#define BOFF_WT2L    70418432
#define BOFF_PW1B    71008256
#define BOFF_PW2B    71041024
#define BOFF_M0      71106560
#define BOFF_MM      71139328

typedef float f32x4 __attribute__((ext_vector_type(4)));
typedef short bf16x8 __attribute__((ext_vector_type(8)));

__device__ __forceinline__ short f2bf(float f) {
    unsigned u = __float_as_uint(f);
    unsigned r = u + 0x7FFFu + ((u >> 16) & 1u);
    return (short)(r >> 16);
}
__device__ __forceinline__ float bf2f(short s) {
    return __uint_as_float(((unsigned)(unsigned short)s) << 16);
}
__device__ __forceinline__ void cvt8(const float4 v0, const float4 v1, bf16x8& h, bf16x8& l) {
    float a[8] = {v0.x, v0.y, v0.z, v0.w, v1.x, v1.y, v1.z, v1.w};
#pragma unroll
    for (int u = 0; u < 8; ++u) {
        short hh = f2bf(a[u]);
        h[u] = hh;
        l[u] = f2bf(a[u] - bf2f(hh));
    }
}

__global__ __launch_bounds__(256) void k_mask_pool(const float* __restrict__ mask, float* __restrict__ m0) {
    int blk = blockIdx.x;
    int b = blk >> 10, pq = blk & 1023, p = pq >> 5, q = pq & 31;
    int t = threadIdx.x, dy = t >> 4, dx = t & 15;
    float v = mask[((size_t)(b * 512 + p * 16 + dy)) * 512 + q * 16 + dx];
#pragma unroll
    for (int o = 32; o; o >>= 1) v = fmaxf(v, __shfl_xor(v, o));
    __shared__ float s[4];
    if ((t & 63) == 0) s[t >> 6] = v;
    __syncthreads();
    if (t == 0) m0[blk] = fmaxf(fmaxf(s[0], s[1]), fmaxf(s[2], s[3]));
}

__global__ void k_mask_dilate(const float* __restrict__ m0, float* __restrict__ mm) {
    int idx = blockIdx.x * 256 + threadIdx.x;
    if (idx >= 8192) return;
    int b = idx >> 10, pq = idx & 1023, p = pq >> 5, q = pq & 31;
    float v = -1e30f;
    for (int di = -1; di <= 1; ++di)
        for (int dj = -1; dj <= 1; ++dj) {
            int pp = p + di, qq = q + dj;
            if (pp >= 0 && pp < 32 && qq >= 0 && qq < 32)
                v = fmaxf(v, m0[(b << 10) + pp * 32 + qq]);
        }
    mm[idx] = 1.0f - v;
}

__global__ void k_srcpad(const float* __restrict__ x, float* __restrict__ sp) {
    int idx = blockIdx.x * 256 + threadIdx.x;
    if (idx >= 8 * 34 * 34 * 128) return;
    int c = idx & 127;
    int r = idx >> 7;
    int xx = r % 34; r /= 34;
    int yy = r % 34; int b = r / 34;
    float v = 0.f;
    if (yy >= 1 && yy <= 32 && xx >= 1 && xx <= 32)
        v = x[(((size_t)(b * 64 + (yy - 1) * 2)) * 64 + (xx - 1) * 2) * 128 + c];
    sp[idx] = v;
}

__global__ void k_invd(const float* __restrict__ sp, float* __restrict__ invd) {
    int idx = blockIdx.x * 256 + threadIdx.x;
    if (idx >= 1024 * 128) return;
    int c = idx & 127, l = idx >> 7, lh = l >> 5, lw = l & 31;
    float s = 0.f;
    for (int b = 0; b < 8; ++b)
#pragma unroll
        for (int i = 0; i < 3; ++i)
#pragma unroll
            for (int j = 0; j < 3; ++j) {
                float v = sp[(((size_t)(b * 34 + lh + i)) * 34 + (lw + j)) * 128 + c];
                s += v * v;
            }
    invd[idx] = 1.0f / fmaxf(s, 1e-8f);
}

// Bf[b][l][ij][c] = sp[b][lh+i][lw+j][c] * invd[l][c], split bf16 pair.
__global__ void k_corr_B(const float* __restrict__ sp, const float* __restrict__ invd,
                         short* __restrict__ bh, short* __restrict__ bl) {
    int idx = blockIdx.x * 256 + threadIdx.x;
    int c8 = idx & 15; int rest = idx >> 4;
    int ij = rest % 9; int rest2 = rest / 9;
    int l = rest2 & 1023, b = rest2 >> 10;
    int lh = l >> 5, lw = l & 31;
    int i = (ij >= 6) ? 2 : (ij >= 3 ? 1 : 0);
    int j = ij - 3 * i;
    int c0 = c8 * 8;
    const float* s = sp + (((size_t)(b * 34 + lh + i)) * 34 + (lw + j)) * 128 + c0;
    const float* dv = invd + l * 128 + c0;
    bf16x8 h, lo;
#pragma unroll
    for (int u = 0; u < 8; ++u) {
        float v = s[u] * dv[u];
        short hh = f2bf(v);
        h[u] = hh;
        lo[u] = f2bf(v - bf2f(hh));
    }
    size_t off = ((size_t)(b * 1024 + l)) * 1152 + ij * 128 + c0;
    *reinterpret_cast<bf16x8*>(bh + off) = h;
    *reinterpret_cast<bf16x8*>(bl + off) = lo;
}

// Bp[b][ij][c][l] = x[b][2lh+ip][2lw+jp][c] (0 OOB), split bf16 pair.
__global__ void k_deconv_B(const float* __restrict__ x, short* __restrict__ bh, short* __restrict__ bl) {
    int idx = blockIdx.x * 256 + threadIdx.x;
    int l8 = idx & 127; int rest = idx >> 7;
    int c = rest & 127; int rest2 = rest >> 7;
    int ij = rest2 % 9; int b = rest2 / 9;
    int ip = (ij >= 6) ? 2 : (ij >= 3 ? 1 : 0);
    int jp = ij - 3 * ip;
    int l0 = l8 * 8;
    int lh = l0 >> 5, lw0 = l0 & 31;
    int rr = 2 * lh + ip;
    bf16x8 h, lo;
#pragma unroll
    for (int u = 0; u < 8; ++u) {
        int ss = 2 * (lw0 + u) + jp;
        float v = (rr < 64 && ss < 64) ? x[(((size_t)(b * 64 + rr)) * 64 + ss) * 128 + c] : 0.f;
        short hh = f2bf(v);
        h[u] = hh;
        lo[u] = f2bf(v - bf2f(hh));
    }
    size_t off = (((size_t)(b * 9 + ij)) * 128 + c) * 1024 + l0;
    *reinterpret_cast<bf16x8*>(bh + off) = h;
    *reinterpret_cast<bf16x8*>(bl + off) = lo;
}

// corr MFMA (pipelined): per batch y[pq,l] = sum_k A[pq,k]*B[k,l]; M=N=1024, K=1152.
// Next-tile A (f32) and B (bf16 pair) are prefetched into registers while the
// current tile's 24 MFMAs run -> load latency hides under compute.
__global__ __launch_bounds__(256) void k_corr_mfma(const float* __restrict__ sp,
                                                   const short* __restrict__ bfh,
                                                   const short* __restrict__ bfl,
                                                   float* __restrict__ outy) {
    const int b = blockIdx.z, tm = blockIdx.y, tn = blockIdx.x;
    __shared__ short Ah[64][40];
    __shared__ short Al[64][40];
    const int tid = threadIdx.x;
    const int w = tid >> 6, lane = tid & 63, m = lane & 15, g = lane >> 4;
    f32x4 acc[4][2];
#pragma unroll
    for (int mf = 0; mf < 4; ++mf)
#pragma unroll
        for (int nn = 0; nn < 2; ++nn) acc[mf][nn] = f32x4{0.f, 0.f, 0.f, 0.f};
    const int srow = tid >> 2, scc = (tid & 3) * 8;
    const int pq = tm * 64 + srow, p = pq >> 5, q = pq & 31;
    const int col0 = tn * 128 + w * 32 + m;
    const size_t bB = (size_t)b * 1024;

    const size_t boff0 = (bB + col0) * 1152 + g * 8;
    const size_t boff1 = (bB + col0 + 16) * 1152 + g * 8;

    // A address generator for k-tile kt
    auto aptr = [&](int kt) -> const float* {
        int ij = kt >> 7;
        int i = (ij >= 6) ? 2 : (ij >= 3 ? 1 : 0);
        int j = ij - 3 * i;
        int c0 = (kt & 127) + scc;
        return sp + (((size_t)(b * 34 + p + i)) * 34 + (q + j)) * 128 + c0;
    };
    // prologue prefetch kt=0
    const float* ap = aptr(0);
    float4 a0 = *reinterpret_cast<const float4*>(ap);
    float4 a1 = *reinterpret_cast<const float4*>(ap + 4);
    bf16x8 nb0h = *reinterpret_cast<const bf16x8*>(bfh + boff0);
    bf16x8 nb0l = *reinterpret_cast<const bf16x8*>(bfl + boff0);
    bf16x8 nb1h = *reinterpret_cast<const bf16x8*>(bfh + boff1);
    bf16x8 nb1l = *reinterpret_cast<const bf16x8*>(bfl + boff1);

    for (int kt = 0; kt < 1152; kt += 32) {
        bf16x8 hh, ll;
        cvt8(a0, a1, hh, ll);
        __syncthreads();
        *reinterpret_cast<bf16x8*>(&Ah[srow][scc]) = hh;
        *reinterpret_cast<bf16x8*>(&Al[srow][scc]) = ll;
        __syncthreads();
        // snapshot current B, issue next-tile prefetch (clamped)
        const int ktn = (kt + 32 < 1152) ? kt + 32 : kt;
        bf16x8 cb0h = nb0h, cb0l = nb0l, cb1h = nb1h, cb1l = nb1l;
        const float* apn = aptr(ktn);
        a0 = *reinterpret_cast<const float4*>(apn);
        a1 = *reinterpret_cast<const float4*>(apn + 4);
        nb0h = *reinterpret_cast<const bf16x8*>(bfh + boff0 + ktn);
        nb0l = *reinterpret_cast<const bf16x8*>(bfl + boff0 + ktn);
        nb1h = *reinterpret_cast<const bf16x8*>(bfh + boff1 + ktn);
        nb1l = *reinterpret_cast<const bf16x8*>(bfl + boff1 + ktn);

        bf16x8 ah[4], al[4];
#pragma unroll
        for (int mf = 0; mf < 4; ++mf) {
            ah[mf] = *reinterpret_cast<const bf16x8*>(&Ah[mf * 16 + m][g * 8]);
            al[mf] = *reinterpret_cast<const bf16x8*>(&Al[mf * 16 + m][g * 8]);
        }
#pragma unroll
        for (int mf = 0; mf < 4; ++mf) {
            acc[mf][0] = __builtin_amdgcn_mfma_f32_16x16x32_bf16(ah[mf], cb0h, acc[mf][0], 0, 0, 0);
            acc[mf][0] = __builtin_amdgcn_mfma_f32_16x16x32_bf16(al[mf], cb0h, acc[mf][0], 0, 0, 0);
            acc[mf][0] = __builtin_amdgcn_mfma_f32_16x16x32_bf16(ah[mf], cb0l, acc[mf][0], 0, 0, 0);
            acc[mf][1] = __builtin_amdgcn_mfma_f32_16x16x32_bf16(ah[mf], cb1h, acc[mf][1], 0, 0, 0);
            acc[mf][1] = __builtin_amdgcn_mfma_f32_16x16x32_bf16(al[mf], cb1h, acc[mf][1], 0, 0, 0);
            acc[mf][1] = __builtin_amdgcn_mfma_f32_16x16x32_bf16(ah[mf], cb1l, acc[mf][1], 0, 0, 0);
        }
    }
#pragma unroll
    for (int mf = 0; mf < 4; ++mf) {
        int row = tm * 64 + mf * 16 + g * 4;
#pragma unroll
        for (int nn = 0; nn < 2; ++nn) {
            int col = col0 + nn * 16;
#pragma unroll
            for (int r = 0; r < 4; ++r)
                outy[((size_t)b << 20) + (size_t)(row + r) * 1024 + col] = acc[mf][nn][r];
        }
    }
}

// deconv MFMA (pipelined): per batch Z[uv,kcol] = sum_l y[uv,l]*Bp[kcol,l]; K=1024.
__global__ __launch_bounds__(256) void k_deconv_mfma(const float* __restrict__ yprob,
                                                     const short* __restrict__ bph,
                                                     const short* __restrict__ bpl,
                                                     float* __restrict__ yup) {
    const int b = blockIdx.z, tm = blockIdx.y, tn = blockIdx.x;   // tn = ij in 0..8
    __shared__ short Ah[64][40];
    __shared__ short Al[64][40];
    const int tid = threadIdx.x;
    const int w = tid >> 6, lane = tid & 63, m = lane & 15, g = lane >> 4;
    f32x4 acc[4][2];
#pragma unroll
    for (int mf = 0; mf < 4; ++mf)
#pragma unroll
        for (int nn = 0; nn < 2; ++nn) acc[mf][nn] = f32x4{0.f, 0.f, 0.f, 0.f};
    const int srow = tid >> 2, scc = (tid & 3) * 8;
    const int uvs = tm * 64 + srow;
    const int col0 = tn * 128 + w * 32 + m;

    const float* abase = yprob + ((size_t)b << 20) + (size_t)uvs * 1024 + scc;
    const size_t boff0 = ((size_t)b * 1152 + col0) * 1024 + g * 8;
    const size_t boff1 = ((size_t)b * 1152 + col0 + 16) * 1024 + g * 8;

    float4 a0 = *reinterpret_cast<const float4*>(abase);
    float4 a1 = *reinterpret_cast<const float4*>(abase + 4);
    bf16x8 nb0h = *reinterpret_cast<const bf16x8*>(bph + boff0);
    bf16x8 nb0l = *reinterpret_cast<const bf16x8*>(bpl + boff0);
    bf16x8 nb1h = *reinterpret_cast<const bf16x8*>(bph + boff1);
    bf16x8 nb1l = *reinterpret_cast<const bf16x8*>(bpl + boff1);

    for (int kt = 0; kt < 1024; kt += 32) {
        bf16x8 hh, ll;
        cvt8(a0, a1, hh, ll);
        __syncthreads();
        *reinterpret_cast<bf16x8*>(&Ah[srow][scc]) = hh;
        *reinterpret_cast<bf16x8*>(&Al[srow][scc]) = ll;
        __syncthreads();
        const int ktn = (kt + 32 < 1024) ? kt + 32 : kt;
        bf16x8 cb0h = nb0h, cb0l = nb0l, cb1h = nb1h, cb1l = nb1l;
        a0 = *reinterpret_cast<const float4*>(abase + ktn);
        a1 = *reinterpret_cast<const float4*>(abase + ktn + 4);
        nb0h = *reinterpret_cast<const bf16x8*>(bph + boff0 + ktn);
        nb0l = *reinterpret_cast<const bf16x8*>(bpl + boff0 + ktn);
        nb1h = *reinterpret_cast<const bf16x8*>(bph + boff1 + ktn);
        nb1l = *reinterpret_cast<const bf16x8*>(bpl + boff1 + ktn);

        bf16x8 ah[4], al[4];
#pragma unroll
        for (int mf = 0; mf < 4; ++mf) {
            ah[mf] = *reinterpret_cast<const bf16x8*>(&Ah[mf * 16 + m][g * 8]);
            al[mf] = *reinterpret_cast<const bf16x8*>(&Al[mf * 16 + m][g * 8]);
        }
#pragma unroll
        for (int mf = 0; mf < 4; ++mf) {
            acc[mf][0] = __builtin_amdgcn_mfma_f32_16x16x32_bf16(ah[mf], cb0h, acc[mf][0], 0, 0, 0);
            acc[mf][0] = __builtin_amdgcn_mfma_f32_16x16x32_bf16(al[mf], cb0h, acc[mf][0], 0, 0, 0);
            acc[mf][0] = __builtin_amdgcn_mfma_f32_16x16x32_bf16(ah[mf], cb0l, acc[mf][0], 0, 0, 0);
            acc[mf][1] = __builtin_amdgcn_mfma_f32_16x16x32_bf16(ah[mf], cb1h, acc[mf][1], 0, 0, 0);
            acc[mf][1] = __builtin_amdgcn_mfma_f32_16x16x32_bf16(al[mf], cb1h, acc[mf][1], 0, 0, 0);
            acc[mf][1] = __builtin_amdgcn_mfma_f32_16x16x32_bf16(ah[mf], cb1l, acc[mf][1], 0, 0, 0);
        }
    }
    const int ip = (tn >= 6) ? 2 : (tn >= 3 ? 1 : 0);
    const int jp = tn - 3 * ip;
#pragma unroll
    for (int mf = 0; mf < 4; ++mf) {
        int uvb = tm * 64 + mf * 16 + g * 4;
#pragma unroll
        for (int nn = 0; nn < 2; ++nn) {
            int c = w * 32 + nn * 16 + m;
#pragma unroll
            for (int r = 0; r < 4; ++r) {
                int uv = uvb + r;
                int uu = uv >> 5, vv = uv & 31;
                int P = 2 * uu + ip, Q = 2 * vv + jp;
                if (P < 64 && Q < 64)
                    atomicAdd(&yup[(((size_t)(b * 64 + P)) * 64 + Q) * 128 + c], acc[mf][nn][r]);
            }
        }
    }
}

__global__ void k_fuse1(const float* __restrict__ in, float* __restrict__ out) {
    size_t idx = (size_t)blockIdx.x * 256 + threadIdx.x;
    if (idx >= (size_t)8 * 1024 * 1024) return;
    int t = (int)(idx & 1023);
    int s = (int)((idx >> 10) & 1023);
    int b = (int)(idx >> 20);
    const float* base = in + ((size_t)b << 20);
    float v = base[(size_t)s * 1024 + t];
    if (s > 0 && t > 0) v += base[(size_t)(s - 1) * 1024 + (t - 1)];
    if (s < 1023 && t < 1023) v += base[(size_t)(s + 1) * 1024 + (t + 1)];
    out[idx] = v;
}

__global__ void k_fuse2(const float* __restrict__ in, float* __restrict__ out) {
    size_t idx = (size_t)blockIdx.x * 256 + threadIdx.x;
    if (idx >= (size_t)8 * 1024 * 1024) return;
    int t = (int)(idx & 1023);
    int s = (int)((idx >> 10) & 1023);
    int b = (int)(idx >> 20);
    int m0 = ((s & 31) << 5) + (s >> 5);
    int n0 = ((t & 31) << 5) + (t >> 5);
    const float* base = in + ((size_t)b << 20);
    float v = 0.f;
#pragma unroll
    for (int d = -1; d <= 1; ++d) {
        int m = m0 + d, n = n0 + d;
        if (m >= 0 && m < 1024 && n >= 0 && n < 1024)
            v += base[(size_t)(((m & 31) << 5) + (m >> 5)) * 1024 + (((n & 31) << 5) + (n >> 5))];
    }
    out[idx] = v;
}

__global__ __launch_bounds__(256) void k_softmax1024(const float* __restrict__ yv,
                                                     const float* __restrict__ mm,
                                                     float* __restrict__ outc) {
    int row = blockIdx.x;
    const float* base = yv + (size_t)row * 1024;
    float mmv = mm[row];
    int t = threadIdx.x;
    float vals[4];
    float mx = -1e30f;
#pragma unroll
    for (int i = 0; i < 4; ++i) {
        vals[i] = base[t + i * 256] * mmv * 10.0f;
        mx = fmaxf(mx, vals[i]);
    }
#pragma unroll
    for (int o = 32; o; o >>= 1) mx = fmaxf(mx, __shfl_xor(mx, o));
    __shared__ float red[8];
    if ((t & 63) == 0) red[t >> 6] = mx;
    __syncthreads();
    mx = fmaxf(fmaxf(red[0], red[1]), fmaxf(red[2], red[3]));
    float s = 0.f;
#pragma unroll
    for (int i = 0; i < 4; ++i) {
        vals[i] = expf(vals[i] - mx);
        s += vals[i];
    }
#pragma unroll
    for (int o = 32; o; o >>= 1) s += __shfl_xor(s, o);
    if ((t & 63) == 0) red[4 + (t >> 6)] = s;
    __syncthreads();
    s = red[4] + red[5] + red[6] + red[7];
    float inv = mmv / s;
#pragma unroll
    for (int i = 0; i < 4; ++i)
        outc[(size_t)row * 1024 + t + i * 256] = vals[i] * inv;
}

// f32 image (8,64,64,128) -> padded bf16 hi/lo pair (8,66,66,128), zero halo
__global__ __launch_bounds__(256) void k_pair_pad(const float* __restrict__ in,
                                                  short* __restrict__ hi, short* __restrict__ lo) {
    int idx = blockIdx.x * 256 + threadIdx.x;   // [0, 8*66*66*16)
    int c8 = idx & 15;
    int r = idx >> 4;
    int pc = r % 66; r /= 66;
    int pr = r % 66; int b = r / 66;
    bf16x8 h, l;
    if (pr >= 1 && pr <= 64 && pc >= 1 && pc <= 64) {
        const float* s = in + (((size_t)(b * 64 + pr - 1)) * 64 + (pc - 1)) * 128 + c8 * 8;
        float4 v0 = *reinterpret_cast<const float4*>(s);
        float4 v1 = *reinterpret_cast<const float4*>(s + 4);
        cvt8(v0, v1, h, l);
    } else {
#pragma unroll
        for (int u = 0; u < 8; ++u) { h[u] = 0; l[u] = 0; }
    }
    size_t off = (size_t)idx * 8;
    *reinterpret_cast<bf16x8*>(hi + off) = h;
    *reinterpret_cast<bf16x8*>(lo + off) = l;
}

__global__ void k_wt_pair(const float* __restrict__ w, short* __restrict__ hi,
                          short* __restrict__ lo, int CI) {
    int idx = blockIdx.x * 256 + threadIdx.x;
    if (idx >= 9 * CI * 128) return;
    int ci = idx % CI; int rest = idx / CI;
    int co = rest & 127; int ij = rest >> 7;
    float v = w[((size_t)ij * CI + ci) * 128 + co];
    short h = f2bf(v);
    hi[idx] = h;
    lo[idx] = f2bf(v - bf2f(h));
}

// pw (1,1,CI,128) f32 -> transposed bf16 [co][ci]
__global__ void k_pw_t(const float* __restrict__ pw, short* __restrict__ out, int CI) {
    int idx = blockIdx.x * 256 + threadIdx.x;
    if (idx >= CI * 128) return;
    int co = idx & 127, ci = idx >> 7;
    out[(size_t)co * CI + ci] = f2bf(pw[idx]);
}

// Fused depthwise 3x3 + pointwise (MFMA, K=CI) + channel softmax -> smout f32.
template <int CI>
__global__ __launch_bounds__(256, 2) void k_dwpw_mfma(const short* __restrict__ in0h,
                                                      const short* __restrict__ in0l,
                                                      const short* __restrict__ in1h,
                                                      const short* __restrict__ in1l,
                                                      const float* __restrict__ dwW,
                                                      const short* __restrict__ pwt,
                                                      const float* __restrict__ db,
                                                      float* __restrict__ smout) {
    const int bid = blockIdx.x;
    const int swz = (bid & 7) * 64 + (bid >> 3);
    const int b = swz >> 6, P = swz & 63;
    const int t = threadIdx.x;
    const int w = t >> 6, lane = t & 63, m = lane & 15, g = lane >> 4;
    __shared__ short Adw[64 * CI];
    __shared__ float red[2][4][64];
    char* ab = (char*)Adw;
    const int px = lane;
    const int cb = w * (CI / 4);
    float dwacc[CI / 4];
#pragma unroll
    for (int u = 0; u < CI / 4; ++u) dwacc[u] = 0.f;
#pragma unroll
    for (int i = 0; i < 3; ++i) {
#pragma unroll
        for (int j = 0; j < 3; ++j) {
            const int ij = i * 3 + j;
#pragma unroll
            for (int c8 = 0; c8 < CI / 32; ++c8) {
                const int c = cb + c8 * 8;
                const short* ph = (CI == 256 && c >= 128) ? in1h : in0h;
                const short* pl = (CI == 256 && c >= 128) ? in1l : in0l;
                const int cc = (CI == 256 && c >= 128) ? (c - 128) : c;
                size_t off = (((size_t)b * 66 + P + i) * 66 + px + j) * 128 + cc;
                bf16x8 vh = *reinterpret_cast<const bf16x8*>(ph + off);
                bf16x8 vl = *reinterpret_cast<const bf16x8*>(pl + off);
#pragma unroll
                for (int u = 0; u < 8; ++u) {
                    float v = bf2f(vh[u]) + bf2f(vl[u]);
                    dwacc[c8 * 8 + u] = fmaf(v, dwW[ij * CI + c + u], dwacc[c8 * 8 + u]);
                }
            }
        }
    }
#pragma unroll
    for (int c8 = 0; c8 < CI / 32; ++c8) {
        bf16x8 hv;
#pragma unroll
        for (int u = 0; u < 8; ++u) hv[u] = f2bf(dwacc[c8 * 8 + u]);
        int byte = px * (CI * 2) + (cb + c8 * 8) * 2;
        int sz = byte ^ ((px & 7) << 4);
        *reinterpret_cast<bf16x8*>(ab + sz) = hv;
    }
    __syncthreads();
    f32x4 acc[4][2];
#pragma unroll
    for (int mt = 0; mt < 4; ++mt)
#pragma unroll
        for (int nn = 0; nn < 2; ++nn) acc[mt][nn] = f32x4{0.f, 0.f, 0.f, 0.f};
    const int co0 = w * 32 + m;
#pragma unroll
    for (int kc = 0; kc < CI / 32; ++kc) {
        bf16x8 av[4];
#pragma unroll
        for (int mt = 0; mt < 4; ++mt) {
            int prow = mt * 16 + m;
            int byte = prow * (CI * 2) + (kc * 32 + g * 8) * 2;
            int sz = byte ^ ((prow & 7) << 4);
            av[mt] = *reinterpret_cast<const bf16x8*>(ab + sz);
        }
#pragma unroll
        for (int nn = 0; nn < 2; ++nn) {
            bf16x8 bv = *reinterpret_cast<const bf16x8*>(pwt + (size_t)(co0 + nn * 16) * CI + kc * 32 + g * 8);
#pragma unroll
            for (int mt = 0; mt < 4; ++mt)
                acc[mt][nn] = __builtin_amdgcn_mfma_f32_16x16x32_bf16(av[mt], bv, acc[mt][nn], 0, 0, 0);
        }
    }
    float db0 = db[co0], db1 = db[co0 + 16];
    float mx[4][4];
#pragma unroll
    for (int mt = 0; mt < 4; ++mt)
#pragma unroll
        for (int r = 0; r < 4; ++r) {
            acc[mt][0][r] += db0;
            acc[mt][1][r] += db1;
            float v = fmaxf(acc[mt][0][r], acc[mt][1][r]);
#pragma unroll
            for (int o = 1; o <= 8; o <<= 1) v = fmaxf(v, __shfl_xor(v, o));
            mx[mt][r] = v;
        }
    if (m == 0) {
#pragma unroll
        for (int mt = 0; mt < 4; ++mt)
#pragma unroll
            for (int r = 0; r < 4; ++r) red[0][w][mt * 16 + g * 4 + r] = mx[mt][r];
    }
    __syncthreads();
    float sume[4][4];
#pragma unroll
    for (int mt = 0; mt < 4; ++mt)
#pragma unroll
        for (int r = 0; r < 4; ++r) {
            int p = mt * 16 + g * 4 + r;
            float M = fmaxf(fmaxf(red[0][0][p], red[0][1][p]), fmaxf(red[0][2][p], red[0][3][p]));
            acc[mt][0][r] = expf(acc[mt][0][r] - M);
            acc[mt][1][r] = expf(acc[mt][1][r] - M);
            float s = acc[mt][0][r] + acc[mt][1][r];
#pragma unroll
            for (int o = 1; o <= 8; o <<= 1) s += __shfl_xor(s, o);
            sume[mt][r] = s;
        }
    if (m == 0) {
#pragma unroll
        for (int mt = 0; mt < 4; ++mt)
#pragma unroll
            for (int r = 0; r < 4; ++r) red[1][w][mt * 16 + g * 4 + r] = sume[mt][r];
    }
    __syncthreads();
#pragma unroll
    for (int mt = 0; mt < 4; ++mt)
#pragma unroll
        for (int r = 0; r < 4; ++r) {
            int p = mt * 16 + g * 4 + r;
            float S = red[1][0][p] + red[1][1][p] + red[1][2][p] + red[1][3][p];
            float inv = 1.0f / S;
            size_t pix = ((size_t)b * 64 + P) * 64 + p;
            smout[pix * 128 + co0] = acc[mt][0][r] * inv;
            smout[pix * 128 + co0 + 16] = acc[mt][1][r] * inv;
        }
}

// MFMA split-bf16 implicit-GEMM 3x3 conv + bias + elu + gate, LDS-staged rows.
template <int CI>
__global__ __launch_bounds__(256, 4) void k_conv_lds(const short* __restrict__ in0h,
                                                     const short* __restrict__ in0l,
                                                     const short* __restrict__ in1h,
                                                     const short* __restrict__ in1l,
                                                     const short* __restrict__ wh,
                                                     const short* __restrict__ wl,
                                                     const float* __restrict__ bias,
                                                     const float* __restrict__ sm,
                                                     float* __restrict__ out) {
    const int bid = blockIdx.x;
    const int swz = (bid & 7) * 64 + (bid >> 3);   // XCD-contiguous rows
    const int b = swz >> 6, P = swz & 63;
    const int tid = threadIdx.x;
    const int w = tid >> 6, lane = tid & 63;
    const int m = lane & 15, g = lane >> 4;
    __shared__ short Sh[66 * 128];
    __shared__ short Sl[66 * 128];
    char* shb = (char*)Sh;
    char* slb = (char*)Sl;
    f32x4 acc[4][2];
#pragma unroll
    for (int mt = 0; mt < 4; ++mt)
#pragma unroll
        for (int nn = 0; nn < 2; ++nn) acc[mt][nn] = f32x4{0.f, 0.f, 0.f, 0.f};

#pragma unroll
    for (int half = 0; half < CI / 128; ++half) {
        const short* ih = (half == 0) ? in0h : in1h;
        const short* il = (half == 0) ? in0l : in1l;
        const size_t rbase0 = ((size_t)b * 66 + P) * 66 * 128;
#pragma unroll
        for (int i = 0; i < 3; ++i) {
            __syncthreads();
            const size_t rsrc = rbase0 + (size_t)i * 66 * 128;
#pragma unroll
            for (int e0 = 0; e0 < 1056; e0 += 256) {
                int e = e0 + tid;
                if (e < 1056) {
                    int px = e >> 4, c8 = e & 15;
                    int lin = px * 256 + c8 * 16;
                    int sz = lin ^ ((px & 7) << 4);
                    size_t so = rsrc + (size_t)px * 128 + c8 * 8;
                    *reinterpret_cast<bf16x8*>(shb + sz) = *reinterpret_cast<const bf16x8*>(ih + so);
                    *reinterpret_cast<bf16x8*>(slb + sz) = *reinterpret_cast<const bf16x8*>(il + so);
                }
            }
            __syncthreads();
#pragma unroll
            for (int j = 0; j < 3; ++j) {
                const int ij = i * 3 + j;
                const short* wph = wh + ((size_t)ij * 128 + w * 32 + m) * CI + half * 128 + g * 8;
                const short* wpl = wl + ((size_t)ij * 128 + w * 32 + m) * CI + half * 128 + g * 8;
#pragma unroll
                for (int ci0 = 0; ci0 < 128; ci0 += 32) {
                    bf16x8 bhv[2], blv[2];
#pragma unroll
                    for (int nn = 0; nn < 2; ++nn) {
                        bhv[nn] = *reinterpret_cast<const bf16x8*>(wph + (size_t)nn * 16 * CI + ci0);
                        blv[nn] = *reinterpret_cast<const bf16x8*>(wpl + (size_t)nn * 16 * CI + ci0);
                    }
                    bf16x8 ah[4], al[4];
#pragma unroll
                    for (int mt = 0; mt < 4; ++mt) {
                        int px = mt * 16 + m + j;
                        int lin = px * 256 + ci0 * 2 + g * 16;
                        int sz = lin ^ ((px & 7) << 4);
                        ah[mt] = *reinterpret_cast<const bf16x8*>(shb + sz);
                        al[mt] = *reinterpret_cast<const bf16x8*>(slb + sz);
                    }
#pragma unroll
                    for (int nn = 0; nn < 2; ++nn)
#pragma unroll
                        for (int mt = 0; mt < 4; ++mt) {
                            acc[mt][nn] = __builtin_amdgcn_mfma_f32_16x16x32_bf16(ah[mt], bhv[nn], acc[mt][nn], 0, 0, 0);
                            acc[mt][nn] = __builtin_amdgcn_mfma_f32_16x16x32_bf16(ah[mt], blv[nn], acc[mt][nn], 0, 0, 0);
                            acc[mt][nn] = __builtin_amdgcn_mfma_f32_16x16x32_bf16(al[mt], bhv[nn], acc[mt][nn], 0, 0, 0);
                        }
                }
            }
        }
    }
#pragma unroll
    for (int nn = 0; nn < 2; ++nn) {
        const int co = w * 32 + nn * 16 + m;
        const float bb = bias[co];
#pragma unroll
        for (int mt = 0; mt < 4; ++mt) {
#pragma unroll
            for (int r = 0; r < 4; ++r) {
                int Q = mt * 16 + g * 4 + r;
                size_t pix = ((size_t)b * 64 + P) * 64 + Q;
                float z = acc[mt][nn][r] + bb;
                z = z > 0.f ? z : expm1f(z);
                out[pix * 128 + co] = z * sm[pix * 128 + co];
            }
        }
    }
}

extern "C" void kernel_launch(void* const* d_in, const int* in_sizes, int n_in,
                              void* d_out, int out_size, void* d_ws, size_t ws_size,
                              hipStream_t stream) {
    const float* x    = (const float*)d_in[0];
    const float* mask = (const float*)d_in[1];
    const float* w1   = (const float*)d_in[2];
    const float* b1   = (const float*)d_in[3];
    const float* dw1  = (const float*)d_in[4];
    const float* pw1  = (const float*)d_in[5];
    const float* db1  = (const float*)d_in[6];
    const float* w2   = (const float*)d_in[7];
    const float* b2   = (const float*)d_in[8];
    const float* dw2  = (const float*)d_in[9];
    const float* pw2  = (const float*)d_in[10];
    const float* db2  = (const float*)d_in[11];

    float* out_a = (float*)d_out;            // (8,64,64,128)
    float* out_c = out_a + 4194304;          // (8,32,32,1024)

    char* wsb = (char*)d_ws;
    float* sp   = (float*)(wsb + BOFF_SP);
    float* invd = (float*)(wsb + BOFF_INVD);
    short* bfh  = (short*)(wsb + BOFF_BFH);
    short* bfl  = (short*)(wsb + BOFF_BFL);
    float* Tbuf = (float*)(wsb + BOFF_T);
    short* bph  = (short*)(wsb + BOFF_BPH);
    short* bpl  = (short*)(wsb + BOFF_BPL);
    float* yup  = (float*)(wsb + BOFF_YUP);
    float* smb  = (float*)(wsb + BOFF_SM);
    short* p3h  = (short*)(wsb + BOFF_P3H);
    short* p3l  = (short*)(wsb + BOFF_P3L);
    float* a1   = (float*)(wsb + BOFF_A1);
    short* xh   = (short*)(wsb + BOFF_XH);
    short* xl   = (short*)(wsb + BOFF_XL);
    short* wt1h = (short*)(wsb + BOFF_WT1H);
    short* wt1l = (short*)(wsb + BOFF_WT1L);
    short* wt2h = (short*)(wsb + BOFF_WT2H);
    short* wt2l = (short*)(wsb + BOFF_WT2L);
    short* pw1t = (short*)(wsb + BOFF_PW1B);
    short* pw2t = (short*)(wsb + BOFF_PW2B);
    float* m0   = (float*)(wsb + BOFF_M0);
    float* mmb  = (float*)(wsb + BOFF_MM);

    // phase A: mask + correlation (MFMA) + fuse + softmax
    k_mask_pool<<<8192, 256, 0, stream>>>(mask, m0);
    k_mask_dilate<<<32, 256, 0, stream>>>(m0, mmb);
    k_srcpad<<<4624, 256, 0, stream>>>(x, sp);
    k_invd<<<512, 256, 0, stream>>>(sp, invd);
    k_wt_pair<<<576, 256, 0, stream>>>(w1, wt1h, wt1l, 128);
    k_wt_pair<<<1152, 256, 0, stream>>>(w2, wt2h, wt2l, 256);
    k_pw_t<<<64, 256, 0, stream>>>(pw1, pw1t, 128);
    k_pw_t<<<128, 256, 0, stream>>>(pw2, pw2t, 256);
    k_corr_B<<<4608, 256, 0, stream>>>(sp, invd, bfh, bfl);
    k_corr_mfma<<<dim3(8, 16, 8), 256, 0, stream>>>(sp, bfh, bfl, out_c);
    k_fuse1<<<32768, 256, 0, stream>>>(out_c, Tbuf);
    k_fuse2<<<32768, 256, 0, stream>>>(Tbuf, out_c);
    k_deconv_B<<<4608, 256, 0, stream>>>(x, bph, bpl);
    k_softmax1024<<<8192, 256, 0, stream>>>(out_c, mmb, out_c);   // in-place, row-local
    // phase B: deconv (MFMA) -> yup
    hipMemsetAsync(yup, 0, (size_t)4194304 * sizeof(float), stream);
    k_deconv_mfma<<<dim3(9, 16, 8), 256, 0, stream>>>(out_c, bph, bpl, yup);
    // phase C: gated conv 1 (pair first, then MFMA dwpw, then conv)
    k_pair_pad<<<2178, 256, 0, stream>>>(yup, p3h, p3l);   // yup dead after this
    k_pair_pad<<<2178, 256, 0, stream>>>(x, xh, xl);       // overlaps dead yup tail
    k_dwpw_mfma<128><<<512, 256, 0, stream>>>(p3h, p3l, nullptr, nullptr,
                                              dw1, pw1t, db1, smb);
    k_conv_lds<128><<<512, 256, 0, stream>>>(p3h, p3l, nullptr, nullptr,
                                             wt1h, wt1l, b1, smb, a1);
    // phase D: gated conv 2 (concat(a1, x))
    k_pair_pad<<<2178, 256, 0, stream>>>(a1, p3h, p3l);
    k_dwpw_mfma<256><<<512, 256, 0, stream>>>(p3h, p3l, xh, xl,
                                              dw2, pw2t, db2, smb);
    k_conv_lds<256><<<512, 256, 0, stream>>>(p3h, p3l, xh, xl,
                                             wt2h, wt2l, b2, smb, out_a);
}

// Round 9
// 623.442 us; speedup vs baseline: 1.7593x; 1.0716x over previous
//
#include <hip/hip_runtime.h>
#include <hip/hip_bf16.h>

// B=8, H=W=64, C=128, rate=2 -> k=3, h=w=32, L=1024
// Workspace (72,433,664 bytes), time-multiplexed regions (liveness checked):
//  phase A/B: sp [0,4.73M) invd [4.73,5.26M) Bf [5.26,43.0M) T [0,33.55M)
//             Bp [0,37.75M) yup [37.75,54.53M)
//  phase C/D: SM [0,16.78M) P3 pair [16.78,34.62M) A1 [34.62,51.40M)
//             X pair [51.40,69.24M)
//  static:    weights [69.24,71.11M) m0/mm [71.11,71.17M)

#define BOFF_SP      0
#define BOFF_INVD    4734976
#define BOFF_BFH     5259264
#define BOFF_BFL     24133632
#define BOFF_T       0
#define BOFF_BPH     0
#define BOFF_BPL     18874368
#define BOFF_YUP     37748736
#define BOFF_SM      0
#define BOFF_P3H     16777216
#define BOFF_P3L     25698304
#define BOFF_A1      34619392
#define BOFF_XH      51396608
#define BOFF_XL      60317696
#define BOFF_WT1H    69238784
#define BOFF_WT1L    69533696
#define BOFF_WT2H    69828608
#define BOFF_WT2L    70418432
#define BOFF_PW1B    71008256
#define BOFF_PW2B    71041024
#define BOFF_M0      71106560
#define BOFF_MM      71139328

typedef float f32x4 __attribute__((ext_vector_type(4)));
typedef short bf16x8 __attribute__((ext_vector_type(8)));

__device__ __forceinline__ short f2bf(float f) {
    unsigned u = __float_as_uint(f);
    unsigned r = u + 0x7FFFu + ((u >> 16) & 1u);
    return (short)(r >> 16);
}
__device__ __forceinline__ float bf2f(short s) {
    return __uint_as_float(((unsigned)(unsigned short)s) << 16);
}
__device__ __forceinline__ void cvt8(const float4 v0, const float4 v1, bf16x8& h, bf16x8& l) {
    float a[8] = {v0.x, v0.y, v0.z, v0.w, v1.x, v1.y, v1.z, v1.w};
#pragma unroll
    for (int u = 0; u < 8; ++u) {
        short hh = f2bf(a[u]);
        h[u] = hh;
        l[u] = f2bf(a[u] - bf2f(hh));
    }
}

__global__ __launch_bounds__(256) void k_mask_pool(const float* __restrict__ mask, float* __restrict__ m0) {
    int blk = blockIdx.x;
    int b = blk >> 10, pq = blk & 1023, p = pq >> 5, q = pq & 31;
    int t = threadIdx.x, dy = t >> 4, dx = t & 15;
    float v = mask[((size_t)(b * 512 + p * 16 + dy)) * 512 + q * 16 + dx];
#pragma unroll
    for (int o = 32; o; o >>= 1) v = fmaxf(v, __shfl_xor(v, o));
    __shared__ float s[4];
    if ((t & 63) == 0) s[t >> 6] = v;
    __syncthreads();
    if (t == 0) m0[blk] = fmaxf(fmaxf(s[0], s[1]), fmaxf(s[2], s[3]));
}

__global__ void k_mask_dilate(const float* __restrict__ m0, float* __restrict__ mm) {
    int idx = blockIdx.x * 256 + threadIdx.x;
    if (idx >= 8192) return;
    int b = idx >> 10, pq = idx & 1023, p = pq >> 5, q = pq & 31;
    float v = -1e30f;
    for (int di = -1; di <= 1; ++di)
        for (int dj = -1; dj <= 1; ++dj) {
            int pp = p + di, qq = q + dj;
            if (pp >= 0 && pp < 32 && qq >= 0 && qq < 32)
                v = fmaxf(v, m0[(b << 10) + pp * 32 + qq]);
        }
    mm[idx] = 1.0f - v;
}

__global__ void k_srcpad(const float* __restrict__ x, float* __restrict__ sp) {
    int idx = blockIdx.x * 256 + threadIdx.x;
    if (idx >= 8 * 34 * 34 * 128) return;
    int c = idx & 127;
    int r = idx >> 7;
    int xx = r % 34; r /= 34;
    int yy = r % 34; int b = r / 34;
    float v = 0.f;
    if (yy >= 1 && yy <= 32 && xx >= 1 && xx <= 32)
        v = x[(((size_t)(b * 64 + (yy - 1) * 2)) * 64 + (xx - 1) * 2) * 128 + c];
    sp[idx] = v;
}

__global__ void k_invd(const float* __restrict__ sp, float* __restrict__ invd) {
    int idx = blockIdx.x * 256 + threadIdx.x;
    if (idx >= 1024 * 128) return;
    int c = idx & 127, l = idx >> 7, lh = l >> 5, lw = l & 31;
    float s = 0.f;
    for (int b = 0; b < 8; ++b)
#pragma unroll
        for (int i = 0; i < 3; ++i)
#pragma unroll
            for (int j = 0; j < 3; ++j) {
                float v = sp[(((size_t)(b * 34 + lh + i)) * 34 + (lw + j)) * 128 + c];
                s += v * v;
            }
    invd[idx] = 1.0f / fmaxf(s, 1e-8f);
}

// Bf[b][l][ij][c] = sp[b][lh+i][lw+j][c] * invd[l][c], split bf16 pair.
__global__ void k_corr_B(const float* __restrict__ sp, const float* __restrict__ invd,
                         short* __restrict__ bh, short* __restrict__ bl) {
    int idx = blockIdx.x * 256 + threadIdx.x;
    int c8 = idx & 15; int rest = idx >> 4;
    int ij = rest % 9; int rest2 = rest / 9;
    int l = rest2 & 1023, b = rest2 >> 10;
    int lh = l >> 5, lw = l & 31;
    int i = (ij >= 6) ? 2 : (ij >= 3 ? 1 : 0);
    int j = ij - 3 * i;
    int c0 = c8 * 8;
    const float* s = sp + (((size_t)(b * 34 + lh + i)) * 34 + (lw + j)) * 128 + c0;
    const float* dv = invd + l * 128 + c0;
    bf16x8 h, lo;
#pragma unroll
    for (int u = 0; u < 8; ++u) {
        float v = s[u] * dv[u];
        short hh = f2bf(v);
        h[u] = hh;
        lo[u] = f2bf(v - bf2f(hh));
    }
    size_t off = ((size_t)(b * 1024 + l)) * 1152 + ij * 128 + c0;
    *reinterpret_cast<bf16x8*>(bh + off) = h;
    *reinterpret_cast<bf16x8*>(bl + off) = lo;
}

// Bp[b][ij][c][l] = x[b][2lh+ip][2lw+jp][c] (0 OOB), split bf16 pair.
__global__ void k_deconv_B(const float* __restrict__ x, short* __restrict__ bh, short* __restrict__ bl) {
    int idx = blockIdx.x * 256 + threadIdx.x;
    int l8 = idx & 127; int rest = idx >> 7;
    int c = rest & 127; int rest2 = rest >> 7;
    int ij = rest2 % 9; int b = rest2 / 9;
    int ip = (ij >= 6) ? 2 : (ij >= 3 ? 1 : 0);
    int jp = ij - 3 * ip;
    int l0 = l8 * 8;
    int lh = l0 >> 5, lw0 = l0 & 31;
    int rr = 2 * lh + ip;
    bf16x8 h, lo;
#pragma unroll
    for (int u = 0; u < 8; ++u) {
        int ss = 2 * (lw0 + u) + jp;
        float v = (rr < 64 && ss < 64) ? x[(((size_t)(b * 64 + rr)) * 64 + ss) * 128 + c] : 0.f;
        short hh = f2bf(v);
        h[u] = hh;
        lo[u] = f2bf(v - bf2f(hh));
    }
    size_t off = (((size_t)(b * 9 + ij)) * 128 + c) * 1024 + l0;
    *reinterpret_cast<bf16x8*>(bh + off) = h;
    *reinterpret_cast<bf16x8*>(bl + off) = lo;
}

// corr MFMA (pipelined): per batch y[pq,l] = sum_k A[pq,k]*B[k,l]; M=N=1024, K=1152.
__global__ __launch_bounds__(256) void k_corr_mfma(const float* __restrict__ sp,
                                                   const short* __restrict__ bfh,
                                                   const short* __restrict__ bfl,
                                                   float* __restrict__ outy) {
    const int b = blockIdx.z, tm = blockIdx.y, tn = blockIdx.x;
    __shared__ short Ah[64][40];
    __shared__ short Al[64][40];
    const int tid = threadIdx.x;
    const int w = tid >> 6, lane = tid & 63, m = lane & 15, g = lane >> 4;
    f32x4 acc[4][2];
#pragma unroll
    for (int mf = 0; mf < 4; ++mf)
#pragma unroll
        for (int nn = 0; nn < 2; ++nn) acc[mf][nn] = f32x4{0.f, 0.f, 0.f, 0.f};
    const int srow = tid >> 2, scc = (tid & 3) * 8;
    const int pq = tm * 64 + srow, p = pq >> 5, q = pq & 31;
    const int col0 = tn * 128 + w * 32 + m;
    const size_t bB = (size_t)b * 1024;

    const size_t boff0 = (bB + col0) * 1152 + g * 8;
    const size_t boff1 = (bB + col0 + 16) * 1152 + g * 8;

    auto aptr = [&](int kt) -> const float* {
        int ij = kt >> 7;
        int i = (ij >= 6) ? 2 : (ij >= 3 ? 1 : 0);
        int j = ij - 3 * i;
        int c0 = (kt & 127) + scc;
        return sp + (((size_t)(b * 34 + p + i)) * 34 + (q + j)) * 128 + c0;
    };
    const float* ap = aptr(0);
    float4 a0 = *reinterpret_cast<const float4*>(ap);
    float4 a1 = *reinterpret_cast<const float4*>(ap + 4);
    bf16x8 nb0h = *reinterpret_cast<const bf16x8*>(bfh + boff0);
    bf16x8 nb0l = *reinterpret_cast<const bf16x8*>(bfl + boff0);
    bf16x8 nb1h = *reinterpret_cast<const bf16x8*>(bfh + boff1);
    bf16x8 nb1l = *reinterpret_cast<const bf16x8*>(bfl + boff1);

    for (int kt = 0; kt < 1152; kt += 32) {
        bf16x8 hh, ll;
        cvt8(a0, a1, hh, ll);
        __syncthreads();
        *reinterpret_cast<bf16x8*>(&Ah[srow][scc]) = hh;
        *reinterpret_cast<bf16x8*>(&Al[srow][scc]) = ll;
        __syncthreads();
        const int ktn = (kt + 32 < 1152) ? kt + 32 : kt;
        bf16x8 cb0h = nb0h, cb0l = nb0l, cb1h = nb1h, cb1l = nb1l;
        const float* apn = aptr(ktn);
        a0 = *reinterpret_cast<const float4*>(apn);
        a1 = *reinterpret_cast<const float4*>(apn + 4);
        nb0h = *reinterpret_cast<const bf16x8*>(bfh + boff0 + ktn);
        nb0l = *reinterpret_cast<const bf16x8*>(bfl + boff0 + ktn);
        nb1h = *reinterpret_cast<const bf16x8*>(bfh + boff1 + ktn);
        nb1l = *reinterpret_cast<const bf16x8*>(bfl + boff1 + ktn);

        bf16x8 ah[4], al[4];
#pragma unroll
        for (int mf = 0; mf < 4; ++mf) {
            ah[mf] = *reinterpret_cast<const bf16x8*>(&Ah[mf * 16 + m][g * 8]);
            al[mf] = *reinterpret_cast<const bf16x8*>(&Al[mf * 16 + m][g * 8]);
        }
#pragma unroll
        for (int mf = 0; mf < 4; ++mf) {
            acc[mf][0] = __builtin_amdgcn_mfma_f32_16x16x32_bf16(ah[mf], cb0h, acc[mf][0], 0, 0, 0);
            acc[mf][0] = __builtin_amdgcn_mfma_f32_16x16x32_bf16(al[mf], cb0h, acc[mf][0], 0, 0, 0);
            acc[mf][0] = __builtin_amdgcn_mfma_f32_16x16x32_bf16(ah[mf], cb0l, acc[mf][0], 0, 0, 0);
            acc[mf][1] = __builtin_amdgcn_mfma_f32_16x16x32_bf16(ah[mf], cb1h, acc[mf][1], 0, 0, 0);
            acc[mf][1] = __builtin_amdgcn_mfma_f32_16x16x32_bf16(al[mf], cb1h, acc[mf][1], 0, 0, 0);
            acc[mf][1] = __builtin_amdgcn_mfma_f32_16x16x32_bf16(ah[mf], cb1l, acc[mf][1], 0, 0, 0);
        }
    }
#pragma unroll
    for (int mf = 0; mf < 4; ++mf) {
        int row = tm * 64 + mf * 16 + g * 4;
#pragma unroll
        for (int nn = 0; nn < 2; ++nn) {
            int col = col0 + nn * 16;
#pragma unroll
            for (int r = 0; r < 4; ++r)
                outy[((size_t)b << 20) + (size_t)(row + r) * 1024 + col] = acc[mf][nn][r];
        }
    }
}

// deconv MFMA (pipelined): per batch Z[uv,kcol] = sum_l y[uv,l]*Bp[kcol,l]; K=1024.
__global__ __launch_bounds__(256) void k_deconv_mfma(const float* __restrict__ yprob,
                                                     const short* __restrict__ bph,
                                                     const short* __restrict__ bpl,
                                                     float* __restrict__ yup) {
    const int b = blockIdx.z, tm = blockIdx.y, tn = blockIdx.x;   // tn = ij in 0..8
    __shared__ short Ah[64][40];
    __shared__ short Al[64][40];
    const int tid = threadIdx.x;
    const int w = tid >> 6, lane = tid & 63, m = lane & 15, g = lane >> 4;
    f32x4 acc[4][2];
#pragma unroll
    for (int mf = 0; mf < 4; ++mf)
#pragma unroll
        for (int nn = 0; nn < 2; ++nn) acc[mf][nn] = f32x4{0.f, 0.f, 0.f, 0.f};
    const int srow = tid >> 2, scc = (tid & 3) * 8;
    const int uvs = tm * 64 + srow;
    const int col0 = tn * 128 + w * 32 + m;

    const float* abase = yprob + ((size_t)b << 20) + (size_t)uvs * 1024 + scc;
    const size_t boff0 = ((size_t)b * 1152 + col0) * 1024 + g * 8;
    const size_t boff1 = ((size_t)b * 1152 + col0 + 16) * 1024 + g * 8;

    float4 a0 = *reinterpret_cast<const float4*>(abase);
    float4 a1 = *reinterpret_cast<const float4*>(abase + 4);
    bf16x8 nb0h = *reinterpret_cast<const bf16x8*>(bph + boff0);
    bf16x8 nb0l = *reinterpret_cast<const bf16x8*>(bpl + boff0);
    bf16x8 nb1h = *reinterpret_cast<const bf16x8*>(bph + boff1);
    bf16x8 nb1l = *reinterpret_cast<const bf16x8*>(bpl + boff1);

    for (int kt = 0; kt < 1024; kt += 32) {
        bf16x8 hh, ll;
        cvt8(a0, a1, hh, ll);
        __syncthreads();
        *reinterpret_cast<bf16x8*>(&Ah[srow][scc]) = hh;
        *reinterpret_cast<bf16x8*>(&Al[srow][scc]) = ll;
        __syncthreads();
        const int ktn = (kt + 32 < 1024) ? kt + 32 : kt;
        bf16x8 cb0h = nb0h, cb0l = nb0l, cb1h = nb1h, cb1l = nb1l;
        a0 = *reinterpret_cast<const float4*>(abase + ktn);
        a1 = *reinterpret_cast<const float4*>(abase + ktn + 4);
        nb0h = *reinterpret_cast<const bf16x8*>(bph + boff0 + ktn);
        nb0l = *reinterpret_cast<const bf16x8*>(bpl + boff0 + ktn);
        nb1h = *reinterpret_cast<const bf16x8*>(bph + boff1 + ktn);
        nb1l = *reinterpret_cast<const bf16x8*>(bpl + boff1 + ktn);

        bf16x8 ah[4], al[4];
#pragma unroll
        for (int mf = 0; mf < 4; ++mf) {
            ah[mf] = *reinterpret_cast<const bf16x8*>(&Ah[mf * 16 + m][g * 8]);
            al[mf] = *reinterpret_cast<const bf16x8*>(&Al[mf * 16 + m][g * 8]);
        }
#pragma unroll
        for (int mf = 0; mf < 4; ++mf) {
            acc[mf][0] = __builtin_amdgcn_mfma_f32_16x16x32_bf16(ah[mf], cb0h, acc[mf][0], 0, 0, 0);
            acc[mf][0] = __builtin_amdgcn_mfma_f32_16x16x32_bf16(al[mf], cb0h, acc[mf][0], 0, 0, 0);
            acc[mf][0] = __builtin_amdgcn_mfma_f32_16x16x32_bf16(ah[mf], cb0l, acc[mf][0], 0, 0, 0);
            acc[mf][1] = __builtin_amdgcn_mfma_f32_16x16x32_bf16(ah[mf], cb1h, acc[mf][1], 0, 0, 0);
            acc[mf][1] = __builtin_amdgcn_mfma_f32_16x16x32_bf16(al[mf], cb1h, acc[mf][1], 0, 0, 0);
            acc[mf][1] = __builtin_amdgcn_mfma_f32_16x16x32_bf16(ah[mf], cb1l, acc[mf][1], 0, 0, 0);
        }
    }
    const int ip = (tn >= 6) ? 2 : (tn >= 3 ? 1 : 0);
    const int jp = tn - 3 * ip;
#pragma unroll
    for (int mf = 0; mf < 4; ++mf) {
        int uvb = tm * 64 + mf * 16 + g * 4;
#pragma unroll
        for (int nn = 0; nn < 2; ++nn) {
            int c = w * 32 + nn * 16 + m;
#pragma unroll
            for (int r = 0; r < 4; ++r) {
                int uv = uvb + r;
                int uu = uv >> 5, vv = uv & 31;
                int P = 2 * uu + ip, Q = 2 * vv + jp;
                if (P < 64 && Q < 64)
                    atomicAdd(&yup[(((size_t)(b * 64 + P)) * 64 + Q) * 128 + c], acc[mf][nn][r]);
            }
        }
    }
}

__global__ void k_fuse1(const float* __restrict__ in, float* __restrict__ out) {
    size_t idx = (size_t)blockIdx.x * 256 + threadIdx.x;
    if (idx >= (size_t)8 * 1024 * 1024) return;
    int t = (int)(idx & 1023);
    int s = (int)((idx >> 10) & 1023);
    int b = (int)(idx >> 20);
    const float* base = in + ((size_t)b << 20);
    float v = base[(size_t)s * 1024 + t];
    if (s > 0 && t > 0) v += base[(size_t)(s - 1) * 1024 + (t - 1)];
    if (s < 1023 && t < 1023) v += base[(size_t)(s + 1) * 1024 + (t + 1)];
    out[idx] = v;
}

__global__ void k_fuse2(const float* __restrict__ in, float* __restrict__ out) {
    size_t idx = (size_t)blockIdx.x * 256 + threadIdx.x;
    if (idx >= (size_t)8 * 1024 * 1024) return;
    int t = (int)(idx & 1023);
    int s = (int)((idx >> 10) & 1023);
    int b = (int)(idx >> 20);
    int m0 = ((s & 31) << 5) + (s >> 5);
    int n0 = ((t & 31) << 5) + (t >> 5);
    const float* base = in + ((size_t)b << 20);
    float v = 0.f;
#pragma unroll
    for (int d = -1; d <= 1; ++d) {
        int m = m0 + d, n = n0 + d;
        if (m >= 0 && m < 1024 && n >= 0 && n < 1024)
            v += base[(size_t)(((m & 31) << 5) + (m >> 5)) * 1024 + (((n & 31) << 5) + (n >> 5))];
    }
    out[idx] = v;
}

__global__ __launch_bounds__(256) void k_softmax1024(const float* __restrict__ yv,
                                                     const float* __restrict__ mm,
                                                     float* __restrict__ outc) {
    int row = blockIdx.x;
    const float* base = yv + (size_t)row * 1024;
    float mmv = mm[row];
    int t = threadIdx.x;
    float vals[4];
    float mx = -1e30f;
#pragma unroll
    for (int i = 0; i < 4; ++i) {
        vals[i] = base[t + i * 256] * mmv * 10.0f;
        mx = fmaxf(mx, vals[i]);
    }
#pragma unroll
    for (int o = 32; o; o >>= 1) mx = fmaxf(mx, __shfl_xor(mx, o));
    __shared__ float red[8];
    if ((t & 63) == 0) red[t >> 6] = mx;
    __syncthreads();
    mx = fmaxf(fmaxf(red[0], red[1]), fmaxf(red[2], red[3]));
    float s = 0.f;
#pragma unroll
    for (int i = 0; i < 4; ++i) {
        vals[i] = expf(vals[i] - mx);
        s += vals[i];
    }
#pragma unroll
    for (int o = 32; o; o >>= 1) s += __shfl_xor(s, o);
    if ((t & 63) == 0) red[4 + (t >> 6)] = s;
    __syncthreads();
    s = red[4] + red[5] + red[6] + red[7];
    float inv = mmv / s;
#pragma unroll
    for (int i = 0; i < 4; ++i)
        outc[(size_t)row * 1024 + t + i * 256] = vals[i] * inv;
}

// f32 image (8,64,64,128) -> padded bf16 hi/lo pair (8,66,66,128), zero halo
__global__ __launch_bounds__(256) void k_pair_pad(const float* __restrict__ in,
                                                  short* __restrict__ hi, short* __restrict__ lo) {
    int idx = blockIdx.x * 256 + threadIdx.x;   // [0, 8*66*66*16)
    int c8 = idx & 15;
    int r = idx >> 4;
    int pc = r % 66; r /= 66;
    int pr = r % 66; int b = r / 66;
    bf16x8 h, l;
    if (pr >= 1 && pr <= 64 && pc >= 1 && pc <= 64) {
        const float* s = in + (((size_t)(b * 64 + pr - 1)) * 64 + (pc - 1)) * 128 + c8 * 8;
        float4 v0 = *reinterpret_cast<const float4*>(s);
        float4 v1 = *reinterpret_cast<const float4*>(s + 4);
        cvt8(v0, v1, h, l);
    } else {
#pragma unroll
        for (int u = 0; u < 8; ++u) { h[u] = 0; l[u] = 0; }
    }
    size_t off = (size_t)idx * 8;
    *reinterpret_cast<bf16x8*>(hi + off) = h;
    *reinterpret_cast<bf16x8*>(lo + off) = l;
}

__global__ void k_wt_pair(const float* __restrict__ w, short* __restrict__ hi,
                          short* __restrict__ lo, int CI) {
    int idx = blockIdx.x * 256 + threadIdx.x;
    if (idx >= 9 * CI * 128) return;
    int ci = idx % CI; int rest = idx / CI;
    int co = rest & 127; int ij = rest >> 7;
    float v = w[((size_t)ij * CI + ci) * 128 + co];
    short h = f2bf(v);
    hi[idx] = h;
    lo[idx] = f2bf(v - bf2f(h));
}

// pw (1,1,CI,128) f32 -> transposed bf16 [co][ci]
__global__ void k_pw_t(const float* __restrict__ pw, short* __restrict__ out, int CI) {
    int idx = blockIdx.x * 256 + threadIdx.x;
    if (idx >= CI * 128) return;
    int co = idx & 127, ci = idx >> 7;
    out[(size_t)co * CI + ci] = f2bf(pw[idx]);
}

// Fused depthwise 3x3 + pointwise (MFMA, K=CI) + channel softmax -> smout f32.
template <int CI>
__global__ __launch_bounds__(256, 2) void k_dwpw_mfma(const short* __restrict__ in0h,
                                                      const short* __restrict__ in0l,
                                                      const short* __restrict__ in1h,
                                                      const short* __restrict__ in1l,
                                                      const float* __restrict__ dwW,
                                                      const short* __restrict__ pwt,
                                                      const float* __restrict__ db,
                                                      float* __restrict__ smout) {
    const int bid = blockIdx.x;
    const int swz = (bid & 7) * 64 + (bid >> 3);
    const int b = swz >> 6, P = swz & 63;
    const int t = threadIdx.x;
    const int w = t >> 6, lane = t & 63, m = lane & 15, g = lane >> 4;
    __shared__ short Adw[64 * CI];
    __shared__ float red[2][4][64];
    char* ab = (char*)Adw;
    const int px = lane;
    const int cb = w * (CI / 4);
    float dwacc[CI / 4];
#pragma unroll
    for (int u = 0; u < CI / 4; ++u) dwacc[u] = 0.f;
#pragma unroll
    for (int i = 0; i < 3; ++i) {
#pragma unroll
        for (int j = 0; j < 3; ++j) {
            const int ij = i * 3 + j;
#pragma unroll
            for (int c8 = 0; c8 < CI / 32; ++c8) {
                const int c = cb + c8 * 8;
                const short* ph = (CI == 256 && c >= 128) ? in1h : in0h;
                const short* pl = (CI == 256 && c >= 128) ? in1l : in0l;
                const int cc = (CI == 256 && c >= 128) ? (c - 128) : c;
                size_t off = (((size_t)b * 66 + P + i) * 66 + px + j) * 128 + cc;
                bf16x8 vh = *reinterpret_cast<const bf16x8*>(ph + off);
                bf16x8 vl = *reinterpret_cast<const bf16x8*>(pl + off);
#pragma unroll
                for (int u = 0; u < 8; ++u) {
                    float v = bf2f(vh[u]) + bf2f(vl[u]);
                    dwacc[c8 * 8 + u] = fmaf(v, dwW[ij * CI + c + u], dwacc[c8 * 8 + u]);
                }
            }
        }
    }
#pragma unroll
    for (int c8 = 0; c8 < CI / 32; ++c8) {
        bf16x8 hv;
#pragma unroll
        for (int u = 0; u < 8; ++u) hv[u] = f2bf(dwacc[c8 * 8 + u]);
        int byte = px * (CI * 2) + (cb + c8 * 8) * 2;
        int sz = byte ^ ((px & 7) << 4);
        *reinterpret_cast<bf16x8*>(ab + sz) = hv;
    }
    __syncthreads();
    f32x4 acc[4][2];
#pragma unroll
    for (int mt = 0; mt < 4; ++mt)
#pragma unroll
        for (int nn = 0; nn < 2; ++nn) acc[mt][nn] = f32x4{0.f, 0.f, 0.f, 0.f};
    const int co0 = w * 32 + m;
#pragma unroll
    for (int kc = 0; kc < CI / 32; ++kc) {
        bf16x8 av[4];
#pragma unroll
        for (int mt = 0; mt < 4; ++mt) {
            int prow = mt * 16 + m;
            int byte = prow * (CI * 2) + (kc * 32 + g * 8) * 2;
            int sz = byte ^ ((prow & 7) << 4);
            av[mt] = *reinterpret_cast<const bf16x8*>(ab + sz);
        }
#pragma unroll
        for (int nn = 0; nn < 2; ++nn) {
            bf16x8 bv = *reinterpret_cast<const bf16x8*>(pwt + (size_t)(co0 + nn * 16) * CI + kc * 32 + g * 8);
#pragma unroll
            for (int mt = 0; mt < 4; ++mt)
                acc[mt][nn] = __builtin_amdgcn_mfma_f32_16x16x32_bf16(av[mt], bv, acc[mt][nn], 0, 0, 0);
        }
    }
    float db0 = db[co0], db1 = db[co0 + 16];
    float mx[4][4];
#pragma unroll
    for (int mt = 0; mt < 4; ++mt)
#pragma unroll
        for (int r = 0; r < 4; ++r) {
            acc[mt][0][r] += db0;
            acc[mt][1][r] += db1;
            float v = fmaxf(acc[mt][0][r], acc[mt][1][r]);
#pragma unroll
            for (int o = 1; o <= 8; o <<= 1) v = fmaxf(v, __shfl_xor(v, o));
            mx[mt][r] = v;
        }
    if (m == 0) {
#pragma unroll
        for (int mt = 0; mt < 4; ++mt)
#pragma unroll
            for (int r = 0; r < 4; ++r) red[0][w][mt * 16 + g * 4 + r] = mx[mt][r];
    }
    __syncthreads();
    float sume[4][4];
#pragma unroll
    for (int mt = 0; mt < 4; ++mt)
#pragma unroll
        for (int r = 0; r < 4; ++r) {
            int p = mt * 16 + g * 4 + r;
            float M = fmaxf(fmaxf(red[0][0][p], red[0][1][p]), fmaxf(red[0][2][p], red[0][3][p]));
            acc[mt][0][r] = expf(acc[mt][0][r] - M);
            acc[mt][1][r] = expf(acc[mt][1][r] - M);
            float s = acc[mt][0][r] + acc[mt][1][r];
#pragma unroll
            for (int o = 1; o <= 8; o <<= 1) s += __shfl_xor(s, o);
            sume[mt][r] = s;
        }
    if (m == 0) {
#pragma unroll
        for (int mt = 0; mt < 4; ++mt)
#pragma unroll
            for (int r = 0; r < 4; ++r) red[1][w][mt * 16 + g * 4 + r] = sume[mt][r];
    }
    __syncthreads();
#pragma unroll
    for (int mt = 0; mt < 4; ++mt)
#pragma unroll
        for (int r = 0; r < 4; ++r) {
            int p = mt * 16 + g * 4 + r;
            float S = red[1][0][p] + red[1][1][p] + red[1][2][p] + red[1][3][p];
            float inv = 1.0f / S;
            size_t pix = ((size_t)b * 64 + P) * 64 + p;
            smout[pix * 128 + co0] = acc[mt][0][r] * inv;
            smout[pix * 128 + co0 + 16] = acc[mt][1][r] * inv;
        }
}

// MFMA split-bf16 implicit-GEMM 3x3 conv + bias + elu + gate, LDS-staged rows.
// Grid 1024: block = (row, co-half). 4 blocks/CU (vs 2 at grid 512) -> cross-block
// wave overlap hides the stage->barrier->compute chain. XCD swizzle keeps both
// co-halves of a row + all rows of a batch on one XCD (staged row L2-shared).
template <int CI>
__global__ __launch_bounds__(256, 4) void k_conv_lds(const short* __restrict__ in0h,
                                                     const short* __restrict__ in0l,
                                                     const short* __restrict__ in1h,
                                                     const short* __restrict__ in1l,
                                                     const short* __restrict__ wh,
                                                     const short* __restrict__ wl,
                                                     const float* __restrict__ bias,
                                                     const float* __restrict__ sm,
                                                     float* __restrict__ out) {
    const int bid = blockIdx.x;
    const int idx = (bid & 7) * 128 + (bid >> 3);   // bijective, XCD-contiguous
    const int row = idx >> 1, cohalf = idx & 1;
    const int b = row >> 6, P = row & 63;
    const int tid = threadIdx.x;
    const int w = tid >> 6, lane = tid & 63;
    const int m = lane & 15, g = lane >> 4;
    __shared__ short Sh[66 * 128];
    __shared__ short Sl[66 * 128];
    char* shb = (char*)Sh;
    char* slb = (char*)Sl;
    f32x4 acc[4];
#pragma unroll
    for (int mt = 0; mt < 4; ++mt) acc[mt] = f32x4{0.f, 0.f, 0.f, 0.f};
    const int cow = cohalf * 64 + w * 16 + m;   // this wave's co

#pragma unroll
    for (int half = 0; half < CI / 128; ++half) {
        const short* ih = (half == 0) ? in0h : in1h;
        const short* il = (half == 0) ? in0l : in1l;
        const size_t rbase0 = ((size_t)b * 66 + P) * 66 * 128;
#pragma unroll
        for (int i = 0; i < 3; ++i) {
            __syncthreads();
            const size_t rsrc = rbase0 + (size_t)i * 66 * 128;
#pragma unroll
            for (int e0 = 0; e0 < 1056; e0 += 256) {
                int e = e0 + tid;
                if (e < 1056) {
                    int px = e >> 4, c8 = e & 15;
                    int lin = px * 256 + c8 * 16;
                    int sz = lin ^ ((px & 7) << 4);
                    size_t so = rsrc + (size_t)px * 128 + c8 * 8;
                    *reinterpret_cast<bf16x8*>(shb + sz) = *reinterpret_cast<const bf16x8*>(ih + so);
                    *reinterpret_cast<bf16x8*>(slb + sz) = *reinterpret_cast<const bf16x8*>(il + so);
                }
            }
            __syncthreads();
#pragma unroll
            for (int j = 0; j < 3; ++j) {
                const int ij = i * 3 + j;
                const short* wph = wh + ((size_t)ij * 128 + cow) * CI + half * 128 + g * 8;
                const short* wpl = wl + ((size_t)ij * 128 + cow) * CI + half * 128 + g * 8;
#pragma unroll
                for (int ci0 = 0; ci0 < 128; ci0 += 32) {
                    bf16x8 bh = *reinterpret_cast<const bf16x8*>(wph + ci0);
                    bf16x8 bl = *reinterpret_cast<const bf16x8*>(wpl + ci0);
                    bf16x8 ah[4], al[4];
#pragma unroll
                    for (int mt = 0; mt < 4; ++mt) {
                        int px = mt * 16 + m + j;
                        int lin = px * 256 + ci0 * 2 + g * 16;
                        int sz = lin ^ ((px & 7) << 4);
                        ah[mt] = *reinterpret_cast<const bf16x8*>(shb + sz);
                        al[mt] = *reinterpret_cast<const bf16x8*>(slb + sz);
                    }
#pragma unroll
                    for (int mt = 0; mt < 4; ++mt) {
                        acc[mt] = __builtin_amdgcn_mfma_f32_16x16x32_bf16(ah[mt], bh, acc[mt], 0, 0, 0);
                        acc[mt] = __builtin_amdgcn_mfma_f32_16x16x32_bf16(ah[mt], bl, acc[mt], 0, 0, 0);
                        acc[mt] = __builtin_amdgcn_mfma_f32_16x16x32_bf16(al[mt], bh, acc[mt], 0, 0, 0);
                    }
                }
            }
        }
    }
    const float bb = bias[cow];
#pragma unroll
    for (int mt = 0; mt < 4; ++mt) {
#pragma unroll
        for (int r = 0; r < 4; ++r) {
            int Q = mt * 16 + g * 4 + r;
            size_t pix = ((size_t)b * 64 + P) * 64 + Q;
            float z = acc[mt][r] + bb;
            z = z > 0.f ? z : expm1f(z);
            out[pix * 128 + cow] = z * sm[pix * 128 + cow];
        }
    }
}

extern "C" void kernel_launch(void* const* d_in, const int* in_sizes, int n_in,
                              void* d_out, int out_size, void* d_ws, size_t ws_size,
                              hipStream_t stream) {
    const float* x    = (const float*)d_in[0];
    const float* mask = (const float*)d_in[1];
    const float* w1   = (const float*)d_in[2];
    const float* b1   = (const float*)d_in[3];
    const float* dw1  = (const float*)d_in[4];
    const float* pw1  = (const float*)d_in[5];
    const float* db1  = (const float*)d_in[6];
    const float* w2   = (const float*)d_in[7];
    const float* b2   = (const float*)d_in[8];
    const float* dw2  = (const float*)d_in[9];
    const float* pw2  = (const float*)d_in[10];
    const float* db2  = (const float*)d_in[11];

    float* out_a = (float*)d_out;            // (8,64,64,128)
    float* out_c = out_a + 4194304;          // (8,32,32,1024)

    char* wsb = (char*)d_ws;
    float* sp   = (float*)(wsb + BOFF_SP);
    float* invd = (float*)(wsb + BOFF_INVD);
    short* bfh  = (short*)(wsb + BOFF_BFH);
    short* bfl  = (short*)(wsb + BOFF_BFL);
    float* Tbuf = (float*)(wsb + BOFF_T);
    short* bph  = (short*)(wsb + BOFF_BPH);
    short* bpl  = (short*)(wsb + BOFF_BPL);
    float* yup  = (float*)(wsb + BOFF_YUP);
    float* smb  = (float*)(wsb + BOFF_SM);
    short* p3h  = (short*)(wsb + BOFF_P3H);
    short* p3l  = (short*)(wsb + BOFF_P3L);
    float* a1   = (float*)(wsb + BOFF_A1);
    short* xh   = (short*)(wsb + BOFF_XH);
    short* xl   = (short*)(wsb + BOFF_XL);
    short* wt1h = (short*)(wsb + BOFF_WT1H);
    short* wt1l = (short*)(wsb + BOFF_WT1L);
    short* wt2h = (short*)(wsb + BOFF_WT2H);
    short* wt2l = (short*)(wsb + BOFF_WT2L);
    short* pw1t = (short*)(wsb + BOFF_PW1B);
    short* pw2t = (short*)(wsb + BOFF_PW2B);
    float* m0   = (float*)(wsb + BOFF_M0);
    float* mmb  = (float*)(wsb + BOFF_MM);

    // phase A: mask + correlation (MFMA) + fuse + softmax
    k_mask_pool<<<8192, 256, 0, stream>>>(mask, m0);
    k_mask_dilate<<<32, 256, 0, stream>>>(m0, mmb);
    k_srcpad<<<4624, 256, 0, stream>>>(x, sp);
    k_invd<<<512, 256, 0, stream>>>(sp, invd);
    k_wt_pair<<<576, 256, 0, stream>>>(w1, wt1h, wt1l, 128);
    k_wt_pair<<<1152, 256, 0, stream>>>(w2, wt2h, wt2l, 256);
    k_pw_t<<<64, 256, 0, stream>>>(pw1, pw1t, 128);
    k_pw_t<<<128, 256, 0, stream>>>(pw2, pw2t, 256);
    k_corr_B<<<4608, 256, 0, stream>>>(sp, invd, bfh, bfl);
    k_corr_mfma<<<dim3(8, 16, 8), 256, 0, stream>>>(sp, bfh, bfl, out_c);
    k_fuse1<<<32768, 256, 0, stream>>>(out_c, Tbuf);
    k_fuse2<<<32768, 256, 0, stream>>>(Tbuf, out_c);
    k_deconv_B<<<4608, 256, 0, stream>>>(x, bph, bpl);
    k_softmax1024<<<8192, 256, 0, stream>>>(out_c, mmb, out_c);   // in-place, row-local
    // phase B: deconv (MFMA) -> yup
    hipMemsetAsync(yup, 0, (size_t)4194304 * sizeof(float), stream);
    k_deconv_mfma<<<dim3(9, 16, 8), 256, 0, stream>>>(out_c, bph, bpl, yup);
    // phase C: gated conv 1 (pair first, then MFMA dwpw, then conv)
    k_pair_pad<<<2178, 256, 0, stream>>>(yup, p3h, p3l);   // yup dead after this
    k_pair_pad<<<2178, 256, 0, stream>>>(x, xh, xl);       // overlaps dead yup tail
    k_dwpw_mfma<128><<<512, 256, 0, stream>>>(p3h, p3l, nullptr, nullptr,
                                              dw1, pw1t, db1, smb);
    k_conv_lds<128><<<1024, 256, 0, stream>>>(p3h, p3l, nullptr, nullptr,
                                              wt1h, wt1l, b1, smb, a1);
    // phase D: gated conv 2 (concat(a1, x))
    k_pair_pad<<<2178, 256, 0, stream>>>(a1, p3h, p3l);
    k_dwpw_mfma<256><<<512, 256, 0, stream>>>(p3h, p3l, xh, xl,
                                              dw2, pw2t, db2, smb);
    k_conv_lds<256><<<1024, 256, 0, stream>>>(p3h, p3l, xh, xl,
                                              wt2h, wt2l, b2, smb, out_a);
}

// Round 11
// 604.025 us; speedup vs baseline: 1.8159x; 1.0321x over previous
//
#include <hip/hip_runtime.h>
#include <hip/hip_bf16.h>

// B=8, H=W=64, C=128, rate=2 -> k=3, h=w=32, L=1024
// Workspace (72,433,664 bytes), time-multiplexed (liveness checked):
//  phase A: sp [0,4.73M) invd [4.73,5.26M) sph [5.26,7.63M) spl [7.63,10.0M)
//           Bf pair [10.0,47.74M)
//  fuse:    T [0,33.55M) (sp/invd/sppair/Bf dead after corr)
//  deconv:  Bp16 [0,18.87M) yp16 [18.87,35.65M) yup [37.75,54.53M)
//  phase C/D: SM [0,16.78M) P3 [16.78,34.62M) A1 [34.62,51.40M) X [51.40,69.24M)
//  static:  weights [69.24,71.11M) m0/mm [71.11,71.17M)

#define BOFF_SP      0
#define BOFF_INVD    4734976
#define BOFF_SPH     5259264
#define BOFF_SPL     7626752
#define BOFF_BFH     9994240
#define BOFF_BFL     28868608
#define BOFF_T       0
#define BOFF_BP16    0
#define BOFF_YP16    18874368
#define BOFF_YUP     37748736
#define BOFF_SM      0
#define BOFF_P3H     16777216
#define BOFF_P3L     25698304
#define BOFF_A1      34619392
#define BOFF_XH      51396608
#define BOFF_XL      60317696
#define BOFF_WT1H    69238784
#define BOFF_WT1L    69533696
#define BOFF_WT2H    69828608
#define BOFF_WT2L    70418432
#define BOFF_PW1B    71008256
#define BOFF_PW2B    71041024
#define BOFF_M0      71106560
#define BOFF_MM      71139328

typedef float f32x4 __attribute__((ext_vector_type(4)));
typedef short bf16x8 __attribute__((ext_vector_type(8)));
typedef _Float16 f16x8 __attribute__((ext_vector_type(8)));

__device__ __forceinline__ short f2bf(float f) {
    unsigned u = __float_as_uint(f);
    unsigned r = u + 0x7FFFu + ((u >> 16) & 1u);
    return (short)(r >> 16);
}
__device__ __forceinline__ float bf2f(short s) {
    return __uint_as_float(((unsigned)(unsigned short)s) << 16);
}
__device__ __forceinline__ void cvt8(const float4 v0, const float4 v1, bf16x8& h, bf16x8& l) {
    float a[8] = {v0.x, v0.y, v0.z, v0.w, v1.x, v1.y, v1.z, v1.w};
#pragma unroll
    for (int u = 0; u < 8; ++u) {
        short hh = f2bf(a[u]);
        h[u] = hh;
        l[u] = f2bf(a[u] - bf2f(hh));
    }
}

__global__ __launch_bounds__(256) void k_mask_pool(const float* __restrict__ mask, float* __restrict__ m0) {
    int blk = blockIdx.x;
    int b = blk >> 10, pq = blk & 1023, p = pq >> 5, q = pq & 31;
    int t = threadIdx.x, dy = t >> 4, dx = t & 15;
    float v = mask[((size_t)(b * 512 + p * 16 + dy)) * 512 + q * 16 + dx];
#pragma unroll
    for (int o = 32; o; o >>= 1) v = fmaxf(v, __shfl_xor(v, o));
    __shared__ float s[4];
    if ((t & 63) == 0) s[t >> 6] = v;
    __syncthreads();
    if (t == 0) m0[blk] = fmaxf(fmaxf(s[0], s[1]), fmaxf(s[2], s[3]));
}

__global__ void k_mask_dilate(const float* __restrict__ m0, float* __restrict__ mm) {
    int idx = blockIdx.x * 256 + threadIdx.x;
    if (idx >= 8192) return;
    int b = idx >> 10, pq = idx & 1023, p = pq >> 5, q = pq & 31;
    float v = -1e30f;
    for (int di = -1; di <= 1; ++di)
        for (int dj = -1; dj <= 1; ++dj) {
            int pp = p + di, qq = q + dj;
            if (pp >= 0 && pp < 32 && qq >= 0 && qq < 32)
                v = fmaxf(v, m0[(b << 10) + pp * 32 + qq]);
        }
    mm[idx] = 1.0f - v;
}

__global__ void k_srcpad(const float* __restrict__ x, float* __restrict__ sp) {
    int idx = blockIdx.x * 256 + threadIdx.x;
    if (idx >= 8 * 34 * 34 * 128) return;
    int c = idx & 127;
    int r = idx >> 7;
    int xx = r % 34; r /= 34;
    int yy = r % 34; int b = r / 34;
    float v = 0.f;
    if (yy >= 1 && yy <= 32 && xx >= 1 && xx <= 32)
        v = x[(((size_t)(b * 64 + (yy - 1) * 2)) * 64 + (xx - 1) * 2) * 128 + c];
    sp[idx] = v;
}

// sp f32 -> bf16 hi/lo pair (1,183,744 elems, 8/thread)
__global__ void k_pair_sp(const float* __restrict__ sp, short* __restrict__ hi, short* __restrict__ lo) {
    int idx = blockIdx.x * 256 + threadIdx.x;
    if (idx >= 147968) return;
    const float* s = sp + (size_t)idx * 8;
    float4 v0 = *reinterpret_cast<const float4*>(s);
    float4 v1 = *reinterpret_cast<const float4*>(s + 4);
    bf16x8 h, l;
    cvt8(v0, v1, h, l);
    *reinterpret_cast<bf16x8*>(hi + (size_t)idx * 8) = h;
    *reinterpret_cast<bf16x8*>(lo + (size_t)idx * 8) = l;
}

__global__ void k_invd(const float* __restrict__ sp, float* __restrict__ invd) {
    int idx = blockIdx.x * 256 + threadIdx.x;
    if (idx >= 1024 * 128) return;
    int c = idx & 127, l = idx >> 7, lh = l >> 5, lw = l & 31;
    float s = 0.f;
    for (int b = 0; b < 8; ++b)
#pragma unroll
        for (int i = 0; i < 3; ++i)
#pragma unroll
            for (int j = 0; j < 3; ++j) {
                float v = sp[(((size_t)(b * 34 + lh + i)) * 34 + (lw + j)) * 128 + c];
                s += v * v;
            }
    invd[idx] = 1.0f / fmaxf(s, 1e-8f);
}

// Bf[b][l][ij][c] = sp[b][lh+i][lw+j][c] * invd[l][c], split bf16 pair.
__global__ void k_corr_B(const float* __restrict__ sp, const float* __restrict__ invd,
                         short* __restrict__ bh, short* __restrict__ bl) {
    int idx = blockIdx.x * 256 + threadIdx.x;
    int c8 = idx & 15; int rest = idx >> 4;
    int ij = rest % 9; int rest2 = rest / 9;
    int l = rest2 & 1023, b = rest2 >> 10;
    int lh = l >> 5, lw = l & 31;
    int i = (ij >= 6) ? 2 : (ij >= 3 ? 1 : 0);
    int j = ij - 3 * i;
    int c0 = c8 * 8;
    const float* s = sp + (((size_t)(b * 34 + lh + i)) * 34 + (lw + j)) * 128 + c0;
    const float* dv = invd + l * 128 + c0;
    bf16x8 h, lo;
#pragma unroll
    for (int u = 0; u < 8; ++u) {
        float v = s[u] * dv[u];
        short hh = f2bf(v);
        h[u] = hh;
        lo[u] = f2bf(v - bf2f(hh));
    }
    size_t off = ((size_t)(b * 1024 + l)) * 1152 + ij * 128 + c0;
    *reinterpret_cast<bf16x8*>(bh + off) = h;
    *reinterpret_cast<bf16x8*>(bl + off) = lo;
}

// Bp16[b][ij][c][l] = x[b][2lh+ip][2lw+jp][c] (0 OOB), single fp16.
// 9,437,184 halves / 8 per thread = 1,179,648 threads (4608 blocks).
__global__ void k_deconv_B16(const float* __restrict__ x, _Float16* __restrict__ bp) {
    int idx = blockIdx.x * 256 + threadIdx.x;
    if (idx >= 1179648) return;
    int l8 = idx & 127; int rest = idx >> 7;
    int c = rest & 127; int rest2 = rest >> 7;
    int ij = rest2 % 9; int b = rest2 / 9;
    int ip = (ij >= 6) ? 2 : (ij >= 3 ? 1 : 0);
    int jp = ij - 3 * ip;
    int l0 = l8 * 8;
    int lh = l0 >> 5, lw0 = l0 & 31;
    int rr = 2 * lh + ip;
    f16x8 h;
#pragma unroll
    for (int u = 0; u < 8; ++u) {
        int ss = 2 * (lw0 + u) + jp;
        float v = (rr < 64 && ss < 64) ? x[(((size_t)(b * 64 + rr)) * 64 + ss) * 128 + c] : 0.f;
        h[u] = (_Float16)v;
    }
    size_t off = (((size_t)(b * 9 + ij)) * 128 + c) * 1024 + l0;
    *reinterpret_cast<f16x8*>(bp + off) = h;
}

// corr MFMA: M-tile 128, 512 thr / 8 waves (row-half x 4 col-groups).
// A staged from pre-paired sp (no cvt in loop); B split-bf16 pair, reg-prefetched.
__global__ __launch_bounds__(512) void k_corr_mfma(const short* __restrict__ sph,
                                                   const short* __restrict__ spl,
                                                   const short* __restrict__ bfh,
                                                   const short* __restrict__ bfl,
                                                   float* __restrict__ outy) {
    const int b = blockIdx.z, tm = blockIdx.y, tn = blockIdx.x;
    __shared__ short Ah[128][40];
    __shared__ short Al[128][40];
    const int tid = threadIdx.x;
    const int w = tid >> 6, lane = tid & 63, m = lane & 15, g = lane >> 4;
    const int rh = w & 1, cg = w >> 1;
    f32x4 acc[4][2];
#pragma unroll
    for (int mf = 0; mf < 4; ++mf)
#pragma unroll
        for (int nn = 0; nn < 2; ++nn) acc[mf][nn] = f32x4{0.f, 0.f, 0.f, 0.f};
    const int srow = tid >> 2, scc = (tid & 3) * 8;
    const int pq = tm * 128 + srow, p = pq >> 5, q = pq & 31;
    const int col0 = tn * 128 + cg * 32 + m;
    const size_t bB = (size_t)b * 1024;
    const size_t boff0 = (bB + col0) * 1152 + g * 8;
    const size_t boff1 = (bB + col0 + 16) * 1152 + g * 8;

    auto aoff = [&](int kt) -> size_t {
        int ij = kt >> 7;
        int i = (ij >= 6) ? 2 : (ij >= 3 ? 1 : 0);
        int j = ij - 3 * i;
        int c0 = (kt & 127) + scc;
        return (((size_t)(b * 34 + p + i)) * 34 + (q + j)) * 128 + c0;
    };
    size_t ao = aoff(0);
    bf16x8 arh = *reinterpret_cast<const bf16x8*>(sph + ao);
    bf16x8 arl = *reinterpret_cast<const bf16x8*>(spl + ao);
    bf16x8 nb0h = *reinterpret_cast<const bf16x8*>(bfh + boff0);
    bf16x8 nb0l = *reinterpret_cast<const bf16x8*>(bfl + boff0);
    bf16x8 nb1h = *reinterpret_cast<const bf16x8*>(bfh + boff1);
    bf16x8 nb1l = *reinterpret_cast<const bf16x8*>(bfl + boff1);

    for (int kt = 0; kt < 1152; kt += 32) {
        __syncthreads();
        *reinterpret_cast<bf16x8*>(&Ah[srow][scc]) = arh;
        *reinterpret_cast<bf16x8*>(&Al[srow][scc]) = arl;
        __syncthreads();
        const int ktn = (kt + 32 < 1152) ? kt + 32 : kt;
        bf16x8 cb0h = nb0h, cb0l = nb0l, cb1h = nb1h, cb1l = nb1l;
        size_t aon = aoff(ktn);
        arh = *reinterpret_cast<const bf16x8*>(sph + aon);
        arl = *reinterpret_cast<const bf16x8*>(spl + aon);
        nb0h = *reinterpret_cast<const bf16x8*>(bfh + boff0 + ktn);
        nb0l = *reinterpret_cast<const bf16x8*>(bfl + boff0 + ktn);
        nb1h = *reinterpret_cast<const bf16x8*>(bfh + boff1 + ktn);
        nb1l = *reinterpret_cast<const bf16x8*>(bfl + boff1 + ktn);

        bf16x8 ah[4], al[4];
#pragma unroll
        for (int mf = 0; mf < 4; ++mf) {
            ah[mf] = *reinterpret_cast<const bf16x8*>(&Ah[rh * 64 + mf * 16 + m][g * 8]);
            al[mf] = *reinterpret_cast<const bf16x8*>(&Al[rh * 64 + mf * 16 + m][g * 8]);
        }
#pragma unroll
        for (int mf = 0; mf < 4; ++mf) {
            acc[mf][0] = __builtin_amdgcn_mfma_f32_16x16x32_bf16(ah[mf], cb0h, acc[mf][0], 0, 0, 0);
            acc[mf][0] = __builtin_amdgcn_mfma_f32_16x16x32_bf16(al[mf], cb0h, acc[mf][0], 0, 0, 0);
            acc[mf][0] = __builtin_amdgcn_mfma_f32_16x16x32_bf16(ah[mf], cb0l, acc[mf][0], 0, 0, 0);
            acc[mf][1] = __builtin_amdgcn_mfma_f32_16x16x32_bf16(ah[mf], cb1h, acc[mf][1], 0, 0, 0);
            acc[mf][1] = __builtin_amdgcn_mfma_f32_16x16x32_bf16(al[mf], cb1h, acc[mf][1], 0, 0, 0);
            acc[mf][1] = __builtin_amdgcn_mfma_f32_16x16x32_bf16(ah[mf], cb1l, acc[mf][1], 0, 0, 0);
        }
    }
#pragma unroll
    for (int mf = 0; mf < 4; ++mf) {
        int row = tm * 128 + rh * 64 + mf * 16 + g * 4;
#pragma unroll
        for (int nn = 0; nn < 2; ++nn) {
            int col = col0 + nn * 16;
#pragma unroll
            for (int r = 0; r < 4; ++r)
                outy[((size_t)b << 20) + (size_t)(row + r) * 1024 + col] = acc[mf][nn][r];
        }
    }
}

// deconv MFMA fp16: M-tile 128, 512 thr / 8 waves; A from fp16 probs (no cvt),
// B single fp16 -> 1 MFMA per step (post-softmax precision is sufficient).
__global__ __launch_bounds__(512) void k_deconv_mfma(const _Float16* __restrict__ yp16,
                                                     const _Float16* __restrict__ bp,
                                                     float* __restrict__ yup) {
    const int b = blockIdx.z, tm = blockIdx.y, tn = blockIdx.x;   // tn = ij 0..8
    __shared__ _Float16 A16[128][40];
    const int tid = threadIdx.x;
    const int w = tid >> 6, lane = tid & 63, m = lane & 15, g = lane >> 4;
    const int rh = w & 1, cg = w >> 1;
    f32x4 acc[4][2];
#pragma unroll
    for (int mf = 0; mf < 4; ++mf)
#pragma unroll
        for (int nn = 0; nn < 2; ++nn) acc[mf][nn] = f32x4{0.f, 0.f, 0.f, 0.f};
    const int srow = tid >> 2, scc = (tid & 3) * 8;
    const int c0 = cg * 32 + m;
    const _Float16* abase = yp16 + ((size_t)b << 20) + (size_t)(tm * 128 + srow) * 1024 + scc;
    const size_t boff0 = (((size_t)(b * 9 + tn)) * 128 + c0) * 1024 + g * 8;
    const size_t boff1 = (((size_t)(b * 9 + tn)) * 128 + c0 + 16) * 1024 + g * 8;

    f16x8 ar = *reinterpret_cast<const f16x8*>(abase);
    f16x8 nb0 = *reinterpret_cast<const f16x8*>(bp + boff0);
    f16x8 nb1 = *reinterpret_cast<const f16x8*>(bp + boff1);

    for (int kt = 0; kt < 1024; kt += 32) {
        __syncthreads();
        *reinterpret_cast<f16x8*>(&A16[srow][scc]) = ar;
        __syncthreads();
        const int ktn = (kt + 32 < 1024) ? kt + 32 : kt;
        f16x8 cb0 = nb0, cb1 = nb1;
        ar = *reinterpret_cast<const f16x8*>(abase + ktn);
        nb0 = *reinterpret_cast<const f16x8*>(bp + boff0 + ktn);
        nb1 = *reinterpret_cast<const f16x8*>(bp + boff1 + ktn);

        f16x8 av[4];
#pragma unroll
        for (int mf = 0; mf < 4; ++mf)
            av[mf] = *reinterpret_cast<const f16x8*>(&A16[rh * 64 + mf * 16 + m][g * 8]);
#pragma unroll
        for (int mf = 0; mf < 4; ++mf) {
            acc[mf][0] = __builtin_amdgcn_mfma_f32_16x16x32_f16(av[mf], cb0, acc[mf][0], 0, 0, 0);
            acc[mf][1] = __builtin_amdgcn_mfma_f32_16x16x32_f16(av[mf], cb1, acc[mf][1], 0, 0, 0);
        }
    }
    const int ip = (tn >= 6) ? 2 : (tn >= 3 ? 1 : 0);
    const int jp = tn - 3 * ip;
#pragma unroll
    for (int mf = 0; mf < 4; ++mf) {
        int uvb = tm * 128 + rh * 64 + mf * 16 + g * 4;
#pragma unroll
        for (int nn = 0; nn < 2; ++nn) {
            int c = c0 + nn * 16;
#pragma unroll
            for (int r = 0; r < 4; ++r) {
                int uv = uvb + r;
                int uu = uv >> 5, vv = uv & 31;
                int P = 2 * uu + ip, Q = 2 * vv + jp;
                if (P < 64 && Q < 64)
                    atomicAdd(&yup[(((size_t)(b * 64 + P)) * 64 + Q) * 128 + c], acc[mf][nn][r]);
            }
        }
    }
}

__global__ void k_fuse1(const float* __restrict__ in, float* __restrict__ out) {
    size_t idx = (size_t)blockIdx.x * 256 + threadIdx.x;
    if (idx >= (size_t)8 * 1024 * 1024) return;
    int t = (int)(idx & 1023);
    int s = (int)((idx >> 10) & 1023);
    int b = (int)(idx >> 20);
    const float* base = in + ((size_t)b << 20);
    float v = base[(size_t)s * 1024 + t];
    if (s > 0 && t > 0) v += base[(size_t)(s - 1) * 1024 + (t - 1)];
    if (s < 1023 && t < 1023) v += base[(size_t)(s + 1) * 1024 + (t + 1)];
    out[idx] = v;
}

__global__ void k_fuse2(const float* __restrict__ in, float* __restrict__ out) {
    size_t idx = (size_t)blockIdx.x * 256 + threadIdx.x;
    if (idx >= (size_t)8 * 1024 * 1024) return;
    int t = (int)(idx & 1023);
    int s = (int)((idx >> 10) & 1023);
    int b = (int)(idx >> 20);
    int m0 = ((s & 31) << 5) + (s >> 5);
    int n0 = ((t & 31) << 5) + (t >> 5);
    const float* base = in + ((size_t)b << 20);
    float v = 0.f;
#pragma unroll
    for (int d = -1; d <= 1; ++d) {
        int m = m0 + d, n = n0 + d;
        if (m >= 0 && m < 1024 && n >= 0 && n < 1024)
            v += base[(size_t)(((m & 31) << 5) + (m >> 5)) * 1024 + (((n & 31) << 5) + (n >> 5))];
    }
    out[idx] = v;
}

__global__ __launch_bounds__(256) void k_softmax1024(const float* __restrict__ yv,
                                                     const float* __restrict__ mm,
                                                     float* __restrict__ outc,
                                                     _Float16* __restrict__ yp16) {
    int row = blockIdx.x;
    const float* base = yv + (size_t)row * 1024;
    float mmv = mm[row];
    int t = threadIdx.x;
    float vals[4];
    float mx = -1e30f;
#pragma unroll
    for (int i = 0; i < 4; ++i) {
        vals[i] = base[t + i * 256] * mmv * 10.0f;
        mx = fmaxf(mx, vals[i]);
    }
#pragma unroll
    for (int o = 32; o; o >>= 1) mx = fmaxf(mx, __shfl_xor(mx, o));
    __shared__ float red[8];
    if ((t & 63) == 0) red[t >> 6] = mx;
    __syncthreads();
    mx = fmaxf(fmaxf(red[0], red[1]), fmaxf(red[2], red[3]));
    float s = 0.f;
#pragma unroll
    for (int i = 0; i < 4; ++i) {
        vals[i] = expf(vals[i] - mx);
        s += vals[i];
    }
#pragma unroll
    for (int o = 32; o; o >>= 1) s += __shfl_xor(s, o);
    if ((t & 63) == 0) red[4 + (t >> 6)] = s;
    __syncthreads();
    s = red[4] + red[5] + red[6] + red[7];
    float inv = mmv / s;
#pragma unroll
    for (int i = 0; i < 4; ++i) {
        float pv = vals[i] * inv;
        outc[(size_t)row * 1024 + t + i * 256] = pv;
        yp16[(size_t)row * 1024 + t + i * 256] = (_Float16)pv;
    }
}

// f32 image (8,64,64,128) -> padded bf16 hi/lo pair (8,66,66,128), zero halo
__global__ __launch_bounds__(256) void k_pair_pad(const float* __restrict__ in,
                                                  short* __restrict__ hi, short* __restrict__ lo) {
    int idx = blockIdx.x * 256 + threadIdx.x;
    int c8 = idx & 15;
    int r = idx >> 4;
    int pc = r % 66; r /= 66;
    int pr = r % 66; int b = r / 66;
    bf16x8 h, l;
    if (pr >= 1 && pr <= 64 && pc >= 1 && pc <= 64) {
        const float* s = in + (((size_t)(b * 64 + pr - 1)) * 64 + (pc - 1)) * 128 + c8 * 8;
        float4 v0 = *reinterpret_cast<const float4*>(s);
        float4 v1 = *reinterpret_cast<const float4*>(s + 4);
        cvt8(v0, v1, h, l);
    } else {
#pragma unroll
        for (int u = 0; u < 8; ++u) { h[u] = 0; l[u] = 0; }
    }
    size_t off = (size_t)idx * 8;
    *reinterpret_cast<bf16x8*>(hi + off) = h;
    *reinterpret_cast<bf16x8*>(lo + off) = l;
}

__global__ void k_wt_pair(const float* __restrict__ w, short* __restrict__ hi,
                          short* __restrict__ lo, int CI) {
    int idx = blockIdx.x * 256 + threadIdx.x;
    if (idx >= 9 * CI * 128) return;
    int ci = idx % CI; int rest = idx / CI;
    int co = rest & 127; int ij = rest >> 7;
    float v = w[((size_t)ij * CI + ci) * 128 + co];
    short h = f2bf(v);
    hi[idx] = h;
    lo[idx] = f2bf(v - bf2f(h));
}

// pw (1,1,CI,128) f32 -> transposed bf16 [co][ci]
__global__ void k_pw_t(const float* __restrict__ pw, short* __restrict__ out, int CI) {
    int idx = blockIdx.x * 256 + threadIdx.x;
    if (idx >= CI * 128) return;
    int co = idx & 127, ci = idx >> 7;
    out[(size_t)co * CI + ci] = f2bf(pw[idx]);
}

// Fused depthwise 3x3 + pointwise (MFMA, K=CI) + channel softmax -> smout f32.
template <int CI>
__global__ __launch_bounds__(256, 2) void k_dwpw_mfma(const short* __restrict__ in0h,
                                                      const short* __restrict__ in0l,
                                                      const short* __restrict__ in1h,
                                                      const short* __restrict__ in1l,
                                                      const float* __restrict__ dwW,
                                                      const short* __restrict__ pwt,
                                                      const float* __restrict__ db,
                                                      float* __restrict__ smout) {
    const int bid = blockIdx.x;
    const int swz = (bid & 7) * 64 + (bid >> 3);
    const int b = swz >> 6, P = swz & 63;
    const int t = threadIdx.x;
    const int w = t >> 6, lane = t & 63, m = lane & 15, g = lane >> 4;
    __shared__ short Adw[64 * CI];
    __shared__ float red[2][4][64];
    char* ab = (char*)Adw;
    const int px = lane;
    const int cb = w * (CI / 4);
    float dwacc[CI / 4];
#pragma unroll
    for (int u = 0; u < CI / 4; ++u) dwacc[u] = 0.f;
#pragma unroll
    for (int i = 0; i < 3; ++i) {
#pragma unroll
        for (int j = 0; j < 3; ++j) {
            const int ij = i * 3 + j;
#pragma unroll
            for (int c8 = 0; c8 < CI / 32; ++c8) {
                const int c = cb + c8 * 8;
                const short* ph = (CI == 256 && c >= 128) ? in1h : in0h;
                const short* pl = (CI == 256 && c >= 128) ? in1l : in0l;
                const int cc = (CI == 256 && c >= 128) ? (c - 128) : c;
                size_t off = (((size_t)b * 66 + P + i) * 66 + px + j) * 128 + cc;
                bf16x8 vh = *reinterpret_cast<const bf16x8*>(ph + off);
                bf16x8 vl = *reinterpret_cast<const bf16x8*>(pl + off);
#pragma unroll
                for (int u = 0; u < 8; ++u) {
                    float v = bf2f(vh[u]) + bf2f(vl[u]);
                    dwacc[c8 * 8 + u] = fmaf(v, dwW[ij * CI + c + u], dwacc[c8 * 8 + u]);
                }
            }
        }
    }
#pragma unroll
    for (int c8 = 0; c8 < CI / 32; ++c8) {
        bf16x8 hv;
#pragma unroll
        for (int u = 0; u < 8; ++u) hv[u] = f2bf(dwacc[c8 * 8 + u]);
        int byte = px * (CI * 2) + (cb + c8 * 8) * 2;
        int sz = byte ^ ((px & 7) << 4);
        *reinterpret_cast<bf16x8*>(ab + sz) = hv;
    }
    __syncthreads();
    f32x4 acc[4][2];
#pragma unroll
    for (int mt = 0; mt < 4; ++mt)
#pragma unroll
        for (int nn = 0; nn < 2; ++nn) acc[mt][nn] = f32x4{0.f, 0.f, 0.f, 0.f};
    const int co0 = w * 32 + m;
#pragma unroll
    for (int kc = 0; kc < CI / 32; ++kc) {
        bf16x8 av[4];
#pragma unroll
        for (int mt = 0; mt < 4; ++mt) {
            int prow = mt * 16 + m;
            int byte = prow * (CI * 2) + (kc * 32 + g * 8) * 2;
            int sz = byte ^ ((prow & 7) << 4);
            av[mt] = *reinterpret_cast<const bf16x8*>(ab + sz);
        }
#pragma unroll
        for (int nn = 0; nn < 2; ++nn) {
            bf16x8 bv = *reinterpret_cast<const bf16x8*>(pwt + (size_t)(co0 + nn * 16) * CI + kc * 32 + g * 8);
#pragma unroll
            for (int mt = 0; mt < 4; ++mt)
                acc[mt][nn] = __builtin_amdgcn_mfma_f32_16x16x32_bf16(av[mt], bv, acc[mt][nn], 0, 0, 0);
        }
    }
    float db0 = db[co0], db1 = db[co0 + 16];
    float mx[4][4];
#pragma unroll
    for (int mt = 0; mt < 4; ++mt)
#pragma unroll
        for (int r = 0; r < 4; ++r) {
            acc[mt][0][r] += db0;
            acc[mt][1][r] += db1;
            float v = fmaxf(acc[mt][0][r], acc[mt][1][r]);
#pragma unroll
            for (int o = 1; o <= 8; o <<= 1) v = fmaxf(v, __shfl_xor(v, o));
            mx[mt][r] = v;
        }
    if (m == 0) {
#pragma unroll
        for (int mt = 0; mt < 4; ++mt)
#pragma unroll
            for (int r = 0; r < 4; ++r) red[0][w][mt * 16 + g * 4 + r] = mx[mt][r];
    }
    __syncthreads();
    float sume[4][4];
#pragma unroll
    for (int mt = 0; mt < 4; ++mt)
#pragma unroll
        for (int r = 0; r < 4; ++r) {
            int p = mt * 16 + g * 4 + r;
            float M = fmaxf(fmaxf(red[0][0][p], red[0][1][p]), fmaxf(red[0][2][p], red[0][3][p]));
            acc[mt][0][r] = expf(acc[mt][0][r] - M);
            acc[mt][1][r] = expf(acc[mt][1][r] - M);
            float s = acc[mt][0][r] + acc[mt][1][r];
#pragma unroll
            for (int o = 1; o <= 8; o <<= 1) s += __shfl_xor(s, o);
            sume[mt][r] = s;
        }
    if (m == 0) {
#pragma unroll
        for (int mt = 0; mt < 4; ++mt)
#pragma unroll
            for (int r = 0; r < 4; ++r) red[1][w][mt * 16 + g * 4 + r] = sume[mt][r];
    }
    __syncthreads();
#pragma unroll
    for (int mt = 0; mt < 4; ++mt)
#pragma unroll
        for (int r = 0; r < 4; ++r) {
            int p = mt * 16 + g * 4 + r;
            float S = red[1][0][p] + red[1][1][p] + red[1][2][p] + red[1][3][p];
            float inv = 1.0f / S;
            size_t pix = ((size_t)b * 64 + P) * 64 + p;
            smout[pix * 128 + co0] = acc[mt][0][r] * inv;
            smout[pix * 128 + co0 + 16] = acc[mt][1][r] * inv;
        }
}

// MFMA split-bf16 implicit-GEMM 3x3 conv + bias + elu + gate, LDS-staged rows.
template <int CI>
__global__ __launch_bounds__(256, 4) void k_conv_lds(const short* __restrict__ in0h,
                                                     const short* __restrict__ in0l,
                                                     const short* __restrict__ in1h,
                                                     const short* __restrict__ in1l,
                                                     const short* __restrict__ wh,
                                                     const short* __restrict__ wl,
                                                     const float* __restrict__ bias,
                                                     const float* __restrict__ sm,
                                                     float* __restrict__ out) {
    const int bid = blockIdx.x;
    const int idx = (bid & 7) * 128 + (bid >> 3);
    const int row = idx >> 1, cohalf = idx & 1;
    const int b = row >> 6, P = row & 63;
    const int tid = threadIdx.x;
    const int w = tid >> 6, lane = tid & 63;
    const int m = lane & 15, g = lane >> 4;
    __shared__ short Sh[66 * 128];
    __shared__ short Sl[66 * 128];
    char* shb = (char*)Sh;
    char* slb = (char*)Sl;
    f32x4 acc[4];
#pragma unroll
    for (int mt = 0; mt < 4; ++mt) acc[mt] = f32x4{0.f, 0.f, 0.f, 0.f};
    const int cow = cohalf * 64 + w * 16 + m;

#pragma unroll
    for (int half = 0; half < CI / 128; ++half) {
        const short* ih = (half == 0) ? in0h : in1h;
        const short* il = (half == 0) ? in0l : in1l;
        const size_t rbase0 = ((size_t)b * 66 + P) * 66 * 128;
#pragma unroll
        for (int i = 0; i < 3; ++i) {
            __syncthreads();
            const size_t rsrc = rbase0 + (size_t)i * 66 * 128;
#pragma unroll
            for (int e0 = 0; e0 < 1056; e0 += 256) {
                int e = e0 + tid;
                if (e < 1056) {
                    int px = e >> 4, c8 = e & 15;
                    int lin = px * 256 + c8 * 16;
                    int sz = lin ^ ((px & 7) << 4);
                    size_t so = rsrc + (size_t)px * 128 + c8 * 8;
                    *reinterpret_cast<bf16x8*>(shb + sz) = *reinterpret_cast<const bf16x8*>(ih + so);
                    *reinterpret_cast<bf16x8*>(slb + sz) = *reinterpret_cast<const bf16x8*>(il + so);
                }
            }
            __syncthreads();
#pragma unroll
            for (int j = 0; j < 3; ++j) {
                const int ij = i * 3 + j;
                const short* wph = wh + ((size_t)ij * 128 + cow) * CI + half * 128 + g * 8;
                const short* wpl = wl + ((size_t)ij * 128 + cow) * CI + half * 128 + g * 8;
#pragma unroll
                for (int ci0 = 0; ci0 < 128; ci0 += 32) {
                    bf16x8 bh = *reinterpret_cast<const bf16x8*>(wph + ci0);
                    bf16x8 bl = *reinterpret_cast<const bf16x8*>(wpl + ci0);
                    bf16x8 ah[4], al[4];
#pragma unroll
                    for (int mt = 0; mt < 4; ++mt) {
                        int px = mt * 16 + m + j;
                        int lin = px * 256 + ci0 * 2 + g * 16;
                        int sz = lin ^ ((px & 7) << 4);
                        ah[mt] = *reinterpret_cast<const bf16x8*>(shb + sz);
                        al[mt] = *reinterpret_cast<const bf16x8*>(slb + sz);
                    }
#pragma unroll
                    for (int mt = 0; mt < 4; ++mt) {
                        acc[mt] = __builtin_amdgcn_mfma_f32_16x16x32_bf16(ah[mt], bh, acc[mt], 0, 0, 0);
                        acc[mt] = __builtin_amdgcn_mfma_f32_16x16x32_bf16(ah[mt], bl, acc[mt], 0, 0, 0);
                        acc[mt] = __builtin_amdgcn_mfma_f32_16x16x32_bf16(al[mt], bh, acc[mt], 0, 0, 0);
                    }
                }
            }
        }
    }
    const float bb = bias[cow];
#pragma unroll
    for (int mt = 0; mt < 4; ++mt) {
#pragma unroll
        for (int r = 0; r < 4; ++r) {
            int Q = mt * 16 + g * 4 + r;
            size_t pix = ((size_t)b * 64 + P) * 64 + Q;
            float z = acc[mt][r] + bb;
            z = z > 0.f ? z : expm1f(z);
            out[pix * 128 + cow] = z * sm[pix * 128 + cow];
        }
    }
}

extern "C" void kernel_launch(void* const* d_in, const int* in_sizes, int n_in,
                              void* d_out, int out_size, void* d_ws, size_t ws_size,
                              hipStream_t stream) {
    const float* x    = (const float*)d_in[0];
    const float* mask = (const float*)d_in[1];
    const float* w1   = (const float*)d_in[2];
    const float* b1   = (const float*)d_in[3];
    const float* dw1  = (const float*)d_in[4];
    const float* pw1  = (const float*)d_in[5];
    const float* db1  = (const float*)d_in[6];
    const float* w2   = (const float*)d_in[7];
    const float* b2   = (const float*)d_in[8];
    const float* dw2  = (const float*)d_in[9];
    const float* pw2  = (const float*)d_in[10];
    const float* db2  = (const float*)d_in[11];

    float* out_a = (float*)d_out;            // (8,64,64,128)
    float* out_c = out_a + 4194304;          // (8,32,32,1024)

    char* wsb = (char*)d_ws;
    float* sp    = (float*)(wsb + BOFF_SP);
    float* invd  = (float*)(wsb + BOFF_INVD);
    short* sph   = (short*)(wsb + BOFF_SPH);
    short* spl   = (short*)(wsb + BOFF_SPL);
    short* bfh   = (short*)(wsb + BOFF_BFH);
    short* bfl   = (short*)(wsb + BOFF_BFL);
    float* Tbuf  = (float*)(wsb + BOFF_T);
    _Float16* bp16 = (_Float16*)(wsb + BOFF_BP16);
    _Float16* yp16 = (_Float16*)(wsb + BOFF_YP16);
    float* yup   = (float*)(wsb + BOFF_YUP);
    float* smb   = (float*)(wsb + BOFF_SM);
    short* p3h   = (short*)(wsb + BOFF_P3H);
    short* p3l   = (short*)(wsb + BOFF_P3L);
    float* a1    = (float*)(wsb + BOFF_A1);
    short* xh    = (short*)(wsb + BOFF_XH);
    short* xl    = (short*)(wsb + BOFF_XL);
    short* wt1h  = (short*)(wsb + BOFF_WT1H);
    short* wt1l  = (short*)(wsb + BOFF_WT1L);
    short* wt2h  = (short*)(wsb + BOFF_WT2H);
    short* wt2l  = (short*)(wsb + BOFF_WT2L);
    short* pw1t  = (short*)(wsb + BOFF_PW1B);
    short* pw2t  = (short*)(wsb + BOFF_PW2B);
    float* m0    = (float*)(wsb + BOFF_M0);
    float* mmb   = (float*)(wsb + BOFF_MM);

    // phase A: mask + correlation (MFMA) + fuse + softmax
    k_mask_pool<<<8192, 256, 0, stream>>>(mask, m0);
    k_mask_dilate<<<32, 256, 0, stream>>>(m0, mmb);
    k_srcpad<<<4624, 256, 0, stream>>>(x, sp);
    k_pair_sp<<<579, 256, 0, stream>>>(sp, sph, spl);
    k_invd<<<512, 256, 0, stream>>>(sp, invd);
    k_wt_pair<<<576, 256, 0, stream>>>(w1, wt1h, wt1l, 128);
    k_wt_pair<<<1152, 256, 0, stream>>>(w2, wt2h, wt2l, 256);
    k_pw_t<<<64, 256, 0, stream>>>(pw1, pw1t, 128);
    k_pw_t<<<128, 256, 0, stream>>>(pw2, pw2t, 256);
    k_corr_B<<<4608, 256, 0, stream>>>(sp, invd, bfh, bfl);
    k_corr_mfma<<<dim3(8, 8, 8), 512, 0, stream>>>(sph, spl, bfh, bfl, out_c);
    k_fuse1<<<32768, 256, 0, stream>>>(out_c, Tbuf);
    k_fuse2<<<32768, 256, 0, stream>>>(Tbuf, out_c);
    k_deconv_B16<<<4608, 256, 0, stream>>>(x, bp16);
    k_softmax1024<<<8192, 256, 0, stream>>>(out_c, mmb, out_c, yp16);
    // phase B: deconv (fp16 MFMA) -> yup
    hipMemsetAsync(yup, 0, (size_t)4194304 * sizeof(float), stream);
    k_deconv_mfma<<<dim3(9, 8, 8), 512, 0, stream>>>(yp16, bp16, yup);
    // phase C: gated conv 1
    k_pair_pad<<<2178, 256, 0, stream>>>(yup, p3h, p3l);
    k_pair_pad<<<2178, 256, 0, stream>>>(x, xh, xl);
    k_dwpw_mfma<128><<<512, 256, 0, stream>>>(p3h, p3l, nullptr, nullptr,
                                              dw1, pw1t, db1, smb);
    k_conv_lds<128><<<1024, 256, 0, stream>>>(p3h, p3l, nullptr, nullptr,
                                              wt1h, wt1l, b1, smb, a1);
    // phase D: gated conv 2 (concat(a1, x))
    k_pair_pad<<<2178, 256, 0, stream>>>(a1, p3h, p3l);
    k_dwpw_mfma<256><<<512, 256, 0, stream>>>(p3h, p3l, xh, xl,
                                              dw2, pw2t, db2, smb);
    k_conv_lds<256><<<1024, 256, 0, stream>>>(p3h, p3l, xh, xl,
                                              wt2h, wt2l, b2, smb, out_a);
}

// Round 12
// 548.687 us; speedup vs baseline: 1.9990x; 1.1009x over previous
//
#include <hip/hip_runtime.h>
#include <hip/hip_bf16.h>

// B=8, H=W=64, C=128, rate=2 -> k=3, h=w=32, L=1024
// Workspace (72,433,664 bytes), time-multiplexed (liveness checked):
//  phase A: sp [0,4.73M) invd [4.73,5.26M) sp16 [5.26,7.63M) Bf16 [7.63,26.5M)
//  fuse:    T [0,33.55M) (sp/invd/sp16/Bf16 dead after corr)
//  deconv:  Bp16 [0,18.87M) yp16 [18.87,35.65M) yup [37.75,54.53M)
//  phase C/D: SM [0,16.78M) P3 [16.78,34.62M) A1 [34.62,51.40M) X [51.40,69.24M)
//  static:  weights [69.24,71.11M) m0/mm [71.11,71.17M)

#define BOFF_SP      0
#define BOFF_INVD    4734976
#define BOFF_SP16    5259264
#define BOFF_BF16    7626752
#define BOFF_T       0
#define BOFF_BP16    0
#define BOFF_YP16    18874368
#define BOFF_YUP     37748736
#define BOFF_SM      0
#define BOFF_P3H     16777216
#define BOFF_P3L     25698304
#define BOFF_A1      34619392
#define BOFF_XH      51396608
#define BOFF_XL      60317696
#define BOFF_WT1H    69238784
#define BOFF_WT1L    69533696
#define BOFF_WT2H    69828608
#define BOFF_WT2L    70418432
#define BOFF_PW1B    71008256
#define BOFF_PW2B    71041024
#define BOFF_M0      71106560
#define BOFF_MM      71139328

typedef float f32x4 __attribute__((ext_vector_type(4)));
typedef short bf16x8 __attribute__((ext_vector_type(8)));
typedef _Float16 f16x8 __attribute__((ext_vector_type(8)));

__device__ __forceinline__ short f2bf(float f) {
    unsigned u = __float_as_uint(f);
    unsigned r = u + 0x7FFFu + ((u >> 16) & 1u);
    return (short)(r >> 16);
}
__device__ __forceinline__ float bf2f(short s) {
    return __uint_as_float(((unsigned)(unsigned short)s) << 16);
}
__device__ __forceinline__ void cvt8(const float4 v0, const float4 v1, bf16x8& h, bf16x8& l) {
    float a[8] = {v0.x, v0.y, v0.z, v0.w, v1.x, v1.y, v1.z, v1.w};
#pragma unroll
    for (int u = 0; u < 8; ++u) {
        short hh = f2bf(a[u]);
        h[u] = hh;
        l[u] = f2bf(a[u] - bf2f(hh));
    }
}

__global__ __launch_bounds__(256) void k_mask_pool(const float* __restrict__ mask, float* __restrict__ m0) {
    int blk = blockIdx.x;
    int b = blk >> 10, pq = blk & 1023, p = pq >> 5, q = pq & 31;
    int t = threadIdx.x, dy = t >> 4, dx = t & 15;
    float v = mask[((size_t)(b * 512 + p * 16 + dy)) * 512 + q * 16 + dx];
#pragma unroll
    for (int o = 32; o; o >>= 1) v = fmaxf(v, __shfl_xor(v, o));
    __shared__ float s[4];
    if ((t & 63) == 0) s[t >> 6] = v;
    __syncthreads();
    if (t == 0) m0[blk] = fmaxf(fmaxf(s[0], s[1]), fmaxf(s[2], s[3]));
}

__global__ void k_mask_dilate(const float* __restrict__ m0, float* __restrict__ mm) {
    int idx = blockIdx.x * 256 + threadIdx.x;
    if (idx >= 8192) return;
    int b = idx >> 10, pq = idx & 1023, p = pq >> 5, q = pq & 31;
    float v = -1e30f;
    for (int di = -1; di <= 1; ++di)
        for (int dj = -1; dj <= 1; ++dj) {
            int pp = p + di, qq = q + dj;
            if (pp >= 0 && pp < 32 && qq >= 0 && qq < 32)
                v = fmaxf(v, m0[(b << 10) + pp * 32 + qq]);
        }
    mm[idx] = 1.0f - v;
}

__global__ void k_srcpad(const float* __restrict__ x, float* __restrict__ sp) {
    int idx = blockIdx.x * 256 + threadIdx.x;
    if (idx >= 8 * 34 * 34 * 128) return;
    int c = idx & 127;
    int r = idx >> 7;
    int xx = r % 34; r /= 34;
    int yy = r % 34; int b = r / 34;
    float v = 0.f;
    if (yy >= 1 && yy <= 32 && xx >= 1 && xx <= 32)
        v = x[(((size_t)(b * 64 + (yy - 1) * 2)) * 64 + (xx - 1) * 2) * 128 + c];
    sp[idx] = v;
}

// sp f32 -> fp16 (1,183,744 elems, 8/thread)
__global__ void k_sp16(const float* __restrict__ sp, _Float16* __restrict__ o) {
    int idx = blockIdx.x * 256 + threadIdx.x;
    if (idx >= 147968) return;
    const float* s = sp + (size_t)idx * 8;
    float4 v0 = *reinterpret_cast<const float4*>(s);
    float4 v1 = *reinterpret_cast<const float4*>(s + 4);
    f16x8 h;
    h[0] = (_Float16)v0.x; h[1] = (_Float16)v0.y; h[2] = (_Float16)v0.z; h[3] = (_Float16)v0.w;
    h[4] = (_Float16)v1.x; h[5] = (_Float16)v1.y; h[6] = (_Float16)v1.z; h[7] = (_Float16)v1.w;
    *reinterpret_cast<f16x8*>(o + (size_t)idx * 8) = h;
}

__global__ void k_invd(const float* __restrict__ sp, float* __restrict__ invd) {
    int idx = blockIdx.x * 256 + threadIdx.x;
    if (idx >= 1024 * 128) return;
    int c = idx & 127, l = idx >> 7, lh = l >> 5, lw = l & 31;
    float s = 0.f;
    for (int b = 0; b < 8; ++b)
#pragma unroll
        for (int i = 0; i < 3; ++i)
#pragma unroll
            for (int j = 0; j < 3; ++j) {
                float v = sp[(((size_t)(b * 34 + lh + i)) * 34 + (lw + j)) * 128 + c];
                s += v * v;
            }
    invd[idx] = 1.0f / fmaxf(s, 1e-8f);
}

// Bf16[b][l][ij][c] = sp[b][lh+i][lw+j][c] * invd[l][c], single fp16.
__global__ void k_corr_B16(const float* __restrict__ sp, const float* __restrict__ invd,
                           _Float16* __restrict__ bf) {
    int idx = blockIdx.x * 256 + threadIdx.x;
    if (idx >= 1179648) return;
    int c8 = idx & 15; int rest = idx >> 4;
    int ij = rest % 9; int rest2 = rest / 9;
    int l = rest2 & 1023, b = rest2 >> 10;
    int lh = l >> 5, lw = l & 31;
    int i = (ij >= 6) ? 2 : (ij >= 3 ? 1 : 0);
    int j = ij - 3 * i;
    int c0 = c8 * 8;
    const float* s = sp + (((size_t)(b * 34 + lh + i)) * 34 + (lw + j)) * 128 + c0;
    const float* dv = invd + l * 128 + c0;
    f16x8 h;
#pragma unroll
    for (int u = 0; u < 8; ++u) h[u] = (_Float16)(s[u] * dv[u]);
    size_t off = ((size_t)(b * 1024 + l)) * 1152 + ij * 128 + c0;
    *reinterpret_cast<f16x8*>(bf + off) = h;
}

// Bp16[b][ij][c][l] = x[b][2lh+ip][2lw+jp][c] (0 OOB), single fp16.
__global__ void k_deconv_B16(const float* __restrict__ x, _Float16* __restrict__ bp) {
    int idx = blockIdx.x * 256 + threadIdx.x;
    if (idx >= 1179648) return;
    int l8 = idx & 127; int rest = idx >> 7;
    int c = rest & 127; int rest2 = rest >> 7;
    int ij = rest2 % 9; int b = rest2 / 9;
    int ip = (ij >= 6) ? 2 : (ij >= 3 ? 1 : 0);
    int jp = ij - 3 * ip;
    int l0 = l8 * 8;
    int lh = l0 >> 5, lw0 = l0 & 31;
    int rr = 2 * lh + ip;
    f16x8 h;
#pragma unroll
    for (int u = 0; u < 8; ++u) {
        int ss = 2 * (lw0 + u) + jp;
        float v = (rr < 64 && ss < 64) ? x[(((size_t)(b * 64 + rr)) * 64 + ss) * 128 + c] : 0.f;
        h[u] = (_Float16)v;
    }
    size_t off = (((size_t)(b * 9 + ij)) * 128 + c) * 1024 + l0;
    *reinterpret_cast<f16x8*>(bp + off) = h;
}

// corr MFMA fp16: M-tile 128, N-tile 64, grid (16,8,8)=1024 blocks (4/CU).
// 512 thr / 8 waves (2 row-halves x 4 col-groups of 16). 1 fp16 MFMA per mf.
__global__ __launch_bounds__(512) void k_corr_mfma(const _Float16* __restrict__ sp16,
                                                   const _Float16* __restrict__ bf,
                                                   float* __restrict__ outy) {
    const int b = blockIdx.z, tm = blockIdx.y, tn = blockIdx.x;  // tn 0..15
    __shared__ _Float16 A16[128][40];
    const int tid = threadIdx.x;
    const int w = tid >> 6, lane = tid & 63, m = lane & 15, g = lane >> 4;
    const int rh = w & 1, cg = w >> 1;
    f32x4 acc[4];
#pragma unroll
    for (int mf = 0; mf < 4; ++mf) acc[mf] = f32x4{0.f, 0.f, 0.f, 0.f};
    const int srow = tid >> 2, scc = (tid & 3) * 8;
    const int pq = tm * 128 + srow, p = pq >> 5, q = pq & 31;
    const int col0 = tn * 64 + cg * 16 + m;
    const size_t boff = ((size_t)b * 1024 + col0) * 1152 + g * 8;

    auto aoff = [&](int kt) -> size_t {
        int ij = kt >> 7;
        int i = (ij >= 6) ? 2 : (ij >= 3 ? 1 : 0);
        int j = ij - 3 * i;
        int c0 = (kt & 127) + scc;
        return (((size_t)(b * 34 + p + i)) * 34 + (q + j)) * 128 + c0;
    };
    f16x8 ar = *reinterpret_cast<const f16x8*>(sp16 + aoff(0));
    f16x8 nb = *reinterpret_cast<const f16x8*>(bf + boff);

    for (int kt = 0; kt < 1152; kt += 32) {
        __syncthreads();
        *reinterpret_cast<f16x8*>(&A16[srow][scc]) = ar;
        __syncthreads();
        const int ktn = (kt + 32 < 1152) ? kt + 32 : kt;
        f16x8 cb = nb;
        ar = *reinterpret_cast<const f16x8*>(sp16 + aoff(ktn));
        nb = *reinterpret_cast<const f16x8*>(bf + boff + ktn);

        f16x8 av[4];
#pragma unroll
        for (int mf = 0; mf < 4; ++mf)
            av[mf] = *reinterpret_cast<const f16x8*>(&A16[rh * 64 + mf * 16 + m][g * 8]);
#pragma unroll
        for (int mf = 0; mf < 4; ++mf)
            acc[mf] = __builtin_amdgcn_mfma_f32_16x16x32_f16(av[mf], cb, acc[mf], 0, 0, 0);
    }
#pragma unroll
    for (int mf = 0; mf < 4; ++mf) {
        int row = tm * 128 + rh * 64 + mf * 16 + g * 4;
#pragma unroll
        for (int r = 0; r < 4; ++r)
            outy[((size_t)b << 20) + (size_t)(row + r) * 1024 + col0] = acc[mf][r];
    }
}

// deconv MFMA fp16: M-tile 128, 512 thr / 8 waves (2 rh x 4 cg of 32).
__global__ __launch_bounds__(512) void k_deconv_mfma(const _Float16* __restrict__ yp16,
                                                     const _Float16* __restrict__ bp,
                                                     float* __restrict__ yup) {
    const int b = blockIdx.z, tm = blockIdx.y, tn = blockIdx.x;   // tn = ij 0..8
    __shared__ _Float16 A16[128][40];
    const int tid = threadIdx.x;
    const int w = tid >> 6, lane = tid & 63, m = lane & 15, g = lane >> 4;
    const int rh = w & 1, cg = w >> 1;
    f32x4 acc[4][2];
#pragma unroll
    for (int mf = 0; mf < 4; ++mf)
#pragma unroll
        for (int nn = 0; nn < 2; ++nn) acc[mf][nn] = f32x4{0.f, 0.f, 0.f, 0.f};
    const int srow = tid >> 2, scc = (tid & 3) * 8;
    const int c0 = cg * 32 + m;
    const _Float16* abase = yp16 + ((size_t)b << 20) + (size_t)(tm * 128 + srow) * 1024 + scc;
    const size_t boff0 = (((size_t)(b * 9 + tn)) * 128 + c0) * 1024 + g * 8;
    const size_t boff1 = (((size_t)(b * 9 + tn)) * 128 + c0 + 16) * 1024 + g * 8;

    f16x8 ar = *reinterpret_cast<const f16x8*>(abase);
    f16x8 nb0 = *reinterpret_cast<const f16x8*>(bp + boff0);
    f16x8 nb1 = *reinterpret_cast<const f16x8*>(bp + boff1);

    for (int kt = 0; kt < 1024; kt += 32) {
        __syncthreads();
        *reinterpret_cast<f16x8*>(&A16[srow][scc]) = ar;
        __syncthreads();
        const int ktn = (kt + 32 < 1024) ? kt + 32 : kt;
        f16x8 cb0 = nb0, cb1 = nb1;
        ar = *reinterpret_cast<const f16x8*>(abase + ktn);
        nb0 = *reinterpret_cast<const f16x8*>(bp + boff0 + ktn);
        nb1 = *reinterpret_cast<const f16x8*>(bp + boff1 + ktn);

        f16x8 av[4];
#pragma unroll
        for (int mf = 0; mf < 4; ++mf)
            av[mf] = *reinterpret_cast<const f16x8*>(&A16[rh * 64 + mf * 16 + m][g * 8]);
#pragma unroll
        for (int mf = 0; mf < 4; ++mf) {
            acc[mf][0] = __builtin_amdgcn_mfma_f32_16x16x32_f16(av[mf], cb0, acc[mf][0], 0, 0, 0);
            acc[mf][1] = __builtin_amdgcn_mfma_f32_16x16x32_f16(av[mf], cb1, acc[mf][1], 0, 0, 0);
        }
    }
    const int ip = (tn >= 6) ? 2 : (tn >= 3 ? 1 : 0);
    const int jp = tn - 3 * ip;
#pragma unroll
    for (int mf = 0; mf < 4; ++mf) {
        int uvb = tm * 128 + rh * 64 + mf * 16 + g * 4;
#pragma unroll
        for (int nn = 0; nn < 2; ++nn) {
            int c = c0 + nn * 16;
#pragma unroll
            for (int r = 0; r < 4; ++r) {
                int uv = uvb + r;
                int uu = uv >> 5, vv = uv & 31;
                int P = 2 * uu + ip, Q = 2 * vv + jp;
                if (P < 64 && Q < 64)
                    atomicAdd(&yup[(((size_t)(b * 64 + P)) * 64 + Q) * 128 + c], acc[mf][nn][r]);
            }
        }
    }
}

__global__ void k_fuse1(const float* __restrict__ in, float* __restrict__ out) {
    size_t idx = (size_t)blockIdx.x * 256 + threadIdx.x;
    if (idx >= (size_t)8 * 1024 * 1024) return;
    int t = (int)(idx & 1023);
    int s = (int)((idx >> 10) & 1023);
    int b = (int)(idx >> 20);
    const float* base = in + ((size_t)b << 20);
    float v = base[(size_t)s * 1024 + t];
    if (s > 0 && t > 0) v += base[(size_t)(s - 1) * 1024 + (t - 1)];
    if (s < 1023 && t < 1023) v += base[(size_t)(s + 1) * 1024 + (t + 1)];
    out[idx] = v;
}

__global__ void k_fuse2(const float* __restrict__ in, float* __restrict__ out) {
    size_t idx = (size_t)blockIdx.x * 256 + threadIdx.x;
    if (idx >= (size_t)8 * 1024 * 1024) return;
    int t = (int)(idx & 1023);
    int s = (int)((idx >> 10) & 1023);
    int b = (int)(idx >> 20);
    int m0 = ((s & 31) << 5) + (s >> 5);
    int n0 = ((t & 31) << 5) + (t >> 5);
    const float* base = in + ((size_t)b << 20);
    float v = 0.f;
#pragma unroll
    for (int d = -1; d <= 1; ++d) {
        int m = m0 + d, n = n0 + d;
        if (m >= 0 && m < 1024 && n >= 0 && n < 1024)
            v += base[(size_t)(((m & 31) << 5) + (m >> 5)) * 1024 + (((n & 31) << 5) + (n >> 5))];
    }
    out[idx] = v;
}

__global__ __launch_bounds__(256) void k_softmax1024(const float* __restrict__ yv,
                                                     const float* __restrict__ mm,
                                                     float* __restrict__ outc,
                                                     _Float16* __restrict__ yp16) {
    int row = blockIdx.x;
    const float* base = yv + (size_t)row * 1024;
    float mmv = mm[row];
    int t = threadIdx.x;
    float vals[4];
    float mx = -1e30f;
#pragma unroll
    for (int i = 0; i < 4; ++i) {
        vals[i] = base[t + i * 256] * mmv * 10.0f;
        mx = fmaxf(mx, vals[i]);
    }
#pragma unroll
    for (int o = 32; o; o >>= 1) mx = fmaxf(mx, __shfl_xor(mx, o));
    __shared__ float red[8];
    if ((t & 63) == 0) red[t >> 6] = mx;
    __syncthreads();
    mx = fmaxf(fmaxf(red[0], red[1]), fmaxf(red[2], red[3]));
    float s = 0.f;
#pragma unroll
    for (int i = 0; i < 4; ++i) {
        vals[i] = expf(vals[i] - mx);
        s += vals[i];
    }
#pragma unroll
    for (int o = 32; o; o >>= 1) s += __shfl_xor(s, o);
    if ((t & 63) == 0) red[4 + (t >> 6)] = s;
    __syncthreads();
    s = red[4] + red[5] + red[6] + red[7];
    float inv = mmv / s;
#pragma unroll
    for (int i = 0; i < 4; ++i) {
        float pv = vals[i] * inv;
        outc[(size_t)row * 1024 + t + i * 256] = pv;
        yp16[(size_t)row * 1024 + t + i * 256] = (_Float16)pv;
    }
}

// f32 image (8,64,64,128) -> padded bf16 hi/lo pair (8,66,66,128), zero halo
__global__ __launch_bounds__(256) void k_pair_pad(const float* __restrict__ in,
                                                  short* __restrict__ hi, short* __restrict__ lo) {
    int idx = blockIdx.x * 256 + threadIdx.x;
    int c8 = idx & 15;
    int r = idx >> 4;
    int pc = r % 66; r /= 66;
    int pr = r % 66; int b = r / 66;
    bf16x8 h, l;
    if (pr >= 1 && pr <= 64 && pc >= 1 && pc <= 64) {
        const float* s = in + (((size_t)(b * 64 + pr - 1)) * 64 + (pc - 1)) * 128 + c8 * 8;
        float4 v0 = *reinterpret_cast<const float4*>(s);
        float4 v1 = *reinterpret_cast<const float4*>(s + 4);
        cvt8(v0, v1, h, l);
    } else {
#pragma unroll
        for (int u = 0; u < 8; ++u) { h[u] = 0; l[u] = 0; }
    }
    size_t off = (size_t)idx * 8;
    *reinterpret_cast<bf16x8*>(hi + off) = h;
    *reinterpret_cast<bf16x8*>(lo + off) = l;
}

__global__ void k_wt_pair(const float* __restrict__ w, short* __restrict__ hi,
                          short* __restrict__ lo, int CI) {
    int idx = blockIdx.x * 256 + threadIdx.x;
    if (idx >= 9 * CI * 128) return;
    int ci = idx % CI; int rest = idx / CI;
    int co = rest & 127; int ij = rest >> 7;
    float v = w[((size_t)ij * CI + ci) * 128 + co];
    short h = f2bf(v);
    hi[idx] = h;
    lo[idx] = f2bf(v - bf2f(h));
}

// pw (1,1,CI,128) f32 -> transposed bf16 [co][ci]
__global__ void k_pw_t(const float* __restrict__ pw, short* __restrict__ out, int CI) {
    int idx = blockIdx.x * 256 + threadIdx.x;
    if (idx >= CI * 128) return;
    int co = idx & 127, ci = idx >> 7;
    out[(size_t)co * CI + ci] = f2bf(pw[idx]);
}

// Fused depthwise 3x3 + pointwise (MFMA, K=CI) + channel softmax -> smout f32.
template <int CI>
__global__ __launch_bounds__(256, 2) void k_dwpw_mfma(const short* __restrict__ in0h,
                                                      const short* __restrict__ in0l,
                                                      const short* __restrict__ in1h,
                                                      const short* __restrict__ in1l,
                                                      const float* __restrict__ dwW,
                                                      const short* __restrict__ pwt,
                                                      const float* __restrict__ db,
                                                      float* __restrict__ smout) {
    const int bid = blockIdx.x;
    const int swz = (bid & 7) * 64 + (bid >> 3);
    const int b = swz >> 6, P = swz & 63;
    const int t = threadIdx.x;
    const int w = t >> 6, lane = t & 63, m = lane & 15, g = lane >> 4;
    __shared__ short Adw[64 * CI];
    __shared__ float red[2][4][64];
    char* ab = (char*)Adw;
    const int px = lane;
    const int cb = w * (CI / 4);
    float dwacc[CI / 4];
#pragma unroll
    for (int u = 0; u < CI / 4; ++u) dwacc[u] = 0.f;
#pragma unroll
    for (int i = 0; i < 3; ++i) {
#pragma unroll
        for (int j = 0; j < 3; ++j) {
            const int ij = i * 3 + j;
#pragma unroll
            for (int c8 = 0; c8 < CI / 32; ++c8) {
                const int c = cb + c8 * 8;
                const short* ph = (CI == 256 && c >= 128) ? in1h : in0h;
                const short* pl = (CI == 256 && c >= 128) ? in1l : in0l;
                const int cc = (CI == 256 && c >= 128) ? (c - 128) : c;
                size_t off = (((size_t)b * 66 + P + i) * 66 + px + j) * 128 + cc;
                bf16x8 vh = *reinterpret_cast<const bf16x8*>(ph + off);
                bf16x8 vl = *reinterpret_cast<const bf16x8*>(pl + off);
#pragma unroll
                for (int u = 0; u < 8; ++u) {
                    float v = bf2f(vh[u]) + bf2f(vl[u]);
                    dwacc[c8 * 8 + u] = fmaf(v, dwW[ij * CI + c + u], dwacc[c8 * 8 + u]);
                }
            }
        }
    }
#pragma unroll
    for (int c8 = 0; c8 < CI / 32; ++c8) {
        bf16x8 hv;
#pragma unroll
        for (int u = 0; u < 8; ++u) hv[u] = f2bf(dwacc[c8 * 8 + u]);
        int byte = px * (CI * 2) + (cb + c8 * 8) * 2;
        int sz = byte ^ ((px & 7) << 4);
        *reinterpret_cast<bf16x8*>(ab + sz) = hv;
    }
    __syncthreads();
    f32x4 acc[4][2];
#pragma unroll
    for (int mt = 0; mt < 4; ++mt)
#pragma unroll
        for (int nn = 0; nn < 2; ++nn) acc[mt][nn] = f32x4{0.f, 0.f, 0.f, 0.f};
    const int co0 = w * 32 + m;
#pragma unroll
    for (int kc = 0; kc < CI / 32; ++kc) {
        bf16x8 av[4];
#pragma unroll
        for (int mt = 0; mt < 4; ++mt) {
            int prow = mt * 16 + m;
            int byte = prow * (CI * 2) + (kc * 32 + g * 8) * 2;
            int sz = byte ^ ((prow & 7) << 4);
            av[mt] = *reinterpret_cast<const bf16x8*>(ab + sz);
        }
#pragma unroll
        for (int nn = 0; nn < 2; ++nn) {
            bf16x8 bv = *reinterpret_cast<const bf16x8*>(pwt + (size_t)(co0 + nn * 16) * CI + kc * 32 + g * 8);
#pragma unroll
            for (int mt = 0; mt < 4; ++mt)
                acc[mt][nn] = __builtin_amdgcn_mfma_f32_16x16x32_bf16(av[mt], bv, acc[mt][nn], 0, 0, 0);
        }
    }
    float db0 = db[co0], db1 = db[co0 + 16];
    float mx[4][4];
#pragma unroll
    for (int mt = 0; mt < 4; ++mt)
#pragma unroll
        for (int r = 0; r < 4; ++r) {
            acc[mt][0][r] += db0;
            acc[mt][1][r] += db1;
            float v = fmaxf(acc[mt][0][r], acc[mt][1][r]);
#pragma unroll
            for (int o = 1; o <= 8; o <<= 1) v = fmaxf(v, __shfl_xor(v, o));
            mx[mt][r] = v;
        }
    if (m == 0) {
#pragma unroll
        for (int mt = 0; mt < 4; ++mt)
#pragma unroll
            for (int r = 0; r < 4; ++r) red[0][w][mt * 16 + g * 4 + r] = mx[mt][r];
    }
    __syncthreads();
    float sume[4][4];
#pragma unroll
    for (int mt = 0; mt < 4; ++mt)
#pragma unroll
        for (int r = 0; r < 4; ++r) {
            int p = mt * 16 + g * 4 + r;
            float M = fmaxf(fmaxf(red[0][0][p], red[0][1][p]), fmaxf(red[0][2][p], red[0][3][p]));
            acc[mt][0][r] = expf(acc[mt][0][r] - M);
            acc[mt][1][r] = expf(acc[mt][1][r] - M);
            float s = acc[mt][0][r] + acc[mt][1][r];
#pragma unroll
            for (int o = 1; o <= 8; o <<= 1) s += __shfl_xor(s, o);
            sume[mt][r] = s;
        }
    if (m == 0) {
#pragma unroll
        for (int mt = 0; mt < 4; ++mt)
#pragma unroll
            for (int r = 0; r < 4; ++r) red[1][w][mt * 16 + g * 4 + r] = sume[mt][r];
    }
    __syncthreads();
#pragma unroll
    for (int mt = 0; mt < 4; ++mt)
#pragma unroll
        for (int r = 0; r < 4; ++r) {
            int p = mt * 16 + g * 4 + r;
            float S = red[1][0][p] + red[1][1][p] + red[1][2][p] + red[1][3][p];
            float inv = 1.0f / S;
            size_t pix = ((size_t)b * 64 + P) * 64 + p;
            smout[pix * 128 + co0] = acc[mt][0][r] * inv;
            smout[pix * 128 + co0 + 16] = acc[mt][1][r] * inv;
        }
}

// MFMA split-bf16 implicit-GEMM 3x3 conv + bias + elu + gate, LDS-staged rows.
template <int CI>
__global__ __launch_bounds__(256, 4) void k_conv_lds(const short* __restrict__ in0h,
                                                     const short* __restrict__ in0l,
                                                     const short* __restrict__ in1h,
                                                     const short* __restrict__ in1l,
                                                     const short* __restrict__ wh,
                                                     const short* __restrict__ wl,
                                                     const float* __restrict__ bias,
                                                     const float* __restrict__ sm,
                                                     float* __restrict__ out) {
    const int bid = blockIdx.x;
    const int idx = (bid & 7) * 128 + (bid >> 3);
    const int row = idx >> 1, cohalf = idx & 1;
    const int b = row >> 6, P = row & 63;
    const int tid = threadIdx.x;
    const int w = tid >> 6, lane = tid & 63;
    const int m = lane & 15, g = lane >> 4;
    __shared__ short Sh[66 * 128];
    __shared__ short Sl[66 * 128];
    char* shb = (char*)Sh;
    char* slb = (char*)Sl;
    f32x4 acc[4];
#pragma unroll
    for (int mt = 0; mt < 4; ++mt) acc[mt] = f32x4{0.f, 0.f, 0.f, 0.f};
    const int cow = cohalf * 64 + w * 16 + m;

#pragma unroll
    for (int half = 0; half < CI / 128; ++half) {
        const short* ih = (half == 0) ? in0h : in1h;
        const short* il = (half == 0) ? in0l : in1l;
        const size_t rbase0 = ((size_t)b * 66 + P) * 66 * 128;
#pragma unroll
        for (int i = 0; i < 3; ++i) {
            __syncthreads();
            const size_t rsrc = rbase0 + (size_t)i * 66 * 128;
#pragma unroll
            for (int e0 = 0; e0 < 1056; e0 += 256) {
                int e = e0 + tid;
                if (e < 1056) {
                    int px = e >> 4, c8 = e & 15;
                    int lin = px * 256 + c8 * 16;
                    int sz = lin ^ ((px & 7) << 4);
                    size_t so = rsrc + (size_t)px * 128 + c8 * 8;
                    *reinterpret_cast<bf16x8*>(shb + sz) = *reinterpret_cast<const bf16x8*>(ih + so);
                    *reinterpret_cast<bf16x8*>(slb + sz) = *reinterpret_cast<const bf16x8*>(il + so);
                }
            }
            __syncthreads();
#pragma unroll
            for (int j = 0; j < 3; ++j) {
                const int ij = i * 3 + j;
                const short* wph = wh + ((size_t)ij * 128 + cow) * CI + half * 128 + g * 8;
                const short* wpl = wl + ((size_t)ij * 128 + cow) * CI + half * 128 + g * 8;
#pragma unroll
                for (int ci0 = 0; ci0 < 128; ci0 += 32) {
                    bf16x8 bh = *reinterpret_cast<const bf16x8*>(wph + ci0);
                    bf16x8 bl = *reinterpret_cast<const bf16x8*>(wpl + ci0);
                    bf16x8 ah[4], al[4];
#pragma unroll
                    for (int mt = 0; mt < 4; ++mt) {
                        int px = mt * 16 + m + j;
                        int lin = px * 256 + ci0 * 2 + g * 16;
                        int sz = lin ^ ((px & 7) << 4);
                        ah[mt] = *reinterpret_cast<const bf16x8*>(shb + sz);
                        al[mt] = *reinterpret_cast<const bf16x8*>(slb + sz);
                    }
#pragma unroll
                    for (int mt = 0; mt < 4; ++mt) {
                        acc[mt] = __builtin_amdgcn_mfma_f32_16x16x32_bf16(ah[mt], bh, acc[mt], 0, 0, 0);
                        acc[mt] = __builtin_amdgcn_mfma_f32_16x16x32_bf16(ah[mt], bl, acc[mt], 0, 0, 0);
                        acc[mt] = __builtin_amdgcn_mfma_f32_16x16x32_bf16(al[mt], bh, acc[mt], 0, 0, 0);
                    }
                }
            }
        }
    }
    const float bb = bias[cow];
#pragma unroll
    for (int mt = 0; mt < 4; ++mt) {
#pragma unroll
        for (int r = 0; r < 4; ++r) {
            int Q = mt * 16 + g * 4 + r;
            size_t pix = ((size_t)b * 64 + P) * 64 + Q;
            float z = acc[mt][r] + bb;
            z = z > 0.f ? z : expm1f(z);
            out[pix * 128 + cow] = z * sm[pix * 128 + cow];
        }
    }
}

extern "C" void kernel_launch(void* const* d_in, const int* in_sizes, int n_in,
                              void* d_out, int out_size, void* d_ws, size_t ws_size,
                              hipStream_t stream) {
    const float* x    = (const float*)d_in[0];
    const float* mask = (const float*)d_in[1];
    const float* w1   = (const float*)d_in[2];
    const float* b1   = (const float*)d_in[3];
    const float* dw1  = (const float*)d_in[4];
    const float* pw1  = (const float*)d_in[5];
    const float* db1  = (const float*)d_in[6];
    const float* w2   = (const float*)d_in[7];
    const float* b2   = (const float*)d_in[8];
    const float* dw2  = (const float*)d_in[9];
    const float* pw2  = (const float*)d_in[10];
    const float* db2  = (const float*)d_in[11];

    float* out_a = (float*)d_out;            // (8,64,64,128)
    float* out_c = out_a + 4194304;          // (8,32,32,1024)

    char* wsb = (char*)d_ws;
    float* sp     = (float*)(wsb + BOFF_SP);
    float* invd   = (float*)(wsb + BOFF_INVD);
    _Float16* sp16 = (_Float16*)(wsb + BOFF_SP16);
    _Float16* bf16b = (_Float16*)(wsb + BOFF_BF16);
    float* Tbuf   = (float*)(wsb + BOFF_T);
    _Float16* bp16 = (_Float16*)(wsb + BOFF_BP16);
    _Float16* yp16 = (_Float16*)(wsb + BOFF_YP16);
    float* yup    = (float*)(wsb + BOFF_YUP);
    float* smb    = (float*)(wsb + BOFF_SM);
    short* p3h    = (short*)(wsb + BOFF_P3H);
    short* p3l    = (short*)(wsb + BOFF_P3L);
    float* a1     = (float*)(wsb + BOFF_A1);
    short* xh     = (short*)(wsb + BOFF_XH);
    short* xl     = (short*)(wsb + BOFF_XL);
    short* wt1h   = (short*)(wsb + BOFF_WT1H);
    short* wt1l   = (short*)(wsb + BOFF_WT1L);
    short* wt2h   = (short*)(wsb + BOFF_WT2H);
    short* wt2l   = (short*)(wsb + BOFF_WT2L);
    short* pw1t   = (short*)(wsb + BOFF_PW1B);
    short* pw2t   = (short*)(wsb + BOFF_PW2B);
    float* m0     = (float*)(wsb + BOFF_M0);
    float* mmb    = (float*)(wsb + BOFF_MM);

    // phase A: mask + correlation (fp16 MFMA) + fuse + softmax
    k_mask_pool<<<8192, 256, 0, stream>>>(mask, m0);
    k_mask_dilate<<<32, 256, 0, stream>>>(m0, mmb);
    k_srcpad<<<4624, 256, 0, stream>>>(x, sp);
    k_sp16<<<579, 256, 0, stream>>>(sp, sp16);
    k_invd<<<512, 256, 0, stream>>>(sp, invd);
    k_wt_pair<<<576, 256, 0, stream>>>(w1, wt1h, wt1l, 128);
    k_wt_pair<<<1152, 256, 0, stream>>>(w2, wt2h, wt2l, 256);
    k_pw_t<<<64, 256, 0, stream>>>(pw1, pw1t, 128);
    k_pw_t<<<128, 256, 0, stream>>>(pw2, pw2t, 256);
    k_corr_B16<<<4608, 256, 0, stream>>>(sp, invd, bf16b);
    k_corr_mfma<<<dim3(16, 8, 8), 512, 0, stream>>>(sp16, bf16b, out_c);
    k_fuse1<<<32768, 256, 0, stream>>>(out_c, Tbuf);
    k_fuse2<<<32768, 256, 0, stream>>>(Tbuf, out_c);
    k_deconv_B16<<<4608, 256, 0, stream>>>(x, bp16);
    k_softmax1024<<<8192, 256, 0, stream>>>(out_c, mmb, out_c, yp16);
    // phase B: deconv (fp16 MFMA) -> yup
    hipMemsetAsync(yup, 0, (size_t)4194304 * sizeof(float), stream);
    k_deconv_mfma<<<dim3(9, 8, 8), 512, 0, stream>>>(yp16, bp16, yup);
    // phase C: gated conv 1
    k_pair_pad<<<2178, 256, 0, stream>>>(yup, p3h, p3l);
    k_pair_pad<<<2178, 256, 0, stream>>>(x, xh, xl);
    k_dwpw_mfma<128><<<512, 256, 0, stream>>>(p3h, p3l, nullptr, nullptr,
                                              dw1, pw1t, db1, smb);
    k_conv_lds<128><<<1024, 256, 0, stream>>>(p3h, p3l, nullptr, nullptr,
                                              wt1h, wt1l, b1, smb, a1);
    // phase D: gated conv 2 (concat(a1, x))
    k_pair_pad<<<2178, 256, 0, stream>>>(a1, p3h, p3l);
    k_dwpw_mfma<256><<<512, 256, 0, stream>>>(p3h, p3l, xh, xl,
                                              dw2, pw2t, db2, smb);
    k_conv_lds<256><<<1024, 256, 0, stream>>>(p3h, p3l, xh, xl,
                                              wt2h, wt2l, b2, smb, out_a);
}

// Round 13
// 434.462 us; speedup vs baseline: 2.5246x; 1.2629x over previous
//
#include <hip/hip_runtime.h>
#include <hip/hip_bf16.h>

// B=8, H=W=64, C=128, rate=2 -> k=3, h=w=32, L=1024
// Workspace (72,433,664 bytes), time-multiplexed (liveness checked):
//  phase A: sp [0,4.73M) invd [4.73,5.26M) sp16 [5.26,7.63M) Bf16 [7.63,26.5M)
//  fuse:    T [0,33.55M)
//  deconv:  Bp16 [0,18.87M) yp16 [18.87,35.65M) yup [37.75,54.53M)
//  phase C/D: SM [0,16.78M) P3 fp16 [16.78,25.70M) A1 [25.70,42.48M) X16 [42.48,51.40M)
//  static:  wt1 [69.24M) wt2 [69.83M) pw1 [71.01M) pw2 [71.04M) m0/mm [71.11M)

#define BOFF_SP      0
#define BOFF_INVD    4734976
#define BOFF_SP16    5259264
#define BOFF_BF16    7626752
#define BOFF_T       0
#define BOFF_BP16    0
#define BOFF_YP16    18874368
#define BOFF_YUP     37748736
#define BOFF_SM      0
#define BOFF_P316    16777216
#define BOFF_A1      25698304
#define BOFF_X16     42475520
#define BOFF_WT1     69238784
#define BOFF_WT2     69828608
#define BOFF_PW1     71008256
#define BOFF_PW2     71041024
#define BOFF_M0      71106560
#define BOFF_MM      71139328

typedef float f32x4 __attribute__((ext_vector_type(4)));
typedef _Float16 f16x8 __attribute__((ext_vector_type(8)));

__global__ __launch_bounds__(256) void k_mask_pool(const float* __restrict__ mask, float* __restrict__ m0) {
    int blk = blockIdx.x;
    int b = blk >> 10, pq = blk & 1023, p = pq >> 5, q = pq & 31;
    int t = threadIdx.x, dy = t >> 4, dx = t & 15;
    float v = mask[((size_t)(b * 512 + p * 16 + dy)) * 512 + q * 16 + dx];
#pragma unroll
    for (int o = 32; o; o >>= 1) v = fmaxf(v, __shfl_xor(v, o));
    __shared__ float s[4];
    if ((t & 63) == 0) s[t >> 6] = v;
    __syncthreads();
    if (t == 0) m0[blk] = fmaxf(fmaxf(s[0], s[1]), fmaxf(s[2], s[3]));
}

__global__ void k_mask_dilate(const float* __restrict__ m0, float* __restrict__ mm) {
    int idx = blockIdx.x * 256 + threadIdx.x;
    if (idx >= 8192) return;
    int b = idx >> 10, pq = idx & 1023, p = pq >> 5, q = pq & 31;
    float v = -1e30f;
    for (int di = -1; di <= 1; ++di)
        for (int dj = -1; dj <= 1; ++dj) {
            int pp = p + di, qq = q + dj;
            if (pp >= 0 && pp < 32 && qq >= 0 && qq < 32)
                v = fmaxf(v, m0[(b << 10) + pp * 32 + qq]);
        }
    mm[idx] = 1.0f - v;
}

__global__ void k_srcpad(const float* __restrict__ x, float* __restrict__ sp) {
    int idx = blockIdx.x * 256 + threadIdx.x;
    if (idx >= 8 * 34 * 34 * 128) return;
    int c = idx & 127;
    int r = idx >> 7;
    int xx = r % 34; r /= 34;
    int yy = r % 34; int b = r / 34;
    float v = 0.f;
    if (yy >= 1 && yy <= 32 && xx >= 1 && xx <= 32)
        v = x[(((size_t)(b * 64 + (yy - 1) * 2)) * 64 + (xx - 1) * 2) * 128 + c];
    sp[idx] = v;
}

// sp f32 -> fp16
__global__ void k_sp16(const float* __restrict__ sp, _Float16* __restrict__ o) {
    int idx = blockIdx.x * 256 + threadIdx.x;
    if (idx >= 147968) return;
    const float* s = sp + (size_t)idx * 8;
    float4 v0 = *reinterpret_cast<const float4*>(s);
    float4 v1 = *reinterpret_cast<const float4*>(s + 4);
    f16x8 h;
    h[0] = (_Float16)v0.x; h[1] = (_Float16)v0.y; h[2] = (_Float16)v0.z; h[3] = (_Float16)v0.w;
    h[4] = (_Float16)v1.x; h[5] = (_Float16)v1.y; h[6] = (_Float16)v1.z; h[7] = (_Float16)v1.w;
    *reinterpret_cast<f16x8*>(o + (size_t)idx * 8) = h;
}

__global__ void k_invd(const float* __restrict__ sp, float* __restrict__ invd) {
    int idx = blockIdx.x * 256 + threadIdx.x;
    if (idx >= 1024 * 128) return;
    int c = idx & 127, l = idx >> 7, lh = l >> 5, lw = l & 31;
    float s = 0.f;
    for (int b = 0; b < 8; ++b)
#pragma unroll
        for (int i = 0; i < 3; ++i)
#pragma unroll
            for (int j = 0; j < 3; ++j) {
                float v = sp[(((size_t)(b * 34 + lh + i)) * 34 + (lw + j)) * 128 + c];
                s += v * v;
            }
    invd[idx] = 1.0f / fmaxf(s, 1e-8f);
}

// Bf16[b][l][ij][c] = sp[b][lh+i][lw+j][c] * invd[l][c], fp16.
__global__ void k_corr_B16(const float* __restrict__ sp, const float* __restrict__ invd,
                           _Float16* __restrict__ bf) {
    int idx = blockIdx.x * 256 + threadIdx.x;
    if (idx >= 1179648) return;
    int c8 = idx & 15; int rest = idx >> 4;
    int ij = rest % 9; int rest2 = rest / 9;
    int l = rest2 & 1023, b = rest2 >> 10;
    int lh = l >> 5, lw = l & 31;
    int i = (ij >= 6) ? 2 : (ij >= 3 ? 1 : 0);
    int j = ij - 3 * i;
    int c0 = c8 * 8;
    const float* s = sp + (((size_t)(b * 34 + lh + i)) * 34 + (lw + j)) * 128 + c0;
    const float* dv = invd + l * 128 + c0;
    f16x8 h;
#pragma unroll
    for (int u = 0; u < 8; ++u) h[u] = (_Float16)(s[u] * dv[u]);
    size_t off = ((size_t)(b * 1024 + l)) * 1152 + ij * 128 + c0;
    *reinterpret_cast<f16x8*>(bf + off) = h;
}

// Bp16[b][ij][c][l] = x[b][2lh+ip][2lw+jp][c] (0 OOB), fp16.
__global__ void k_deconv_B16(const float* __restrict__ x, _Float16* __restrict__ bp) {
    int idx = blockIdx.x * 256 + threadIdx.x;
    if (idx >= 1179648) return;
    int l8 = idx & 127; int rest = idx >> 7;
    int c = rest & 127; int rest2 = rest >> 7;
    int ij = rest2 % 9; int b = rest2 / 9;
    int ip = (ij >= 6) ? 2 : (ij >= 3 ? 1 : 0);
    int jp = ij - 3 * ip;
    int l0 = l8 * 8;
    int lh = l0 >> 5, lw0 = l0 & 31;
    int rr = 2 * lh + ip;
    f16x8 h;
#pragma unroll
    for (int u = 0; u < 8; ++u) {
        int ss = 2 * (lw0 + u) + jp;
        float v = (rr < 64 && ss < 64) ? x[(((size_t)(b * 64 + rr)) * 64 + ss) * 128 + c] : 0.f;
        h[u] = (_Float16)v;
    }
    size_t off = (((size_t)(b * 9 + ij)) * 128 + c) * 1024 + l0;
    *reinterpret_cast<f16x8*>(bp + off) = h;
}

// corr MFMA fp16: M-tile 128, N-tile 64, grid (16,8,8).
__global__ __launch_bounds__(512) void k_corr_mfma(const _Float16* __restrict__ sp16,
                                                   const _Float16* __restrict__ bf,
                                                   float* __restrict__ outy) {
    const int b = blockIdx.z, tm = blockIdx.y, tn = blockIdx.x;
    __shared__ _Float16 A16[128][40];
    const int tid = threadIdx.x;
    const int w = tid >> 6, lane = tid & 63, m = lane & 15, g = lane >> 4;
    const int rh = w & 1, cg = w >> 1;
    f32x4 acc[4];
#pragma unroll
    for (int mf = 0; mf < 4; ++mf) acc[mf] = f32x4{0.f, 0.f, 0.f, 0.f};
    const int srow = tid >> 2, scc = (tid & 3) * 8;
    const int pq = tm * 128 + srow, p = pq >> 5, q = pq & 31;
    const int col0 = tn * 64 + cg * 16 + m;
    const size_t boff = ((size_t)b * 1024 + col0) * 1152 + g * 8;

    auto aoff = [&](int kt) -> size_t {
        int ij = kt >> 7;
        int i = (ij >= 6) ? 2 : (ij >= 3 ? 1 : 0);
        int j = ij - 3 * i;
        int c0 = (kt & 127) + scc;
        return (((size_t)(b * 34 + p + i)) * 34 + (q + j)) * 128 + c0;
    };
    f16x8 ar = *reinterpret_cast<const f16x8*>(sp16 + aoff(0));
    f16x8 nb = *reinterpret_cast<const f16x8*>(bf + boff);

    for (int kt = 0; kt < 1152; kt += 32) {
        __syncthreads();
        *reinterpret_cast<f16x8*>(&A16[srow][scc]) = ar;
        __syncthreads();
        const int ktn = (kt + 32 < 1152) ? kt + 32 : kt;
        f16x8 cb = nb;
        ar = *reinterpret_cast<const f16x8*>(sp16 + aoff(ktn));
        nb = *reinterpret_cast<const f16x8*>(bf + boff + ktn);

        f16x8 av[4];
#pragma unroll
        for (int mf = 0; mf < 4; ++mf)
            av[mf] = *reinterpret_cast<const f16x8*>(&A16[rh * 64 + mf * 16 + m][g * 8]);
#pragma unroll
        for (int mf = 0; mf < 4; ++mf)
            acc[mf] = __builtin_amdgcn_mfma_f32_16x16x32_f16(av[mf], cb, acc[mf], 0, 0, 0);
    }
#pragma unroll
    for (int mf = 0; mf < 4; ++mf) {
        int row = tm * 128 + rh * 64 + mf * 16 + g * 4;
#pragma unroll
        for (int r = 0; r < 4; ++r)
            outy[((size_t)b << 20) + (size_t)(row + r) * 1024 + col0] = acc[mf][r];
    }
}

// deconv MFMA fp16: M-tile 128.
__global__ __launch_bounds__(512) void k_deconv_mfma(const _Float16* __restrict__ yp16,
                                                     const _Float16* __restrict__ bp,
                                                     float* __restrict__ yup) {
    const int b = blockIdx.z, tm = blockIdx.y, tn = blockIdx.x;   // tn = ij 0..8
    __shared__ _Float16 A16[128][40];
    const int tid = threadIdx.x;
    const int w = tid >> 6, lane = tid & 63, m = lane & 15, g = lane >> 4;
    const int rh = w & 1, cg = w >> 1;
    f32x4 acc[4][2];
#pragma unroll
    for (int mf = 0; mf < 4; ++mf)
#pragma unroll
        for (int nn = 0; nn < 2; ++nn) acc[mf][nn] = f32x4{0.f, 0.f, 0.f, 0.f};
    const int srow = tid >> 2, scc = (tid & 3) * 8;
    const int c0 = cg * 32 + m;
    const _Float16* abase = yp16 + ((size_t)b << 20) + (size_t)(tm * 128 + srow) * 1024 + scc;
    const size_t boff0 = (((size_t)(b * 9 + tn)) * 128 + c0) * 1024 + g * 8;
    const size_t boff1 = (((size_t)(b * 9 + tn)) * 128 + c0 + 16) * 1024 + g * 8;

    f16x8 ar = *reinterpret_cast<const f16x8*>(abase);
    f16x8 nb0 = *reinterpret_cast<const f16x8*>(bp + boff0);
    f16x8 nb1 = *reinterpret_cast<const f16x8*>(bp + boff1);

    for (int kt = 0; kt < 1024; kt += 32) {
        __syncthreads();
        *reinterpret_cast<f16x8*>(&A16[srow][scc]) = ar;
        __syncthreads();
        const int ktn = (kt + 32 < 1024) ? kt + 32 : kt;
        f16x8 cb0 = nb0, cb1 = nb1;
        ar = *reinterpret_cast<const f16x8*>(abase + ktn);
        nb0 = *reinterpret_cast<const f16x8*>(bp + boff0 + ktn);
        nb1 = *reinterpret_cast<const f16x8*>(bp + boff1 + ktn);

        f16x8 av[4];
#pragma unroll
        for (int mf = 0; mf < 4; ++mf)
            av[mf] = *reinterpret_cast<const f16x8*>(&A16[rh * 64 + mf * 16 + m][g * 8]);
#pragma unroll
        for (int mf = 0; mf < 4; ++mf) {
            acc[mf][0] = __builtin_amdgcn_mfma_f32_16x16x32_f16(av[mf], cb0, acc[mf][0], 0, 0, 0);
            acc[mf][1] = __builtin_amdgcn_mfma_f32_16x16x32_f16(av[mf], cb1, acc[mf][1], 0, 0, 0);
        }
    }
    const int ip = (tn >= 6) ? 2 : (tn >= 3 ? 1 : 0);
    const int jp = tn - 3 * ip;
#pragma unroll
    for (int mf = 0; mf < 4; ++mf) {
        int uvb = tm * 128 + rh * 64 + mf * 16 + g * 4;
#pragma unroll
        for (int nn = 0; nn < 2; ++nn) {
            int c = c0 + nn * 16;
#pragma unroll
            for (int r = 0; r < 4; ++r) {
                int uv = uvb + r;
                int uu = uv >> 5, vv = uv & 31;
                int P = 2 * uu + ip, Q = 2 * vv + jp;
                if (P < 64 && Q < 64)
                    atomicAdd(&yup[(((size_t)(b * 64 + P)) * 64 + Q) * 128 + c], acc[mf][nn][r]);
            }
        }
    }
}

__global__ void k_fuse1(const float* __restrict__ in, float* __restrict__ out) {
    size_t idx = (size_t)blockIdx.x * 256 + threadIdx.x;
    if (idx >= (size_t)8 * 1024 * 1024) return;
    int t = (int)(idx & 1023);
    int s = (int)((idx >> 10) & 1023);
    int b = (int)(idx >> 20);
    const float* base = in + ((size_t)b << 20);
    float v = base[(size_t)s * 1024 + t];
    if (s > 0 && t > 0) v += base[(size_t)(s - 1) * 1024 + (t - 1)];
    if (s < 1023 && t < 1023) v += base[(size_t)(s + 1) * 1024 + (t + 1)];
    out[idx] = v;
}

__global__ void k_fuse2(const float* __restrict__ in, float* __restrict__ out) {
    size_t idx = (size_t)blockIdx.x * 256 + threadIdx.x;
    if (idx >= (size_t)8 * 1024 * 1024) return;
    int t = (int)(idx & 1023);
    int s = (int)((idx >> 10) & 1023);
    int b = (int)(idx >> 20);
    int m0 = ((s & 31) << 5) + (s >> 5);
    int n0 = ((t & 31) << 5) + (t >> 5);
    const float* base = in + ((size_t)b << 20);
    float v = 0.f;
#pragma unroll
    for (int d = -1; d <= 1; ++d) {
        int m = m0 + d, n = n0 + d;
        if (m >= 0 && m < 1024 && n >= 0 && n < 1024)
            v += base[(size_t)(((m & 31) << 5) + (m >> 5)) * 1024 + (((n & 31) << 5) + (n >> 5))];
    }
    out[idx] = v;
}

__global__ __launch_bounds__(256) void k_softmax1024(const float* __restrict__ yv,
                                                     const float* __restrict__ mm,
                                                     float* __restrict__ outc,
                                                     _Float16* __restrict__ yp16) {
    int row = blockIdx.x;
    const float* base = yv + (size_t)row * 1024;
    float mmv = mm[row];
    int t = threadIdx.x;
    float vals[4];
    float mx = -1e30f;
#pragma unroll
    for (int i = 0; i < 4; ++i) {
        vals[i] = base[t + i * 256] * mmv * 10.0f;
        mx = fmaxf(mx, vals[i]);
    }
#pragma unroll
    for (int o = 32; o; o >>= 1) mx = fmaxf(mx, __shfl_xor(mx, o));
    __shared__ float red[8];
    if ((t & 63) == 0) red[t >> 6] = mx;
    __syncthreads();
    mx = fmaxf(fmaxf(red[0], red[1]), fmaxf(red[2], red[3]));
    float s = 0.f;
#pragma unroll
    for (int i = 0; i < 4; ++i) {
        vals[i] = expf(vals[i] - mx);
        s += vals[i];
    }
#pragma unroll
    for (int o = 32; o; o >>= 1) s += __shfl_xor(s, o);
    if ((t & 63) == 0) red[4 + (t >> 6)] = s;
    __syncthreads();
    s = red[4] + red[5] + red[6] + red[7];
    float inv = mmv / s;
#pragma unroll
    for (int i = 0; i < 4; ++i) {
        float pv = vals[i] * inv;
        outc[(size_t)row * 1024 + t + i * 256] = pv;
        yp16[(size_t)row * 1024 + t + i * 256] = (_Float16)pv;
    }
}

// f32 image (8,64,64,128) -> padded fp16 (8,66,66,128), zero halo
__global__ __launch_bounds__(256) void k_pad16(const float* __restrict__ in,
                                               _Float16* __restrict__ o) {
    int idx = blockIdx.x * 256 + threadIdx.x;
    int c8 = idx & 15;
    int r = idx >> 4;
    int pc = r % 66; r /= 66;
    int pr = r % 66; int b = r / 66;
    f16x8 h;
    if (pr >= 1 && pr <= 64 && pc >= 1 && pc <= 64) {
        const float* s = in + (((size_t)(b * 64 + pr - 1)) * 64 + (pc - 1)) * 128 + c8 * 8;
        float4 v0 = *reinterpret_cast<const float4*>(s);
        float4 v1 = *reinterpret_cast<const float4*>(s + 4);
        h[0] = (_Float16)v0.x; h[1] = (_Float16)v0.y; h[2] = (_Float16)v0.z; h[3] = (_Float16)v0.w;
        h[4] = (_Float16)v1.x; h[5] = (_Float16)v1.y; h[6] = (_Float16)v1.z; h[7] = (_Float16)v1.w;
    } else {
#pragma unroll
        for (int u = 0; u < 8; ++u) h[u] = (_Float16)0.f;
    }
    *reinterpret_cast<f16x8*>(o + (size_t)idx * 8) = h;
}

// (3,3,CI,128) f32 -> [9][co=128][ci] fp16
__global__ void k_wt16(const float* __restrict__ w, _Float16* __restrict__ o, int CI) {
    int idx = blockIdx.x * 256 + threadIdx.x;
    if (idx >= 9 * CI * 128) return;
    int ci = idx % CI; int rest = idx / CI;
    int co = rest & 127; int ij = rest >> 7;
    o[idx] = (_Float16)w[((size_t)ij * CI + ci) * 128 + co];
}

// pw (1,1,CI,128) f32 -> transposed fp16 [co][ci]
__global__ void k_pw16(const float* __restrict__ pw, _Float16* __restrict__ out, int CI) {
    int idx = blockIdx.x * 256 + threadIdx.x;
    if (idx >= CI * 128) return;
    int co = idx & 127, ci = idx >> 7;
    out[(size_t)co * CI + ci] = (_Float16)pw[idx];
}

// Fused depthwise 3x3 + pointwise (fp16 MFMA) + channel softmax -> smout f32.
template <int CI>
__global__ __launch_bounds__(256, 2) void k_dwpw_mfma(const _Float16* __restrict__ in0,
                                                      const _Float16* __restrict__ in1,
                                                      const float* __restrict__ dwW,
                                                      const _Float16* __restrict__ pwt,
                                                      const float* __restrict__ db,
                                                      float* __restrict__ smout) {
    const int bid = blockIdx.x;
    const int swz = (bid & 7) * 64 + (bid >> 3);
    const int b = swz >> 6, P = swz & 63;
    const int t = threadIdx.x;
    const int w = t >> 6, lane = t & 63, m = lane & 15, g = lane >> 4;
    __shared__ _Float16 Adw[64 * CI];
    __shared__ float red[2][4][64];
    char* ab = (char*)Adw;
    const int px = lane;
    const int cb = w * (CI / 4);
    float dwacc[CI / 4];
#pragma unroll
    for (int u = 0; u < CI / 4; ++u) dwacc[u] = 0.f;
#pragma unroll
    for (int i = 0; i < 3; ++i) {
#pragma unroll
        for (int j = 0; j < 3; ++j) {
            const int ij = i * 3 + j;
#pragma unroll
            for (int c8 = 0; c8 < CI / 32; ++c8) {
                const int c = cb + c8 * 8;
                const _Float16* ph = (CI == 256 && c >= 128) ? in1 : in0;
                const int cc = (CI == 256 && c >= 128) ? (c - 128) : c;
                size_t off = (((size_t)b * 66 + P + i) * 66 + px + j) * 128 + cc;
                f16x8 vh = *reinterpret_cast<const f16x8*>(ph + off);
#pragma unroll
                for (int u = 0; u < 8; ++u)
                    dwacc[c8 * 8 + u] = fmaf((float)vh[u], dwW[ij * CI + c + u], dwacc[c8 * 8 + u]);
            }
        }
    }
#pragma unroll
    for (int c8 = 0; c8 < CI / 32; ++c8) {
        f16x8 hv;
#pragma unroll
        for (int u = 0; u < 8; ++u) hv[u] = (_Float16)dwacc[c8 * 8 + u];
        int byte = px * (CI * 2) + (cb + c8 * 8) * 2;
        int sz = byte ^ ((px & 7) << 4);
        *reinterpret_cast<f16x8*>(ab + sz) = hv;
    }
    __syncthreads();
    f32x4 acc[4][2];
#pragma unroll
    for (int mt = 0; mt < 4; ++mt)
#pragma unroll
        for (int nn = 0; nn < 2; ++nn) acc[mt][nn] = f32x4{0.f, 0.f, 0.f, 0.f};
    const int co0 = w * 32 + m;
#pragma unroll
    for (int kc = 0; kc < CI / 32; ++kc) {
        f16x8 av[4];
#pragma unroll
        for (int mt = 0; mt < 4; ++mt) {
            int prow = mt * 16 + m;
            int byte = prow * (CI * 2) + (kc * 32 + g * 8) * 2;
            int sz = byte ^ ((prow & 7) << 4);
            av[mt] = *reinterpret_cast<const f16x8*>(ab + sz);
        }
#pragma unroll
        for (int nn = 0; nn < 2; ++nn) {
            f16x8 bv = *reinterpret_cast<const f16x8*>(pwt + (size_t)(co0 + nn * 16) * CI + kc * 32 + g * 8);
#pragma unroll
            for (int mt = 0; mt < 4; ++mt)
                acc[mt][nn] = __builtin_amdgcn_mfma_f32_16x16x32_f16(av[mt], bv, acc[mt][nn], 0, 0, 0);
        }
    }
    float db0 = db[co0], db1 = db[co0 + 16];
    float mx[4][4];
#pragma unroll
    for (int mt = 0; mt < 4; ++mt)
#pragma unroll
        for (int r = 0; r < 4; ++r) {
            acc[mt][0][r] += db0;
            acc[mt][1][r] += db1;
            float v = fmaxf(acc[mt][0][r], acc[mt][1][r]);
#pragma unroll
            for (int o = 1; o <= 8; o <<= 1) v = fmaxf(v, __shfl_xor(v, o));
            mx[mt][r] = v;
        }
    if (m == 0) {
#pragma unroll
        for (int mt = 0; mt < 4; ++mt)
#pragma unroll
            for (int r = 0; r < 4; ++r) red[0][w][mt * 16 + g * 4 + r] = mx[mt][r];
    }
    __syncthreads();
    float sume[4][4];
#pragma unroll
    for (int mt = 0; mt < 4; ++mt)
#pragma unroll
        for (int r = 0; r < 4; ++r) {
            int p = mt * 16 + g * 4 + r;
            float M = fmaxf(fmaxf(red[0][0][p], red[0][1][p]), fmaxf(red[0][2][p], red[0][3][p]));
            acc[mt][0][r] = expf(acc[mt][0][r] - M);
            acc[mt][1][r] = expf(acc[mt][1][r] - M);
            float s = acc[mt][0][r] + acc[mt][1][r];
#pragma unroll
            for (int o = 1; o <= 8; o <<= 1) s += __shfl_xor(s, o);
            sume[mt][r] = s;
        }
    if (m == 0) {
#pragma unroll
        for (int mt = 0; mt < 4; ++mt)
#pragma unroll
            for (int r = 0; r < 4; ++r) red[1][w][mt * 16 + g * 4 + r] = sume[mt][r];
    }
    __syncthreads();
#pragma unroll
    for (int mt = 0; mt < 4; ++mt)
#pragma unroll
        for (int r = 0; r < 4; ++r) {
            int p = mt * 16 + g * 4 + r;
            float S = red[1][0][p] + red[1][1][p] + red[1][2][p] + red[1][3][p];
            float inv = 1.0f / S;
            size_t pix = ((size_t)b * 64 + P) * 64 + p;
            smout[pix * 128 + co0] = acc[mt][0][r] * inv;
            smout[pix * 128 + co0 + 16] = acc[mt][1][r] * inv;
        }
}

// fp16 implicit-GEMM 3x3 conv + bias + elu + gate, LDS-staged rows (1 MFMA/frag).
template <int CI>
__global__ __launch_bounds__(256, 4) void k_conv_lds(const _Float16* __restrict__ in0,
                                                     const _Float16* __restrict__ in1,
                                                     const _Float16* __restrict__ wt,
                                                     const float* __restrict__ bias,
                                                     const float* __restrict__ sm,
                                                     float* __restrict__ out) {
    const int bid = blockIdx.x;
    const int idx = (bid & 7) * 128 + (bid >> 3);
    const int row = idx >> 1, cohalf = idx & 1;
    const int b = row >> 6, P = row & 63;
    const int tid = threadIdx.x;
    const int w = tid >> 6, lane = tid & 63;
    const int m = lane & 15, g = lane >> 4;
    __shared__ _Float16 S[66 * 128];
    char* sb = (char*)S;
    f32x4 acc[4];
#pragma unroll
    for (int mt = 0; mt < 4; ++mt) acc[mt] = f32x4{0.f, 0.f, 0.f, 0.f};
    const int cow = cohalf * 64 + w * 16 + m;

#pragma unroll
    for (int half = 0; half < CI / 128; ++half) {
        const _Float16* ih = (half == 0) ? in0 : in1;
        const size_t rbase0 = ((size_t)b * 66 + P) * 66 * 128;
#pragma unroll
        for (int i = 0; i < 3; ++i) {
            __syncthreads();
            const size_t rsrc = rbase0 + (size_t)i * 66 * 128;
#pragma unroll
            for (int e0 = 0; e0 < 1056; e0 += 256) {
                int e = e0 + tid;
                if (e < 1056) {
                    int px = e >> 4, c8 = e & 15;
                    int lin = px * 256 + c8 * 16;
                    int sz = lin ^ ((px & 7) << 4);
                    size_t so = rsrc + (size_t)px * 128 + c8 * 8;
                    *reinterpret_cast<f16x8*>(sb + sz) = *reinterpret_cast<const f16x8*>(ih + so);
                }
            }
            __syncthreads();
#pragma unroll
            for (int j = 0; j < 3; ++j) {
                const int ij = i * 3 + j;
                const _Float16* wp = wt + ((size_t)ij * 128 + cow) * CI + half * 128 + g * 8;
#pragma unroll
                for (int ci0 = 0; ci0 < 128; ci0 += 32) {
                    f16x8 bv = *reinterpret_cast<const f16x8*>(wp + ci0);
                    f16x8 av[4];
#pragma unroll
                    for (int mt = 0; mt < 4; ++mt) {
                        int px = mt * 16 + m + j;
                        int lin = px * 256 + ci0 * 2 + g * 16;
                        int sz = lin ^ ((px & 7) << 4);
                        av[mt] = *reinterpret_cast<const f16x8*>(sb + sz);
                    }
#pragma unroll
                    for (int mt = 0; mt < 4; ++mt)
                        acc[mt] = __builtin_amdgcn_mfma_f32_16x16x32_f16(av[mt], bv, acc[mt], 0, 0, 0);
                }
            }
        }
    }
    const float bb = bias[cow];
#pragma unroll
    for (int mt = 0; mt < 4; ++mt) {
#pragma unroll
        for (int r = 0; r < 4; ++r) {
            int Q = mt * 16 + g * 4 + r;
            size_t pix = ((size_t)b * 64 + P) * 64 + Q;
            float z = acc[mt][r] + bb;
            z = z > 0.f ? z : expm1f(z);
            out[pix * 128 + cow] = z * sm[pix * 128 + cow];
        }
    }
}

extern "C" void kernel_launch(void* const* d_in, const int* in_sizes, int n_in,
                              void* d_out, int out_size, void* d_ws, size_t ws_size,
                              hipStream_t stream) {
    const float* x    = (const float*)d_in[0];
    const float* mask = (const float*)d_in[1];
    const float* w1   = (const float*)d_in[2];
    const float* b1   = (const float*)d_in[3];
    const float* dw1  = (const float*)d_in[4];
    const float* pw1  = (const float*)d_in[5];
    const float* db1  = (const float*)d_in[6];
    const float* w2   = (const float*)d_in[7];
    const float* b2   = (const float*)d_in[8];
    const float* dw2  = (const float*)d_in[9];
    const float* pw2  = (const float*)d_in[10];
    const float* db2  = (const float*)d_in[11];

    float* out_a = (float*)d_out;            // (8,64,64,128)
    float* out_c = out_a + 4194304;          // (8,32,32,1024)

    char* wsb = (char*)d_ws;
    float* sp      = (float*)(wsb + BOFF_SP);
    float* invd    = (float*)(wsb + BOFF_INVD);
    _Float16* sp16 = (_Float16*)(wsb + BOFF_SP16);
    _Float16* bf16b = (_Float16*)(wsb + BOFF_BF16);
    float* Tbuf    = (float*)(wsb + BOFF_T);
    _Float16* bp16 = (_Float16*)(wsb + BOFF_BP16);
    _Float16* yp16 = (_Float16*)(wsb + BOFF_YP16);
    float* yup     = (float*)(wsb + BOFF_YUP);
    float* smb     = (float*)(wsb + BOFF_SM);
    _Float16* p316 = (_Float16*)(wsb + BOFF_P316);
    float* a1      = (float*)(wsb + BOFF_A1);
    _Float16* x16  = (_Float16*)(wsb + BOFF_X16);
    _Float16* wt1  = (_Float16*)(wsb + BOFF_WT1);
    _Float16* wt2  = (_Float16*)(wsb + BOFF_WT2);
    _Float16* pw1t = (_Float16*)(wsb + BOFF_PW1);
    _Float16* pw2t = (_Float16*)(wsb + BOFF_PW2);
    float* m0      = (float*)(wsb + BOFF_M0);
    float* mmb     = (float*)(wsb + BOFF_MM);

    // phase A: mask + correlation (fp16 MFMA) + fuse + softmax
    k_mask_pool<<<8192, 256, 0, stream>>>(mask, m0);
    k_mask_dilate<<<32, 256, 0, stream>>>(m0, mmb);
    k_srcpad<<<4624, 256, 0, stream>>>(x, sp);
    k_sp16<<<579, 256, 0, stream>>>(sp, sp16);
    k_invd<<<512, 256, 0, stream>>>(sp, invd);
    k_wt16<<<576, 256, 0, stream>>>(w1, wt1, 128);
    k_wt16<<<1152, 256, 0, stream>>>(w2, wt2, 256);
    k_pw16<<<64, 256, 0, stream>>>(pw1, pw1t, 128);
    k_pw16<<<128, 256, 0, stream>>>(pw2, pw2t, 256);
    k_corr_B16<<<4608, 256, 0, stream>>>(sp, invd, bf16b);
    k_corr_mfma<<<dim3(16, 8, 8), 512, 0, stream>>>(sp16, bf16b, out_c);
    k_fuse1<<<32768, 256, 0, stream>>>(out_c, Tbuf);
    k_fuse2<<<32768, 256, 0, stream>>>(Tbuf, out_c);
    k_deconv_B16<<<4608, 256, 0, stream>>>(x, bp16);
    k_softmax1024<<<8192, 256, 0, stream>>>(out_c, mmb, out_c, yp16);
    // phase B: deconv (fp16 MFMA) -> yup
    hipMemsetAsync(yup, 0, (size_t)4194304 * sizeof(float), stream);
    k_deconv_mfma<<<dim3(9, 8, 8), 512, 0, stream>>>(yp16, bp16, yup);
    // phase C: gated conv 1 (all fp16 single-plane)
    k_pad16<<<2178, 256, 0, stream>>>(yup, p316);   // yup dead after this
    k_pad16<<<2178, 256, 0, stream>>>(x, x16);      // overlaps dead yup region
    k_dwpw_mfma<128><<<512, 256, 0, stream>>>(p316, nullptr, dw1, pw1t, db1, smb);
    k_conv_lds<128><<<1024, 256, 0, stream>>>(p316, nullptr, wt1, b1, smb, a1);
    // phase D: gated conv 2 (concat(a1, x))
    k_pad16<<<2178, 256, 0, stream>>>(a1, p316);
    k_dwpw_mfma<256><<<512, 256, 0, stream>>>(p316, x16, dw2, pw2t, db2, smb);
    k_conv_lds<256><<<1024, 256, 0, stream>>>(p316, x16, wt2, b2, smb, out_a);
}